// Round 1
// baseline (1580.308 us; speedup 1.0000x reference)
//
#include <hip/hip_runtime.h>
#include <cstdint>
#include <cstddef>

#define NNODES 50000
#define NEDGES 500000
#define ETOT   (NEDGES + NNODES)

// ---------- ordered-uint encoding for float atomicMax (0 == -infinity-ish) ----------
__device__ __forceinline__ unsigned enc_f(float f) {
    unsigned u = __float_as_uint(f);
    return (u & 0x80000000u) ? ~u : (u | 0x80000000u);
}
__device__ __forceinline__ float dec_f(unsigned u) {
    unsigned v = (u & 0x80000000u) ? (u ^ 0x80000000u) : ~u;
    return __uint_as_float(v);
}

// ---------- generic fused GEMM: C = op(A_cat @ B + bias), optional relu + column stats ----------
// A_cat row i, col k:  k < K1 -> A[i*lda + k]  else A2[i*lda2 + (k-K1)]
// B is [K, N] row-major, C is [M, N] row-major.
#define BM 64
#define BN 64
#define BK 16

__global__ __launch_bounds__(256, 2) void gemm_fused(
    const float* __restrict__ A, int lda,
    const float* __restrict__ A2, int lda2, int K1,
    const float* __restrict__ B,
    float* __restrict__ C,
    const float* __restrict__ bias,
    float* __restrict__ colsum, float* __restrict__ colsq,
    int M, int N, int K, int do_relu)
{
    __shared__ float As[BK][BM + 1];
    __shared__ float Bs[BK][BN + 1];
    __shared__ float red[16][BN];

    int tid = threadIdx.x;
    int tx = tid & 15, ty = tid >> 4;
    int row0 = blockIdx.y * BM;
    int col0 = blockIdx.x * BN;

    float acc[4][4] = {};

    for (int k0 = 0; k0 < K; k0 += BK) {
        // A tile: 64 rows x 16 k
        #pragma unroll
        for (int i = 0; i < 4; ++i) {
            int t = tid + i * 256;
            int r  = t >> 4;
            int kk = t & 15;
            int gr = row0 + r, gk = k0 + kk;
            float v = 0.f;
            if (gr < M && gk < K) {
                if (gk < K1) v = A[(size_t)gr * lda + gk];
                else         v = A2[(size_t)gr * lda2 + (gk - K1)];
            }
            As[kk][r] = v;
        }
        // B tile: 16 k x 64 n
        #pragma unroll
        for (int i = 0; i < 4; ++i) {
            int t = tid + i * 256;
            int nn = t & 63;
            int kk = t >> 6;
            int gk = k0 + kk, gn = col0 + nn;
            Bs[kk][nn] = (gk < K && gn < N) ? B[(size_t)gk * N + gn] : 0.f;
        }
        __syncthreads();
        #pragma unroll
        for (int kk = 0; kk < BK; ++kk) {
            float a[4], b[4];
            #pragma unroll
            for (int r = 0; r < 4; ++r) a[r] = As[kk][ty * 4 + r];
            #pragma unroll
            for (int c = 0; c < 4; ++c) b[c] = Bs[kk][tx * 4 + c];
            #pragma unroll
            for (int r = 0; r < 4; ++r)
                #pragma unroll
                for (int c = 0; c < 4; ++c)
                    acc[r][c] += a[r] * b[c];
        }
        __syncthreads();
    }

    float vals[4][4];
    #pragma unroll
    for (int r = 0; r < 4; ++r) {
        int gr = row0 + ty * 4 + r;
        #pragma unroll
        for (int c = 0; c < 4; ++c) {
            int gc = col0 + tx * 4 + c;
            float v = acc[r][c];
            if (bias != nullptr && gc < N) v += bias[gc];
            if (do_relu) v = fmaxf(v, 0.f);
            bool ok = (gr < M) && (gc < N);
            vals[r][c] = ok ? v : 0.f;
            if (ok) C[(size_t)gr * N + gc] = v;
        }
    }

    if (colsum != nullptr) {
        float ps[4] = {}, pq[4] = {};
        #pragma unroll
        for (int r = 0; r < 4; ++r)
            #pragma unroll
            for (int c = 0; c < 4; ++c) {
                float v = vals[r][c];
                ps[c] += v; pq[c] += v * v;
            }
        #pragma unroll
        for (int c = 0; c < 4; ++c) red[ty][tx * 4 + c] = ps[c];
        __syncthreads();
        if (tid < 64) {
            float s = 0.f;
            #pragma unroll
            for (int t = 0; t < 16; ++t) s += red[t][tid];
            int gc = col0 + tid;
            if (gc < N) atomicAdd(&colsum[gc], s);
        }
        __syncthreads();
        #pragma unroll
        for (int c = 0; c < 4; ++c) red[ty][tx * 4 + c] = pq[c];
        __syncthreads();
        if (tid < 64) {
            float s = 0.f;
            #pragma unroll
            for (int t = 0; t < 16; ++t) s += red[t][tid];
            int gc = col0 + tid;
            if (gc < N) atomicAdd(&colsq[gc], s);
        }
    }
}

// ---------- per-node attention dots: a_src[n,h] = <h[n,h,:], att_src[h,:]> ----------
__global__ __launch_bounds__(256) void att_dots(
    const float* __restrict__ h,
    const float* __restrict__ att_src, const float* __restrict__ att_dst,
    float* __restrict__ a_src, float* __restrict__ a_dst,
    int Nn, int H, int Dd)
{
    int wave = (blockIdx.x * blockDim.x + threadIdx.x) >> 6;
    int lane = threadIdx.x & 63;
    if (wave >= Nn) return;
    const float* hr = h + (size_t)wave * H * Dd;
    for (int hh = 0; hh < H; ++hh) {
        float s = 0.f, d = 0.f;
        for (int j = lane; j < Dd; j += 64) {
            float v = hr[hh * Dd + j];
            s += v * att_src[hh * Dd + j];
            d += v * att_dst[hh * Dd + j];
        }
        #pragma unroll
        for (int off = 32; off > 0; off >>= 1) {
            s += __shfl_down(s, off);
            d += __shfl_down(d, off);
        }
        if (lane == 0) { a_src[wave * H + hh] = s; a_dst[wave * H + hh] = d; }
    }
}

__device__ __forceinline__ void edge_src_dst(const int* ei, int e, int& src, int& dst) {
    if (e < NEDGES) { src = ei[e]; dst = ei[NEDGES + e]; }
    else { src = e - NEDGES; dst = src; }
}

// ---------- edge pass 1: leaky-relu logit + segment max ----------
__global__ __launch_bounds__(256) void edge_logits(
    const int* __restrict__ ei,
    const float* __restrict__ a_src, const float* __restrict__ a_dst,
    float* __restrict__ alpha, unsigned* __restrict__ mbuf, int H)
{
    int e = blockIdx.x * blockDim.x + threadIdx.x;
    if (e >= ETOT) return;
    int src, dst; edge_src_dst(ei, e, src, dst);
    for (int hh = 0; hh < H; ++hh) {
        float v = a_src[src * H + hh] + a_dst[dst * H + hh];
        v = (v >= 0.f) ? v : 0.2f * v;
        alpha[(size_t)e * H + hh] = v;
        atomicMax(&mbuf[dst * H + hh], enc_f(v));
    }
}

// ---------- edge pass 2: exp + segment sum ----------
__global__ __launch_bounds__(256) void edge_expsum(
    const int* __restrict__ ei,
    const float* __restrict__ alpha, const unsigned* __restrict__ mbuf,
    float* __restrict__ ebuf, float* __restrict__ sbuf, int H)
{
    int e = blockIdx.x * blockDim.x + threadIdx.x;
    if (e >= ETOT) return;
    int src, dst; edge_src_dst(ei, e, src, dst);
    (void)src;
    for (int hh = 0; hh < H; ++hh) {
        float m  = dec_f(mbuf[dst * H + hh]);
        float ev = expf(alpha[(size_t)e * H + hh] - m);
        ebuf[(size_t)e * H + hh] = ev;
        atomicAdd(&sbuf[dst * H + hh], ev);
    }
}

// ---------- edge pass 3: weighted scatter-sum (one wave per edge) ----------
__global__ __launch_bounds__(256) void edge_scatter(
    const int* __restrict__ ei,
    const float* __restrict__ h,
    const float* __restrict__ ebuf, const float* __restrict__ sbuf,
    float* __restrict__ out, int H, int Dd)
{
    int gid = blockIdx.x * blockDim.x + threadIdx.x;
    int e = gid >> 6;
    int lane = gid & 63;
    if (e >= ETOT) return;
    int src, dst; edge_src_dst(ei, e, src, dst);
    float w0 = ebuf[(size_t)e * H] / (sbuf[dst * H] + 1e-16f);
    float w1 = (H > 1) ? ebuf[(size_t)e * H + 1] / (sbuf[dst * H + 1] + 1e-16f) : 0.f;
    int HD = H * Dd;
    const float* hs = h + (size_t)src * HD;
    float* od = out + (size_t)dst * HD;
    for (int j = lane; j < HD; j += 64) {
        float w = (j < Dd) ? w0 : w1;
        atomicAdd(&od[j], hs[j] * w);
    }
}

// ---------- elementwise helpers ----------
__global__ void add_bias_k(float* __restrict__ x, const float* __restrict__ bias, int total, int Ncols) {
    int i = blockIdx.x * blockDim.x + threadIdx.x;
    if (i >= total) return;
    x[i] += bias[i % Ncols];
}

__global__ void bn_finalize(const float* __restrict__ colsum, const float* __restrict__ colsq,
                            const float* __restrict__ gamma, const float* __restrict__ beta,
                            float* __restrict__ scale, float* __restrict__ shift,
                            int Ncols, float invM)
{
    int j = blockIdx.x * blockDim.x + threadIdx.x;
    if (j >= Ncols) return;
    float mu  = colsum[j] * invM;
    float var = colsq[j] * invM - mu * mu;
    if (var < 0.f) var = 0.f;
    float sc = gamma[j] * rsqrtf(var + 1e-5f);
    scale[j] = sc;
    shift[j] = beta[j] - mu * sc;
}

__global__ void bn_apply(float* __restrict__ y, const float* __restrict__ scale,
                         const float* __restrict__ shift, int total, int Ncols)
{
    int i = blockIdx.x * blockDim.x + threadIdx.x;
    if (i >= total) return;
    int j = i % Ncols;
    y[i] = y[i] * scale[j] + shift[j];
}

extern "C" void kernel_launch(void* const* d_in, const int* in_sizes, int n_in,
                              void* d_out, int out_size, void* d_ws, size_t ws_size,
                              hipStream_t stream) {
    const float* x        = (const float*)d_in[0];
    const int*   ei       = (const int*)d_in[1];
    const float* W1       = (const float*)d_in[2];
    const float* att_src1 = (const float*)d_in[3];
    const float* att_dst1 = (const float*)d_in[4];
    const float* bias1    = (const float*)d_in[5];
    const float* W2       = (const float*)d_in[6];
    const float* att_src2 = (const float*)d_in[7];
    const float* att_dst2 = (const float*)d_in[8];
    const float* bias2    = (const float*)d_in[9];
    const float* Wl       = (const float*)d_in[10];
    const float* bl       = (const float*)d_in[11];
    const float* gl       = (const float*)d_in[12];
    const float* betal    = (const float*)d_in[13];
    const float* Wa       = (const float*)d_in[14];
    const float* ba       = (const float*)d_in[15];
    const float* ga       = (const float*)d_in[16];
    const float* betaa    = (const float*)d_in[17];
    const float* Wb       = (const float*)d_in[18];
    const float* bb       = (const float*)d_in[19];
    const float* gb       = (const float*)d_in[20];
    const float* betab    = (const float*)d_in[21];
    float* out = (float*)d_out;
    char* ws = (char*)d_ws;

    const int N = NNODES;

    // workspace layout (bytes)
    const size_t offA   = 0;            // 51.2 MB: h1 -> h2 -> y1
    const size_t offB   = 51200000;     // 51.2 MB: x1 -> y2
    const size_t offC   = 102400000;    // 25.6 MB: x2
    const size_t offAl  = 128000000;    // 4.4 MB alpha
    const size_t offEb  = 132400000;    // 4.4 MB exp(alpha - m)
    const size_t offAs1 = 136800000;    // a_src1 [N*2]
    const size_t offAd1 = 137200000;    // a_dst1 [N*2]
    const size_t offM1  = 137600000;    // m1 [N*2] (encoded uint)
    const size_t offS1  = 138000000;    // s1 [N*2]
    const size_t offAs2 = 138400000;    // a_src2 [N]
    const size_t offAd2 = 138600000;    // a_dst2 [N]
    const size_t offM2  = 138800000;    // m2 [N]
    const size_t offS2  = 139000000;    // s2 [N]
    const size_t offSt  = 139200000;    // stats: 12 x 512 B

    float* h1  = (float*)(ws + offA);
    float* x1  = (float*)(ws + offB);
    float* x2  = (float*)(ws + offC);
    float* alp = (float*)(ws + offAl);
    float* eb  = (float*)(ws + offEb);
    float* as1 = (float*)(ws + offAs1);
    float* ad1 = (float*)(ws + offAd1);
    unsigned* m1 = (unsigned*)(ws + offM1);
    float* s1  = (float*)(ws + offS1);
    float* as2 = (float*)(ws + offAs2);
    float* ad2 = (float*)(ws + offAd2);
    unsigned* m2 = (unsigned*)(ws + offM2);
    float* s2  = (float*)(ws + offS2);
    float* h2  = (float*)(ws + offA);   // reuse A (h1 dead after scatter1)
    float* y1  = (float*)(ws + offA);   // reuse A (h2 dead after scatter2)
    float* y2  = (float*)(ws + offB);   // reuse B (x1 dead after lin1 gemm)

    float* csum_l = (float*)(ws + offSt + 0);
    float* csq_l  = (float*)(ws + offSt + 512);
    float* scl_l  = (float*)(ws + offSt + 1024);
    float* shf_l  = (float*)(ws + offSt + 1536);
    float* csum_a = (float*)(ws + offSt + 2048);
    float* csq_a  = (float*)(ws + offSt + 2560);
    float* scl_a  = (float*)(ws + offSt + 3072);
    float* shf_a  = (float*)(ws + offSt + 3584);
    float* csum_b = (float*)(ws + offSt + 4096);
    float* csq_b  = (float*)(ws + offSt + 4608);
    float* scl_b  = (float*)(ws + offSt + 5120);
    float* shf_b  = (float*)(ws + offSt + 5632);

    // zero accumulators (poisoned 0xAA before every launch)
    hipMemsetAsync(ws + offB, 0, 51200000, stream);                    // x1
    hipMemsetAsync(ws + offC, 0, 25600000, stream);                    // x2
    hipMemsetAsync(ws + offAs1, 0, (offSt + 6144) - offAs1, stream);   // m/s/a + stats

    dim3 blk(256);
    int edgeBlocks   = (ETOT + 255) / 256;
    int waveBlocksE  = (ETOT * 64 + 255) / 256;
    int waveBlocksN  = (N + 3) / 4;   // 4 waves per 256-thread block

    // ---- conv1 ----
    gemm_fused<<<dim3((256 + BN - 1) / BN, (N + BM - 1) / BM), blk, 0, stream>>>(
        x, 128, nullptr, 0, 128, W1, h1, nullptr, nullptr, nullptr, N, 256, 128, 0);
    att_dots<<<waveBlocksN, blk, 0, stream>>>(h1, att_src1, att_dst1, as1, ad1, N, 2, 128);
    edge_logits<<<edgeBlocks, blk, 0, stream>>>(ei, as1, ad1, alp, m1, 2);
    edge_expsum<<<edgeBlocks, blk, 0, stream>>>(ei, alp, m1, eb, s1, 2);
    edge_scatter<<<waveBlocksE, blk, 0, stream>>>(ei, h1, eb, s1, x1, 2, 128);
    add_bias_k<<<(N * 256 + 255) / 256, blk, 0, stream>>>(x1, bias1, N * 256, 256);

    // ---- conv2 ----
    gemm_fused<<<dim3((128 + BN - 1) / BN, (N + BM - 1) / BM), blk, 0, stream>>>(
        x1, 256, nullptr, 0, 256, W2, h2, nullptr, nullptr, nullptr, N, 128, 256, 0);
    att_dots<<<waveBlocksN, blk, 0, stream>>>(h2, att_src2, att_dst2, as2, ad2, N, 1, 128);
    edge_logits<<<edgeBlocks, blk, 0, stream>>>(ei, as2, ad2, alp, m2, 1);
    edge_expsum<<<edgeBlocks, blk, 0, stream>>>(ei, alp, m2, eb, s2, 1);
    edge_scatter<<<waveBlocksE, blk, 0, stream>>>(ei, h2, eb, s2, x2, 1, 128);
    add_bias_k<<<(N * 128 + 255) / 256, blk, 0, stream>>>(x2, bias2, N * 128, 128);

    // ---- lin1: relu([x1|x2] @ Wl + bl) + stats ----
    gemm_fused<<<dim3((96 + BN - 1) / BN, (N + BM - 1) / BM), blk, 0, stream>>>(
        x1, 256, x2, 128, 256, Wl, y1, bl, csum_l, csq_l, N, 96, 384, 1);
    bn_finalize<<<1, 128, 0, stream>>>(csum_l, csq_l, gl, betal, scl_l, shf_l, 96, 1.f / N);
    bn_apply<<<(N * 96 + 255) / 256, blk, 0, stream>>>(y1, scl_l, shf_l, N * 96, 96);

    // ---- mlp1 layer 1 ----
    gemm_fused<<<dim3((96 + BN - 1) / BN, (N + BM - 1) / BM), blk, 0, stream>>>(
        y1, 96, nullptr, 0, 96, Wa, y2, ba, csum_a, csq_a, N, 96, 96, 1);
    bn_finalize<<<1, 128, 0, stream>>>(csum_a, csq_a, ga, betaa, scl_a, shf_a, 96, 1.f / N);
    bn_apply<<<(N * 96 + 255) / 256, blk, 0, stream>>>(y2, scl_a, shf_a, N * 96, 96);

    // ---- mlp1 layer 2 (writes d_out) ----
    gemm_fused<<<dim3(1, (N + BM - 1) / BM), blk, 0, stream>>>(
        y2, 96, nullptr, 0, 96, Wb, out, bb, csum_b, csq_b, N, 2, 96, 1);
    bn_finalize<<<1, 64, 0, stream>>>(csum_b, csq_b, gb, betab, scl_b, shf_b, 2, 1.f / N);
    bn_apply<<<(N * 2 + 255) / 256, blk, 0, stream>>>(out, scl_b, shf_b, N * 2, 2);
}

// Round 2
// 1019.488 us; speedup vs baseline: 1.5501x; 1.5501x over previous
//
#include <hip/hip_runtime.h>
#include <cstdint>
#include <cstddef>

#define NNODES 50000
#define NEDGES 500000
#define ETOT   (NEDGES + NNODES)

// ---------- generic fused GEMM: C = op(A_cat @ B + bias), optional relu + column stats ----------
#define BM 64
#define BN 64
#define BK 16

__global__ __launch_bounds__(256, 2) void gemm_fused(
    const float* __restrict__ A, int lda,
    const float* __restrict__ A2, int lda2, int K1,
    const float* __restrict__ B,
    float* __restrict__ C,
    const float* __restrict__ bias,
    float* __restrict__ colsum, float* __restrict__ colsq,
    int M, int N, int K, int do_relu)
{
    __shared__ float As[BK][BM + 1];
    __shared__ float Bs[BK][BN + 1];
    __shared__ float red[16][BN];

    int tid = threadIdx.x;
    int tx = tid & 15, ty = tid >> 4;
    int row0 = blockIdx.y * BM;
    int col0 = blockIdx.x * BN;

    float acc[4][4] = {};

    for (int k0 = 0; k0 < K; k0 += BK) {
        #pragma unroll
        for (int i = 0; i < 4; ++i) {
            int t = tid + i * 256;
            int r  = t >> 4;
            int kk = t & 15;
            int gr = row0 + r, gk = k0 + kk;
            float v = 0.f;
            if (gr < M && gk < K) {
                if (gk < K1) v = A[(size_t)gr * lda + gk];
                else         v = A2[(size_t)gr * lda2 + (gk - K1)];
            }
            As[kk][r] = v;
        }
        #pragma unroll
        for (int i = 0; i < 4; ++i) {
            int t = tid + i * 256;
            int nn = t & 63;
            int kk = t >> 6;
            int gk = k0 + kk, gn = col0 + nn;
            Bs[kk][nn] = (gk < K && gn < N) ? B[(size_t)gk * N + gn] : 0.f;
        }
        __syncthreads();
        #pragma unroll
        for (int kk = 0; kk < BK; ++kk) {
            float a[4], b[4];
            #pragma unroll
            for (int r = 0; r < 4; ++r) a[r] = As[kk][ty * 4 + r];
            #pragma unroll
            for (int c = 0; c < 4; ++c) b[c] = Bs[kk][tx * 4 + c];
            #pragma unroll
            for (int r = 0; r < 4; ++r)
                #pragma unroll
                for (int c = 0; c < 4; ++c)
                    acc[r][c] += a[r] * b[c];
        }
        __syncthreads();
    }

    float vals[4][4];
    #pragma unroll
    for (int r = 0; r < 4; ++r) {
        int gr = row0 + ty * 4 + r;
        #pragma unroll
        for (int c = 0; c < 4; ++c) {
            int gc = col0 + tx * 4 + c;
            float v = acc[r][c];
            if (bias != nullptr && gc < N) v += bias[gc];
            if (do_relu) v = fmaxf(v, 0.f);
            bool ok = (gr < M) && (gc < N);
            vals[r][c] = ok ? v : 0.f;
            if (ok) C[(size_t)gr * N + gc] = v;
        }
    }

    if (colsum != nullptr) {
        float ps[4] = {}, pq[4] = {};
        #pragma unroll
        for (int r = 0; r < 4; ++r)
            #pragma unroll
            for (int c = 0; c < 4; ++c) {
                float v = vals[r][c];
                ps[c] += v; pq[c] += v * v;
            }
        #pragma unroll
        for (int c = 0; c < 4; ++c) red[ty][tx * 4 + c] = ps[c];
        __syncthreads();
        if (tid < 64) {
            float s = 0.f;
            #pragma unroll
            for (int t = 0; t < 16; ++t) s += red[t][tid];
            int gc = col0 + tid;
            if (gc < N) atomicAdd(&colsum[gc], s);
        }
        __syncthreads();
        #pragma unroll
        for (int c = 0; c < 4; ++c) red[ty][tx * 4 + c] = pq[c];
        __syncthreads();
        if (tid < 64) {
            float s = 0.f;
            #pragma unroll
            for (int t = 0; t < 16; ++t) s += red[t][tid];
            int gc = col0 + tid;
            if (gc < N) atomicAdd(&colsq[gc], s);
        }
    }
}

// ---------- per-node attention dots ----------
__global__ __launch_bounds__(256) void att_dots(
    const float* __restrict__ h,
    const float* __restrict__ att_src, const float* __restrict__ att_dst,
    float* __restrict__ a_src, float* __restrict__ a_dst,
    int Nn, int H, int Dd)
{
    int wave = (blockIdx.x * blockDim.x + threadIdx.x) >> 6;
    int lane = threadIdx.x & 63;
    if (wave >= Nn) return;
    const float* hr = h + (size_t)wave * H * Dd;
    for (int hh = 0; hh < H; ++hh) {
        float s = 0.f, d = 0.f;
        for (int j = lane; j < Dd; j += 64) {
            float v = hr[hh * Dd + j];
            s += v * att_src[hh * Dd + j];
            d += v * att_dst[hh * Dd + j];
        }
        #pragma unroll
        for (int off = 32; off > 0; off >>= 1) {
            s += __shfl_down(s, off);
            d += __shfl_down(d, off);
        }
        if (lane == 0) { a_src[wave * H + hh] = s; a_dst[wave * H + hh] = d; }
    }
}

__device__ __forceinline__ void edge_src_dst(const int* ei, int e, int& src, int& dst) {
    if (e < NEDGES) { src = ei[e]; dst = ei[NEDGES + e]; }
    else { src = e - NEDGES; dst = src; }
}

// ---------- CSR build ----------
__global__ __launch_bounds__(256) void csr_count(const int* __restrict__ ei, int* __restrict__ cnt) {
    int e = blockIdx.x * blockDim.x + threadIdx.x;
    if (e >= ETOT) return;
    int src, dst; edge_src_dst(ei, e, src, dst); (void)src;
    atomicAdd(&cnt[dst], 1);
}

// single-block exclusive scan of cnt[0..N) -> rowstart (in place OK: cnt == rowstart array)
__global__ __launch_bounds__(1024) void csr_scan(int* __restrict__ rowcnt, int* __restrict__ cursor) {
    __shared__ int buf[2][1024];
    const int T = 1024, CH = (NNODES + T - 1) / T;   // 49
    int t = threadIdx.x;
    int lo = t * CH, hi = min(lo + CH, NNODES);
    int local = 0;
    for (int i = lo; i < hi; ++i) local += rowcnt[i];
    buf[0][t] = local;
    __syncthreads();
    int cur = 0;
    for (int off = 1; off < T; off <<= 1) {
        int nxt = cur ^ 1;
        int v = buf[cur][t];
        if (t >= off) v += buf[cur][t - off];
        buf[nxt][t] = v;
        __syncthreads();
        cur = nxt;
    }
    int running = buf[cur][t] - local;   // exclusive prefix
    for (int i = lo; i < hi; ++i) {
        int d = rowcnt[i];
        rowcnt[i] = running;     // rowstart
        cursor[i] = running;
        running += d;
    }
    if (t == 0) rowcnt[NNODES] = ETOT;
}

__global__ __launch_bounds__(256) void csr_fill(const int* __restrict__ ei,
                                                int* __restrict__ cursor,
                                                int* __restrict__ esrc) {
    int e = blockIdx.x * blockDim.x + threadIdx.x;
    if (e >= ETOT) return;
    int src, dst; edge_src_dst(ei, e, src, dst);
    int pos = atomicAdd(&cursor[dst], 1);
    esrc[pos] = src;
}

// ---------- fused GAT aggregation (softmax + gather + bias), one wave per node ----------
__global__ __launch_bounds__(256) void gat_gather_h2(
    const int* __restrict__ rowstart, const int* __restrict__ esrc,
    const float* __restrict__ h, const float* __restrict__ a_src,
    const float* __restrict__ a_dst, const float* __restrict__ bias,
    float* __restrict__ out)
{
    int n = (blockIdx.x * blockDim.x + threadIdx.x) >> 6;
    int lane = threadIdx.x & 63;
    if (n >= NNODES) return;
    int beg = rowstart[n], end = rowstart[n + 1];
    float ad0 = a_dst[n * 2], ad1 = a_dst[n * 2 + 1];

    float m0 = -1e30f, m1 = -1e30f;
    for (int i = beg + lane; i < end; i += 64) {
        int s = esrc[i];
        float l0 = a_src[s * 2] + ad0;     l0 = l0 >= 0.f ? l0 : 0.2f * l0;
        float l1 = a_src[s * 2 + 1] + ad1; l1 = l1 >= 0.f ? l1 : 0.2f * l1;
        m0 = fmaxf(m0, l0); m1 = fmaxf(m1, l1);
    }
    #pragma unroll
    for (int off = 1; off < 64; off <<= 1) {
        m0 = fmaxf(m0, __shfl_xor(m0, off));
        m1 = fmaxf(m1, __shfl_xor(m1, off));
    }
    float s0 = 0.f, s1 = 0.f;
    for (int i = beg + lane; i < end; i += 64) {
        int s = esrc[i];
        float l0 = a_src[s * 2] + ad0;     l0 = l0 >= 0.f ? l0 : 0.2f * l0;
        float l1 = a_src[s * 2 + 1] + ad1; l1 = l1 >= 0.f ? l1 : 0.2f * l1;
        s0 += __expf(l0 - m0); s1 += __expf(l1 - m1);
    }
    #pragma unroll
    for (int off = 1; off < 64; off <<= 1) {
        s0 += __shfl_xor(s0, off);
        s1 += __shfl_xor(s1, off);
    }
    int head = lane >> 5;                       // lanes 0-31: feats 0-127 (head 0); 32-63: head 1
    float mh   = head ? m1 : m0;
    float invh = head ? 1.f / (s1 + 1e-16f) : 1.f / (s0 + 1e-16f);
    float adh  = head ? ad1 : ad0;

    float4 acc = {0.f, 0.f, 0.f, 0.f};
    for (int i = beg; i < end; ++i) {
        int s = esrc[i];
        float l = a_src[s * 2 + head] + adh; l = l >= 0.f ? l : 0.2f * l;
        float w = __expf(l - mh) * invh;
        const float4 hv = *(const float4*)(h + (size_t)s * 256 + lane * 4);
        acc.x += w * hv.x; acc.y += w * hv.y; acc.z += w * hv.z; acc.w += w * hv.w;
    }
    const float4 b = *(const float4*)(bias + lane * 4);
    float4 o = {acc.x + b.x, acc.y + b.y, acc.z + b.z, acc.w + b.w};
    *(float4*)(out + (size_t)n * 256 + lane * 4) = o;
}

__global__ __launch_bounds__(256) void gat_gather_h1(
    const int* __restrict__ rowstart, const int* __restrict__ esrc,
    const float* __restrict__ h, const float* __restrict__ a_src,
    const float* __restrict__ a_dst, const float* __restrict__ bias,
    float* __restrict__ out)
{
    int n = (blockIdx.x * blockDim.x + threadIdx.x) >> 6;
    int lane = threadIdx.x & 63;
    if (n >= NNODES) return;
    int beg = rowstart[n], end = rowstart[n + 1];
    float ad0 = a_dst[n];

    float m0 = -1e30f;
    for (int i = beg + lane; i < end; i += 64) {
        int s = esrc[i];
        float l0 = a_src[s] + ad0; l0 = l0 >= 0.f ? l0 : 0.2f * l0;
        m0 = fmaxf(m0, l0);
    }
    #pragma unroll
    for (int off = 1; off < 64; off <<= 1) m0 = fmaxf(m0, __shfl_xor(m0, off));
    float s0 = 0.f;
    for (int i = beg + lane; i < end; i += 64) {
        int s = esrc[i];
        float l0 = a_src[s] + ad0; l0 = l0 >= 0.f ? l0 : 0.2f * l0;
        s0 += __expf(l0 - m0);
    }
    #pragma unroll
    for (int off = 1; off < 64; off <<= 1) s0 += __shfl_xor(s0, off);
    float inv0 = 1.f / (s0 + 1e-16f);

    float2 acc = {0.f, 0.f};
    for (int i = beg; i < end; ++i) {
        int s = esrc[i];
        float l = a_src[s] + ad0; l = l >= 0.f ? l : 0.2f * l;
        float w = __expf(l - m0) * inv0;
        const float2 hv = *(const float2*)(h + (size_t)s * 128 + lane * 2);
        acc.x += w * hv.x; acc.y += w * hv.y;
    }
    const float2 b = *(const float2*)(bias + lane * 2);
    float2 o = {acc.x + b.x, acc.y + b.y};
    *(float2*)(out + (size_t)n * 128 + lane * 2) = o;
}

// ---------- BN helpers ----------
__global__ void bn_finalize(const float* __restrict__ colsum, const float* __restrict__ colsq,
                            const float* __restrict__ gamma, const float* __restrict__ beta,
                            float* __restrict__ scale, float* __restrict__ shift,
                            int Ncols, float invM)
{
    int j = blockIdx.x * blockDim.x + threadIdx.x;
    if (j >= Ncols) return;
    float mu  = colsum[j] * invM;
    float var = colsq[j] * invM - mu * mu;
    if (var < 0.f) var = 0.f;
    float sc = gamma[j] * rsqrtf(var + 1e-5f);
    scale[j] = sc;
    shift[j] = beta[j] - mu * sc;
}

__global__ void bn_apply(float* __restrict__ y, const float* __restrict__ scale,
                         const float* __restrict__ shift, int total, int Ncols)
{
    int i = blockIdx.x * blockDim.x + threadIdx.x;
    if (i >= total) return;
    int j = i % Ncols;
    y[i] = y[i] * scale[j] + shift[j];
}

extern "C" void kernel_launch(void* const* d_in, const int* in_sizes, int n_in,
                              void* d_out, int out_size, void* d_ws, size_t ws_size,
                              hipStream_t stream) {
    const float* x        = (const float*)d_in[0];
    const int*   ei       = (const int*)d_in[1];
    const float* W1       = (const float*)d_in[2];
    const float* att_src1 = (const float*)d_in[3];
    const float* att_dst1 = (const float*)d_in[4];
    const float* bias1    = (const float*)d_in[5];
    const float* W2       = (const float*)d_in[6];
    const float* att_src2 = (const float*)d_in[7];
    const float* att_dst2 = (const float*)d_in[8];
    const float* bias2    = (const float*)d_in[9];
    const float* Wl       = (const float*)d_in[10];
    const float* bl       = (const float*)d_in[11];
    const float* gl       = (const float*)d_in[12];
    const float* betal    = (const float*)d_in[13];
    const float* Wa       = (const float*)d_in[14];
    const float* ba       = (const float*)d_in[15];
    const float* ga       = (const float*)d_in[16];
    const float* betaa    = (const float*)d_in[17];
    const float* Wb       = (const float*)d_in[18];
    const float* bb       = (const float*)d_in[19];
    const float* gb       = (const float*)d_in[20];
    const float* betab    = (const float*)d_in[21];
    float* out = (float*)d_out;
    char* ws = (char*)d_ws;

    const int N = NNODES;

    // workspace layout (bytes)
    const size_t offA    = 0;            // 51.2 MB: h1 -> h2 -> y1
    const size_t offB    = 51200000;     // 51.2 MB: x1 -> y2
    const size_t offC    = 102400000;    // 25.6 MB: x2
    const size_t offRow  = 128000000;    // rowcnt/rowstart [N+1] ints
    const size_t offCur  = 128204800;    // cursor [N] ints
    const size_t offEsrc = 128409600;    // esrc [ETOT] ints (2.2 MB)
    const size_t offAs1  = 136800000;    // a_src1 [N*2]
    const size_t offAd1  = 137200000;    // a_dst1 [N*2]
    const size_t offAs2  = 138400000;    // a_src2 [N]
    const size_t offAd2  = 138600000;    // a_dst2 [N]
    const size_t offSt   = 139200000;    // stats: 12 x 512 B

    float* h1  = (float*)(ws + offA);
    float* x1  = (float*)(ws + offB);
    float* x2  = (float*)(ws + offC);
    int* rowst = (int*)(ws + offRow);
    int* cursor= (int*)(ws + offCur);
    int* esrc  = (int*)(ws + offEsrc);
    float* as1 = (float*)(ws + offAs1);
    float* ad1 = (float*)(ws + offAd1);
    float* as2 = (float*)(ws + offAs2);
    float* ad2 = (float*)(ws + offAd2);
    float* h2  = (float*)(ws + offA);   // reuse A
    float* y1  = (float*)(ws + offA);   // reuse A
    float* y2  = (float*)(ws + offB);   // reuse B

    float* csum_l = (float*)(ws + offSt + 0);
    float* csq_l  = (float*)(ws + offSt + 512);
    float* scl_l  = (float*)(ws + offSt + 1024);
    float* shf_l  = (float*)(ws + offSt + 1536);
    float* csum_a = (float*)(ws + offSt + 2048);
    float* csq_a  = (float*)(ws + offSt + 2560);
    float* scl_a  = (float*)(ws + offSt + 3072);
    float* shf_a  = (float*)(ws + offSt + 3584);
    float* csum_b = (float*)(ws + offSt + 4096);
    float* csq_b  = (float*)(ws + offSt + 4608);
    float* scl_b  = (float*)(ws + offSt + 5120);
    float* shf_b  = (float*)(ws + offSt + 5632);

    // zero only what needs zeroing: CSR histogram + BN stat accumulators
    hipMemsetAsync(ws + offRow, 0, (NNODES + 1) * sizeof(int), stream);
    hipMemsetAsync(ws + offSt, 0, 6144, stream);

    dim3 blk(256);
    int edgeBlocks  = (ETOT + 255) / 256;
    int waveBlocksN = (N + 3) / 4;   // 4 waves per 256-thread block

    // ---- CSR build (shared by both convs) ----
    csr_count<<<edgeBlocks, blk, 0, stream>>>(ei, rowst);
    csr_scan<<<1, 1024, 0, stream>>>(rowst, cursor);
    csr_fill<<<edgeBlocks, blk, 0, stream>>>(ei, cursor, esrc);

    // ---- conv1 ----
    gemm_fused<<<dim3(256 / BN, (N + BM - 1) / BM), blk, 0, stream>>>(
        x, 128, nullptr, 0, 128, W1, h1, nullptr, nullptr, nullptr, N, 256, 128, 0);
    att_dots<<<waveBlocksN, blk, 0, stream>>>(h1, att_src1, att_dst1, as1, ad1, N, 2, 128);
    gat_gather_h2<<<waveBlocksN, blk, 0, stream>>>(rowst, esrc, h1, as1, ad1, bias1, x1);

    // ---- conv2 ----
    gemm_fused<<<dim3(128 / BN, (N + BM - 1) / BM), blk, 0, stream>>>(
        x1, 256, nullptr, 0, 256, W2, h2, nullptr, nullptr, nullptr, N, 128, 256, 0);
    att_dots<<<waveBlocksN, blk, 0, stream>>>(h2, att_src2, att_dst2, as2, ad2, N, 1, 128);
    gat_gather_h1<<<waveBlocksN, blk, 0, stream>>>(rowst, esrc, h2, as2, ad2, bias2, x2);

    // ---- lin1: relu([x1|x2] @ Wl + bl) + stats ----
    gemm_fused<<<dim3((96 + BN - 1) / BN, (N + BM - 1) / BM), blk, 0, stream>>>(
        x1, 256, x2, 128, 256, Wl, y1, bl, csum_l, csq_l, N, 96, 384, 1);
    bn_finalize<<<1, 128, 0, stream>>>(csum_l, csq_l, gl, betal, scl_l, shf_l, 96, 1.f / N);
    bn_apply<<<(N * 96 + 255) / 256, blk, 0, stream>>>(y1, scl_l, shf_l, N * 96, 96);

    // ---- mlp1 layer 1 ----
    gemm_fused<<<dim3((96 + BN - 1) / BN, (N + BM - 1) / BM), blk, 0, stream>>>(
        y1, 96, nullptr, 0, 96, Wa, y2, ba, csum_a, csq_a, N, 96, 96, 1);
    bn_finalize<<<1, 128, 0, stream>>>(csum_a, csq_a, ga, betaa, scl_a, shf_a, 96, 1.f / N);
    bn_apply<<<(N * 96 + 255) / 256, blk, 0, stream>>>(y2, scl_a, shf_a, N * 96, 96);

    // ---- mlp1 layer 2 (writes d_out) ----
    gemm_fused<<<dim3(1, (N + BM - 1) / BM), blk, 0, stream>>>(
        y2, 96, nullptr, 0, 96, Wb, out, bb, csum_b, csq_b, N, 2, 96, 1);
    bn_finalize<<<1, 64, 0, stream>>>(csum_b, csq_b, gb, betab, scl_b, shf_b, 2, 1.f / N);
    bn_apply<<<(N * 2 + 255) / 256, blk, 0, stream>>>(out, scl_b, shf_b, N * 2, 2);
}

// Round 3
// 628.505 us; speedup vs baseline: 2.5144x; 1.6221x over previous
//
#include <hip/hip_runtime.h>
#include <hip/hip_bf16.h>
#include <cstdint>
#include <cstddef>

#define NNODES 50000
#define NEDGES 500000
#define ETOT   (NEDGES + NNODES)

typedef __attribute__((ext_vector_type(8))) short short8;
typedef __attribute__((ext_vector_type(4))) float floatx4;
typedef __attribute__((ext_vector_type(4))) unsigned short ushort4v;
typedef __attribute__((ext_vector_type(2))) unsigned short ushort2v;

__device__ __forceinline__ unsigned short f2bf(float f) {
    union { __hip_bfloat16 h; unsigned short u; } cv;
    cv.h = __float2bfloat16(f);
    return cv.u;
}

// ================= bf16 MFMA GEMM: C = op(A @ Bt^T + bias) =================
// A: bf16 [M][lda] row-major. Bt: bf16 [Npad][K] (i.e. B transposed), Npad >= gridX*64.
// C: fp32 [M][N]. Optional bias+relu+column stats.
#define GBM 128
#define GBN 64
#define GBK 32

__global__ __launch_bounds__(256, 4) void gemm_mfma(
    const unsigned short* __restrict__ A, int lda,
    const unsigned short* __restrict__ Bt,
    float* __restrict__ C,
    const float* __restrict__ bias,
    float* __restrict__ colsum, float* __restrict__ colsq,
    int M, int N, int K, int do_relu)
{
    __shared__ __attribute__((aligned(16))) unsigned short Alds[GBM * GBK];
    __shared__ __attribute__((aligned(16))) unsigned short Blds[GBN * GBK];
    __shared__ float scol[GBN], sqcol[GBN];

    int tid = threadIdx.x;
    int wave = tid >> 6, lane = tid & 63;
    int row0 = blockIdx.y * GBM;
    int col0 = blockIdx.x * GBN;
    int m = lane & 15, q = lane >> 4;

    floatx4 acc[2][4] = {};

    for (int k0 = 0; k0 < K; k0 += GBK) {
        // stage A: 128 rows x 32 bf16 = 512 chunks of 16B; thread does 2
        #pragma unroll
        for (int i = 0; i < 2; ++i) {
            int c = tid + i * 256;
            int r = c >> 2, off = (c & 3) * 8;
            int gr = row0 + r;
            short8 v = {};
            if (gr < M) v = *(const short8*)(A + (size_t)gr * lda + k0 + off);
            *(short8*)(Alds + r * GBK + off) = v;
        }
        // stage Bt: 64 rows x 32 bf16 = 256 chunks of 16B; thread does 1
        {
            int r = tid >> 2, off = (tid & 3) * 8;
            short8 v = *(const short8*)(Bt + (size_t)(col0 + r) * K + k0 + off);
            *(short8*)(Blds + r * GBK + off) = v;
        }
        __syncthreads();

        short8 a0 = *(const short8*)(Alds + (wave * 32 + m) * GBK + q * 8);
        short8 a1 = *(const short8*)(Alds + (wave * 32 + 16 + m) * GBK + q * 8);
        #pragma unroll
        for (int ct = 0; ct < 4; ++ct) {
            short8 b = *(const short8*)(Blds + (ct * 16 + m) * GBK + q * 8);
            acc[0][ct] = __builtin_amdgcn_mfma_f32_16x16x32_bf16(a0, b, acc[0][ct], 0, 0, 0);
            acc[1][ct] = __builtin_amdgcn_mfma_f32_16x16x32_bf16(a1, b, acc[1][ct], 0, 0, 0);
        }
        __syncthreads();
    }

    // epilogue: bias + relu + store + column stats
    float ps[4] = {}, pq[4] = {};
    #pragma unroll
    for (int rt = 0; rt < 2; ++rt) {
        #pragma unroll
        for (int ct = 0; ct < 4; ++ct) {
            #pragma unroll
            for (int r = 0; r < 4; ++r) {
                int gr = row0 + wave * 32 + rt * 16 + q * 4 + r;
                int gc = col0 + ct * 16 + m;
                float v = acc[rt][ct][r];
                if (gc < N) {
                    if (bias != nullptr) v += bias[gc];
                    if (do_relu) v = fmaxf(v, 0.f);
                    if (gr < M) {
                        C[(size_t)gr * N + gc] = v;
                        ps[ct] += v; pq[ct] += v * v;
                    }
                }
            }
        }
    }
    if (colsum != nullptr) {
        if (tid < GBN) { scol[tid] = 0.f; sqcol[tid] = 0.f; }
        __syncthreads();
        #pragma unroll
        for (int ct = 0; ct < 4; ++ct) {
            atomicAdd(&scol[ct * 16 + m], ps[ct]);
            atomicAdd(&sqcol[ct * 16 + m], pq[ct]);
        }
        __syncthreads();
        if (tid < GBN) {
            int gc = col0 + tid;
            if (gc < N) {
                atomicAdd(&colsum[gc], scol[tid]);
                atomicAdd(&colsq[gc], sqcol[tid]);
            }
        }
    }
}

// ================= fp32 fallback GEMM (mlp1b only, N=2) =================
#define BM 64
#define BN 64
#define BK 16

__global__ __launch_bounds__(256, 2) void gemm_fused(
    const float* __restrict__ A, int lda,
    const float* __restrict__ A2, int lda2, int K1,
    const float* __restrict__ B,
    float* __restrict__ C,
    const float* __restrict__ bias,
    float* __restrict__ colsum, float* __restrict__ colsq,
    int M, int N, int K, int do_relu)
{
    __shared__ float As[BK][BM + 1];
    __shared__ float Bs[BK][BN + 1];
    __shared__ float red[16][BN];

    int tid = threadIdx.x;
    int tx = tid & 15, ty = tid >> 4;
    int row0 = blockIdx.y * BM;
    int col0 = blockIdx.x * BN;

    float acc[4][4] = {};

    for (int k0 = 0; k0 < K; k0 += BK) {
        #pragma unroll
        for (int i = 0; i < 4; ++i) {
            int t = tid + i * 256;
            int r  = t >> 4;
            int kk = t & 15;
            int gr = row0 + r, gk = k0 + kk;
            float v = 0.f;
            if (gr < M && gk < K) {
                if (gk < K1) v = A[(size_t)gr * lda + gk];
                else         v = A2[(size_t)gr * lda2 + (gk - K1)];
            }
            As[kk][r] = v;
        }
        #pragma unroll
        for (int i = 0; i < 4; ++i) {
            int t = tid + i * 256;
            int nn = t & 63;
            int kk = t >> 6;
            int gk = k0 + kk, gn = col0 + nn;
            Bs[kk][nn] = (gk < K && gn < N) ? B[(size_t)gk * N + gn] : 0.f;
        }
        __syncthreads();
        #pragma unroll
        for (int kk = 0; kk < BK; ++kk) {
            float a[4], b[4];
            #pragma unroll
            for (int r = 0; r < 4; ++r) a[r] = As[kk][ty * 4 + r];
            #pragma unroll
            for (int c = 0; c < 4; ++c) b[c] = Bs[kk][tx * 4 + c];
            #pragma unroll
            for (int r = 0; r < 4; ++r)
                #pragma unroll
                for (int c = 0; c < 4; ++c)
                    acc[r][c] += a[r] * b[c];
        }
        __syncthreads();
    }

    float vals[4][4];
    #pragma unroll
    for (int r = 0; r < 4; ++r) {
        int gr = row0 + ty * 4 + r;
        #pragma unroll
        for (int c = 0; c < 4; ++c) {
            int gc = col0 + tx * 4 + c;
            float v = acc[r][c];
            if (bias != nullptr && gc < N) v += bias[gc];
            if (do_relu) v = fmaxf(v, 0.f);
            bool ok = (gr < M) && (gc < N);
            vals[r][c] = ok ? v : 0.f;
            if (ok) C[(size_t)gr * N + gc] = v;
        }
    }

    if (colsum != nullptr) {
        float ps[4] = {}, pq[4] = {};
        #pragma unroll
        for (int r = 0; r < 4; ++r)
            #pragma unroll
            for (int c = 0; c < 4; ++c) {
                float v = vals[r][c];
                ps[c] += v; pq[c] += v * v;
            }
        #pragma unroll
        for (int c = 0; c < 4; ++c) red[ty][tx * 4 + c] = ps[c];
        __syncthreads();
        if (tid < 64) {
            float s = 0.f;
            #pragma unroll
            for (int t = 0; t < 16; ++t) s += red[t][tid];
            int gc = col0 + tid;
            if (gc < N) atomicAdd(&colsum[gc], s);
        }
        __syncthreads();
        #pragma unroll
        for (int c = 0; c < 4; ++c) red[ty][tx * 4 + c] = pq[c];
        __syncthreads();
        if (tid < 64) {
            float s = 0.f;
            #pragma unroll
            for (int t = 0; t < 16; ++t) s += red[t][tid];
            int gc = col0 + tid;
            if (gc < N) atomicAdd(&colsq[gc], s);
        }
    }
}

// ================= casts =================
__global__ void cast_x_k(const float* __restrict__ x, unsigned short* __restrict__ xb, int total4) {
    int i = blockIdx.x * blockDim.x + threadIdx.x;
    if (i >= total4) return;
    const float4 v = ((const float4*)x)[i];
    ushort4v o;
    o.x = f2bf(v.x); o.y = f2bf(v.y); o.z = f2bf(v.z); o.w = f2bf(v.w);
    ((ushort4v*)xb)[i] = o;
}

// W [K][N] fp32 -> Wt [Npad][K] bf16 (zero pad rows)
__global__ void cast_wt(const float* __restrict__ W, unsigned short* __restrict__ Wt, int K, int N) {
    int k = blockIdx.x * blockDim.x + threadIdx.x;
    int n = blockIdx.y;
    if (k >= K) return;
    Wt[(size_t)n * K + k] = (n < N) ? f2bf(W[(size_t)k * N + n]) : (unsigned short)0;
}

// ================= per-node attention dots =================
__global__ __launch_bounds__(256) void att_dots(
    const float* __restrict__ h,
    const float* __restrict__ att_src, const float* __restrict__ att_dst,
    float* __restrict__ a_src, float* __restrict__ a_dst,
    int Nn, int H, int Dd)
{
    int wave = (blockIdx.x * blockDim.x + threadIdx.x) >> 6;
    int lane = threadIdx.x & 63;
    if (wave >= Nn) return;
    const float* hr = h + (size_t)wave * H * Dd;
    for (int hh = 0; hh < H; ++hh) {
        float s = 0.f, d = 0.f;
        for (int j = lane; j < Dd; j += 64) {
            float v = hr[hh * Dd + j];
            s += v * att_src[hh * Dd + j];
            d += v * att_dst[hh * Dd + j];
        }
        #pragma unroll
        for (int off = 32; off > 0; off >>= 1) {
            s += __shfl_down(s, off);
            d += __shfl_down(d, off);
        }
        if (lane == 0) { a_src[wave * H + hh] = s; a_dst[wave * H + hh] = d; }
    }
}

__device__ __forceinline__ void edge_src_dst(const int* ei, int e, int& src, int& dst) {
    if (e < NEDGES) { src = ei[e]; dst = ei[NEDGES + e]; }
    else { src = e - NEDGES; dst = src; }
}

// ================= CSR build =================
__global__ __launch_bounds__(256) void csr_count(const int* __restrict__ ei, int* __restrict__ cnt) {
    int e = blockIdx.x * blockDim.x + threadIdx.x;
    if (e >= ETOT) return;
    int src, dst; edge_src_dst(ei, e, src, dst); (void)src;
    atomicAdd(&cnt[dst], 1);
}

__global__ __launch_bounds__(1024) void csr_scan(int* __restrict__ rowcnt, int* __restrict__ cursor) {
    __shared__ int buf[2][1024];
    const int T = 1024, CH = (NNODES + T - 1) / T;
    int t = threadIdx.x;
    int lo = t * CH, hi = min(lo + CH, NNODES);
    int local = 0;
    for (int i = lo; i < hi; ++i) local += rowcnt[i];
    buf[0][t] = local;
    __syncthreads();
    int cur = 0;
    for (int off = 1; off < T; off <<= 1) {
        int nxt = cur ^ 1;
        int v = buf[cur][t];
        if (t >= off) v += buf[cur][t - off];
        buf[nxt][t] = v;
        __syncthreads();
        cur = nxt;
    }
    int running = buf[cur][t] - local;
    for (int i = lo; i < hi; ++i) {
        int d = rowcnt[i];
        rowcnt[i] = running;
        cursor[i] = running;
        running += d;
    }
    if (t == 0) rowcnt[NNODES] = ETOT;
}

__global__ __launch_bounds__(256) void csr_fill(const int* __restrict__ ei,
                                                int* __restrict__ cursor,
                                                int* __restrict__ esrc) {
    int e = blockIdx.x * blockDim.x + threadIdx.x;
    if (e >= ETOT) return;
    int src, dst; edge_src_dst(ei, e, src, dst);
    int pos = atomicAdd(&cursor[dst], 1);
    esrc[pos] = src;
}

// ================= fused GAT aggregation (one wave per node) =================
// conv1 (H=2, D=128): writes bf16 into xcat[n][0..255]
__global__ __launch_bounds__(256) void gat_gather_h2(
    const int* __restrict__ rowstart, const int* __restrict__ esrc,
    const float* __restrict__ h, const float* __restrict__ a_src,
    const float* __restrict__ a_dst, const float* __restrict__ bias,
    unsigned short* __restrict__ xcat)
{
    int n = (blockIdx.x * blockDim.x + threadIdx.x) >> 6;
    int lane = threadIdx.x & 63;
    if (n >= NNODES) return;
    int beg = rowstart[n], end = rowstart[n + 1];
    float ad0 = a_dst[n * 2], ad1 = a_dst[n * 2 + 1];

    float m0 = -1e30f, m1 = -1e30f;
    for (int i = beg + lane; i < end; i += 64) {
        int s = esrc[i];
        float l0 = a_src[s * 2] + ad0;     l0 = l0 >= 0.f ? l0 : 0.2f * l0;
        float l1 = a_src[s * 2 + 1] + ad1; l1 = l1 >= 0.f ? l1 : 0.2f * l1;
        m0 = fmaxf(m0, l0); m1 = fmaxf(m1, l1);
    }
    #pragma unroll
    for (int off = 1; off < 64; off <<= 1) {
        m0 = fmaxf(m0, __shfl_xor(m0, off));
        m1 = fmaxf(m1, __shfl_xor(m1, off));
    }
    float s0 = 0.f, s1 = 0.f;
    for (int i = beg + lane; i < end; i += 64) {
        int s = esrc[i];
        float l0 = a_src[s * 2] + ad0;     l0 = l0 >= 0.f ? l0 : 0.2f * l0;
        float l1 = a_src[s * 2 + 1] + ad1; l1 = l1 >= 0.f ? l1 : 0.2f * l1;
        s0 += __expf(l0 - m0); s1 += __expf(l1 - m1);
    }
    #pragma unroll
    for (int off = 1; off < 64; off <<= 1) {
        s0 += __shfl_xor(s0, off);
        s1 += __shfl_xor(s1, off);
    }
    int head = lane >> 5;
    float mh   = head ? m1 : m0;
    float invh = head ? 1.f / (s1 + 1e-16f) : 1.f / (s0 + 1e-16f);
    float adh  = head ? ad1 : ad0;

    float4 acc = {0.f, 0.f, 0.f, 0.f};
    for (int i = beg; i < end; ++i) {
        int s = esrc[i];
        float l = a_src[s * 2 + head] + adh; l = l >= 0.f ? l : 0.2f * l;
        float w = __expf(l - mh) * invh;
        const float4 hv = *(const float4*)(h + (size_t)s * 256 + lane * 4);
        acc.x += w * hv.x; acc.y += w * hv.y; acc.z += w * hv.z; acc.w += w * hv.w;
    }
    const float4 b = *(const float4*)(bias + lane * 4);
    ushort4v o;
    o.x = f2bf(acc.x + b.x); o.y = f2bf(acc.y + b.y);
    o.z = f2bf(acc.z + b.z); o.w = f2bf(acc.w + b.w);
    *(ushort4v*)(xcat + (size_t)n * 384 + lane * 4) = o;
}

// conv2 (H=1, D=128): writes bf16 into xcat[n][256..383]
__global__ __launch_bounds__(256) void gat_gather_h1(
    const int* __restrict__ rowstart, const int* __restrict__ esrc,
    const float* __restrict__ h, const float* __restrict__ a_src,
    const float* __restrict__ a_dst, const float* __restrict__ bias,
    unsigned short* __restrict__ xcat)
{
    int n = (blockIdx.x * blockDim.x + threadIdx.x) >> 6;
    int lane = threadIdx.x & 63;
    if (n >= NNODES) return;
    int beg = rowstart[n], end = rowstart[n + 1];
    float ad0 = a_dst[n];

    float m0 = -1e30f;
    for (int i = beg + lane; i < end; i += 64) {
        int s = esrc[i];
        float l0 = a_src[s] + ad0; l0 = l0 >= 0.f ? l0 : 0.2f * l0;
        m0 = fmaxf(m0, l0);
    }
    #pragma unroll
    for (int off = 1; off < 64; off <<= 1) m0 = fmaxf(m0, __shfl_xor(m0, off));
    float s0 = 0.f;
    for (int i = beg + lane; i < end; i += 64) {
        int s = esrc[i];
        float l0 = a_src[s] + ad0; l0 = l0 >= 0.f ? l0 : 0.2f * l0;
        s0 += __expf(l0 - m0);
    }
    #pragma unroll
    for (int off = 1; off < 64; off <<= 1) s0 += __shfl_xor(s0, off);
    float inv0 = 1.f / (s0 + 1e-16f);

    float2 acc = {0.f, 0.f};
    for (int i = beg; i < end; ++i) {
        int s = esrc[i];
        float l = a_src[s] + ad0; l = l >= 0.f ? l : 0.2f * l;
        float w = __expf(l - m0) * inv0;
        const float2 hv = *(const float2*)(h + (size_t)s * 128 + lane * 2);
        acc.x += w * hv.x; acc.y += w * hv.y;
    }
    const float2 b = *(const float2*)(bias + lane * 2);
    ushort2v o;
    o.x = f2bf(acc.x + b.x); o.y = f2bf(acc.y + b.y);
    *(ushort2v*)(xcat + (size_t)n * 384 + 256 + lane * 2) = o;
}

// ================= BN helpers =================
__global__ void bn_finalize(const float* __restrict__ colsum, const float* __restrict__ colsq,
                            const float* __restrict__ gamma, const float* __restrict__ beta,
                            float* __restrict__ scale, float* __restrict__ shift,
                            int Ncols, float invM)
{
    int j = blockIdx.x * blockDim.x + threadIdx.x;
    if (j >= Ncols) return;
    float mu  = colsum[j] * invM;
    float var = colsq[j] * invM - mu * mu;
    if (var < 0.f) var = 0.f;
    float sc = gamma[j] * rsqrtf(var + 1e-5f);
    scale[j] = sc;
    shift[j] = beta[j] - mu * sc;
}

__global__ void bn_apply(float* __restrict__ y, const float* __restrict__ scale,
                         const float* __restrict__ shift, int total, int Ncols)
{
    int i = blockIdx.x * blockDim.x + threadIdx.x;
    if (i >= total) return;
    int j = i % Ncols;
    y[i] = y[i] * scale[j] + shift[j];
}

// BN apply producing bf16 (y1 -> y1b, feeds mlp1a)
__global__ void bn_apply_bf16(const float* __restrict__ y, const float* __restrict__ scale,
                              const float* __restrict__ shift, unsigned short* __restrict__ out,
                              int total, int Ncols)
{
    int i = blockIdx.x * blockDim.x + threadIdx.x;
    if (i >= total) return;
    int j = i % Ncols;
    out[i] = f2bf(y[i] * scale[j] + shift[j]);
}

extern "C" void kernel_launch(void* const* d_in, const int* in_sizes, int n_in,
                              void* d_out, int out_size, void* d_ws, size_t ws_size,
                              hipStream_t stream) {
    const float* x        = (const float*)d_in[0];
    const int*   ei       = (const int*)d_in[1];
    const float* W1       = (const float*)d_in[2];
    const float* att_src1 = (const float*)d_in[3];
    const float* att_dst1 = (const float*)d_in[4];
    const float* bias1    = (const float*)d_in[5];
    const float* W2       = (const float*)d_in[6];
    const float* att_src2 = (const float*)d_in[7];
    const float* att_dst2 = (const float*)d_in[8];
    const float* bias2    = (const float*)d_in[9];
    const float* Wl       = (const float*)d_in[10];
    const float* bl       = (const float*)d_in[11];
    const float* gl       = (const float*)d_in[12];
    const float* betal    = (const float*)d_in[13];
    const float* Wa       = (const float*)d_in[14];
    const float* ba       = (const float*)d_in[15];
    const float* ga       = (const float*)d_in[16];
    const float* betaa    = (const float*)d_in[17];
    const float* Wb       = (const float*)d_in[18];
    const float* bb       = (const float*)d_in[19];
    const float* gb       = (const float*)d_in[20];
    const float* betab    = (const float*)d_in[21];
    float* out = (float*)d_out;
    char* ws = (char*)d_ws;

    const int N = NNODES;

    // ---------- workspace layout (bytes) ----------
    const size_t offA    = 0;            // 51.2 MB: h1 -> h2 -> y1 -> y2 (fp32)
    const size_t offXcat = 51200000;     // 38.4 MB: xcat bf16 [50000][384] = [x1b | x2b]
    const size_t offXb   = 89600000;     // 12.8 MB: xb bf16 [50000][128]
    const size_t offY1b  = 102400000;    //  9.6 MB: y1b bf16 [50000][96]
    const size_t offW1t  = 112000000;    // 64 KB  : W1t bf16 [256][128]
    const size_t offW2t  = 112065536;    // 64 KB  : W2t bf16 [128][256]
    const size_t offWlt  = 112131072;    // 96 KB  : Wlt bf16 [128][384]
    const size_t offWat  = 112229376;    // 24 KB  : Wat bf16 [128][96]
    const size_t offRow  = 113000000;    // rowstart [N+1] ints
    const size_t offCur  = 113200128;    // cursor [N] ints
    const size_t offEsrc = 113400832;    // esrc [ETOT] ints
    const size_t offAs1  = 115600896;    // a_src1 [N*2] f32
    const size_t offAd1  = 116000896;    // a_dst1 [N*2]
    const size_t offAs2  = 116400896;    // a_src2 [N]
    const size_t offAd2  = 116600896;    // a_dst2 [N]
    const size_t offSt   = 116800896;    // stats: 12 x 512 B

    float* h1   = (float*)(ws + offA);
    float* h2   = (float*)(ws + offA);
    float* y1   = (float*)(ws + offA);
    float* y2   = (float*)(ws + offA);
    unsigned short* xcat = (unsigned short*)(ws + offXcat);
    unsigned short* xb   = (unsigned short*)(ws + offXb);
    unsigned short* y1b  = (unsigned short*)(ws + offY1b);
    unsigned short* W1t  = (unsigned short*)(ws + offW1t);
    unsigned short* W2t  = (unsigned short*)(ws + offW2t);
    unsigned short* Wlt  = (unsigned short*)(ws + offWlt);
    unsigned short* Wat  = (unsigned short*)(ws + offWat);
    int* rowst  = (int*)(ws + offRow);
    int* cursor = (int*)(ws + offCur);
    int* esrc   = (int*)(ws + offEsrc);
    float* as1  = (float*)(ws + offAs1);
    float* ad1  = (float*)(ws + offAd1);
    float* as2  = (float*)(ws + offAs2);
    float* ad2  = (float*)(ws + offAd2);

    float* csum_l = (float*)(ws + offSt + 0);
    float* csq_l  = (float*)(ws + offSt + 512);
    float* scl_l  = (float*)(ws + offSt + 1024);
    float* shf_l  = (float*)(ws + offSt + 1536);
    float* csum_a = (float*)(ws + offSt + 2048);
    float* csq_a  = (float*)(ws + offSt + 2560);
    float* scl_a  = (float*)(ws + offSt + 3072);
    float* shf_a  = (float*)(ws + offSt + 3584);
    float* csum_b = (float*)(ws + offSt + 4096);
    float* csq_b  = (float*)(ws + offSt + 4608);
    float* scl_b  = (float*)(ws + offSt + 5120);
    float* shf_b  = (float*)(ws + offSt + 5632);

    hipMemsetAsync(ws + offRow, 0, (NNODES + 1) * sizeof(int), stream);
    hipMemsetAsync(ws + offSt, 0, 6144, stream);

    dim3 blk(256);
    int edgeBlocks  = (ETOT + 255) / 256;
    int waveBlocksN = (N + 3) / 4;

    // ---- casts (weights tiny; x 12.8 MB) ----
    cast_x_k<<<(N * 128 / 4 + 255) / 256, blk, 0, stream>>>(x, xb, N * 128 / 4);
    cast_wt<<<dim3(1, 256), blk, 0, stream>>>(W1, W1t, 128, 256);
    cast_wt<<<dim3(1, 128), blk, 0, stream>>>(W2, W2t, 256, 128);
    cast_wt<<<dim3(2, 128), blk, 0, stream>>>(Wl, Wlt, 384, 96);
    cast_wt<<<dim3(1, 128), blk, 0, stream>>>(Wa, Wat, 96, 96);

    // ---- CSR build ----
    csr_count<<<edgeBlocks, blk, 0, stream>>>(ei, rowst);
    csr_scan<<<1, 1024, 0, stream>>>(rowst, cursor);
    csr_fill<<<edgeBlocks, blk, 0, stream>>>(ei, cursor, esrc);

    // ---- conv1: h1 = xb @ W1 ----
    gemm_mfma<<<dim3(4, (N + GBM - 1) / GBM), blk, 0, stream>>>(
        xb, 128, W1t, h1, nullptr, nullptr, nullptr, N, 256, 128, 0);
    att_dots<<<waveBlocksN, blk, 0, stream>>>(h1, att_src1, att_dst1, as1, ad1, N, 2, 128);
    gat_gather_h2<<<waveBlocksN, blk, 0, stream>>>(rowst, esrc, h1, as1, ad1, bias1, xcat);

    // ---- conv2: h2 = x1b @ W2 ----
    gemm_mfma<<<dim3(2, (N + GBM - 1) / GBM), blk, 0, stream>>>(
        xcat, 384, W2t, h2, nullptr, nullptr, nullptr, N, 128, 256, 0);
    att_dots<<<waveBlocksN, blk, 0, stream>>>(h2, att_src2, att_dst2, as2, ad2, N, 1, 128);
    gat_gather_h1<<<waveBlocksN, blk, 0, stream>>>(rowst, esrc, h2, as2, ad2, bias2, xcat);

    // ---- lin1: y1 = relu(xcat @ Wl + bl), stats ----
    gemm_mfma<<<dim3(2, (N + GBM - 1) / GBM), blk, 0, stream>>>(
        xcat, 384, Wlt, y1, bl, csum_l, csq_l, N, 96, 384, 1);
    bn_finalize<<<1, 128, 0, stream>>>(csum_l, csq_l, gl, betal, scl_l, shf_l, 96, 1.f / N);
    bn_apply_bf16<<<(N * 96 + 255) / 256, blk, 0, stream>>>(y1, scl_l, shf_l, y1b, N * 96, 96);

    // ---- mlp1 layer 1: y2 = relu(y1b @ Wa + ba), stats ----
    gemm_mfma<<<dim3(2, (N + GBM - 1) / GBM), blk, 0, stream>>>(
        y1b, 96, Wat, y2, ba, csum_a, csq_a, N, 96, 96, 1);
    bn_finalize<<<1, 128, 0, stream>>>(csum_a, csq_a, ga, betaa, scl_a, shf_a, 96, 1.f / N);
    bn_apply<<<(N * 96 + 255) / 256, blk, 0, stream>>>(y2, scl_a, shf_a, N * 96, 96);

    // ---- mlp1 layer 2 (fp32, N=2, writes d_out) ----
    gemm_fused<<<dim3(1, (N + BM - 1) / BM), blk, 0, stream>>>(
        y2, 96, nullptr, 0, 96, Wb, out, bb, csum_b, csq_b, N, 2, 96, 1);
    bn_finalize<<<1, 64, 0, stream>>>(csum_b, csq_b, gb, betab, scl_b, shf_b, 2, 1.f / N);
    bn_apply<<<(N * 2 + 255) / 256, blk, 0, stream>>>(out, scl_b, shf_b, N * 2, 2);
}

// Round 4
// 532.726 us; speedup vs baseline: 2.9665x; 1.1798x over previous
//
#include <hip/hip_runtime.h>
#include <hip/hip_bf16.h>
#include <cstdint>
#include <cstddef>

#define NNODES 50000
#define NEDGES 500000
#define ETOT   (NEDGES + NNODES)

typedef __attribute__((ext_vector_type(8))) short short8;
typedef __attribute__((ext_vector_type(4))) float floatx4;
typedef __attribute__((ext_vector_type(4))) unsigned short ushort4v;
typedef __attribute__((ext_vector_type(2))) unsigned short ushort2v;

__device__ __forceinline__ unsigned short f2bf(float f) {
    union { __hip_bfloat16 h; unsigned short u; } cv;
    cv.h = __float2bfloat16(f);
    return cv.u;
}

// ================= bf16 MFMA GEMM: C = op(A @ Bt^T + bias) =================
#define GBM 128
#define GBN 64
#define GBK 32

__global__ __launch_bounds__(256, 4) void gemm_mfma(
    const unsigned short* __restrict__ A, int lda,
    const unsigned short* __restrict__ Bt,
    float* __restrict__ C,
    const float* __restrict__ bias,
    float* __restrict__ colsum, float* __restrict__ colsq,
    int M, int N, int K, int do_relu)
{
    __shared__ __attribute__((aligned(16))) unsigned short Alds[GBM * GBK];
    __shared__ __attribute__((aligned(16))) unsigned short Blds[GBN * GBK];
    __shared__ float scol[GBN], sqcol[GBN];

    int tid = threadIdx.x;
    int wave = tid >> 6, lane = tid & 63;
    int row0 = blockIdx.y * GBM;
    int col0 = blockIdx.x * GBN;
    int m = lane & 15, q = lane >> 4;

    floatx4 acc[2][4] = {};

    for (int k0 = 0; k0 < K; k0 += GBK) {
        #pragma unroll
        for (int i = 0; i < 2; ++i) {
            int c = tid + i * 256;
            int r = c >> 2, off = (c & 3) * 8;
            int gr = row0 + r;
            short8 v = {};
            if (gr < M) v = *(const short8*)(A + (size_t)gr * lda + k0 + off);
            *(short8*)(Alds + r * GBK + off) = v;
        }
        {
            int r = tid >> 2, off = (tid & 3) * 8;
            short8 v = *(const short8*)(Bt + (size_t)(col0 + r) * K + k0 + off);
            *(short8*)(Blds + r * GBK + off) = v;
        }
        __syncthreads();

        short8 a0 = *(const short8*)(Alds + (wave * 32 + m) * GBK + q * 8);
        short8 a1 = *(const short8*)(Alds + (wave * 32 + 16 + m) * GBK + q * 8);
        #pragma unroll
        for (int ct = 0; ct < 4; ++ct) {
            short8 b = *(const short8*)(Blds + (ct * 16 + m) * GBK + q * 8);
            acc[0][ct] = __builtin_amdgcn_mfma_f32_16x16x32_bf16(a0, b, acc[0][ct], 0, 0, 0);
            acc[1][ct] = __builtin_amdgcn_mfma_f32_16x16x32_bf16(a1, b, acc[1][ct], 0, 0, 0);
        }
        __syncthreads();
    }

    float ps[4] = {}, pq[4] = {};
    #pragma unroll
    for (int rt = 0; rt < 2; ++rt) {
        #pragma unroll
        for (int ct = 0; ct < 4; ++ct) {
            #pragma unroll
            for (int r = 0; r < 4; ++r) {
                int gr = row0 + wave * 32 + rt * 16 + q * 4 + r;
                int gc = col0 + ct * 16 + m;
                float v = acc[rt][ct][r];
                if (gc < N) {
                    if (bias != nullptr) v += bias[gc];
                    if (do_relu) v = fmaxf(v, 0.f);
                    if (gr < M) {
                        C[(size_t)gr * N + gc] = v;
                        ps[ct] += v; pq[ct] += v * v;
                    }
                }
            }
        }
    }
    if (colsum != nullptr) {
        if (tid < GBN) { scol[tid] = 0.f; sqcol[tid] = 0.f; }
        __syncthreads();
        #pragma unroll
        for (int ct = 0; ct < 4; ++ct) {
            atomicAdd(&scol[ct * 16 + m], ps[ct]);
            atomicAdd(&sqcol[ct * 16 + m], pq[ct]);
        }
        __syncthreads();
        if (tid < GBN) {
            int gc = col0 + tid;
            if (gc < N) {
                atomicAdd(&colsum[gc], scol[tid]);
                atomicAdd(&colsq[gc], sqcol[tid]);
            }
        }
    }
}

// ================= fp32 fallback GEMM (mlp1b only, N=2) =================
#define BM 64
#define BN 64
#define BK 16

__global__ __launch_bounds__(256, 2) void gemm_fused(
    const float* __restrict__ A, int lda,
    const float* __restrict__ A2, int lda2, int K1,
    const float* __restrict__ B,
    float* __restrict__ C,
    const float* __restrict__ bias,
    float* __restrict__ colsum, float* __restrict__ colsq,
    int M, int N, int K, int do_relu)
{
    __shared__ float As[BK][BM + 1];
    __shared__ float Bs[BK][BN + 1];
    __shared__ float red[16][BN];

    int tid = threadIdx.x;
    int tx = tid & 15, ty = tid >> 4;
    int row0 = blockIdx.y * BM;
    int col0 = blockIdx.x * BN;

    float acc[4][4] = {};

    for (int k0 = 0; k0 < K; k0 += BK) {
        #pragma unroll
        for (int i = 0; i < 4; ++i) {
            int t = tid + i * 256;
            int r  = t >> 4;
            int kk = t & 15;
            int gr = row0 + r, gk = k0 + kk;
            float v = 0.f;
            if (gr < M && gk < K) {
                if (gk < K1) v = A[(size_t)gr * lda + gk];
                else         v = A2[(size_t)gr * lda2 + (gk - K1)];
            }
            As[kk][r] = v;
        }
        #pragma unroll
        for (int i = 0; i < 4; ++i) {
            int t = tid + i * 256;
            int nn = t & 63;
            int kk = t >> 6;
            int gk = k0 + kk, gn = col0 + nn;
            Bs[kk][nn] = (gk < K && gn < N) ? B[(size_t)gk * N + gn] : 0.f;
        }
        __syncthreads();
        #pragma unroll
        for (int kk = 0; kk < BK; ++kk) {
            float a[4], b[4];
            #pragma unroll
            for (int r = 0; r < 4; ++r) a[r] = As[kk][ty * 4 + r];
            #pragma unroll
            for (int c = 0; c < 4; ++c) b[c] = Bs[kk][tx * 4 + c];
            #pragma unroll
            for (int r = 0; r < 4; ++r)
                #pragma unroll
                for (int c = 0; c < 4; ++c)
                    acc[r][c] += a[r] * b[c];
        }
        __syncthreads();
    }

    float vals[4][4];
    #pragma unroll
    for (int r = 0; r < 4; ++r) {
        int gr = row0 + ty * 4 + r;
        #pragma unroll
        for (int c = 0; c < 4; ++c) {
            int gc = col0 + tx * 4 + c;
            float v = acc[r][c];
            if (bias != nullptr && gc < N) v += bias[gc];
            if (do_relu) v = fmaxf(v, 0.f);
            bool ok = (gr < M) && (gc < N);
            vals[r][c] = ok ? v : 0.f;
            if (ok) C[(size_t)gr * N + gc] = v;
        }
    }

    if (colsum != nullptr) {
        float ps[4] = {}, pq[4] = {};
        #pragma unroll
        for (int r = 0; r < 4; ++r)
            #pragma unroll
            for (int c = 0; c < 4; ++c) {
                float v = vals[r][c];
                ps[c] += v; pq[c] += v * v;
            }
        #pragma unroll
        for (int c = 0; c < 4; ++c) red[ty][tx * 4 + c] = ps[c];
        __syncthreads();
        if (tid < 64) {
            float s = 0.f;
            #pragma unroll
            for (int t = 0; t < 16; ++t) s += red[t][tid];
            int gc = col0 + tid;
            if (gc < N) atomicAdd(&colsum[gc], s);
        }
        __syncthreads();
        #pragma unroll
        for (int c = 0; c < 4; ++c) red[ty][tx * 4 + c] = pq[c];
        __syncthreads();
        if (tid < 64) {
            float s = 0.f;
            #pragma unroll
            for (int t = 0; t < 16; ++t) s += red[t][tid];
            int gc = col0 + tid;
            if (gc < N) atomicAdd(&colsq[gc], s);
        }
    }
}

// ================= casts =================
__global__ void cast_x_k(const float* __restrict__ x, unsigned short* __restrict__ xb, int total4) {
    int i = blockIdx.x * blockDim.x + threadIdx.x;
    if (i >= total4) return;
    const float4 v = ((const float4*)x)[i];
    ushort4v o;
    o.x = f2bf(v.x); o.y = f2bf(v.y); o.z = f2bf(v.z); o.w = f2bf(v.w);
    ((ushort4v*)xb)[i] = o;
}

__global__ void cast_wt(const float* __restrict__ W, unsigned short* __restrict__ Wt, int K, int N) {
    int k = blockIdx.x * blockDim.x + threadIdx.x;
    int n = blockIdx.y;
    if (k >= K) return;
    Wt[(size_t)n * K + k] = (n < N) ? f2bf(W[(size_t)k * N + n]) : (unsigned short)0;
}

// ================= per-node attention dots =================
__global__ __launch_bounds__(256) void att_dots(
    const float* __restrict__ h,
    const float* __restrict__ att_src, const float* __restrict__ att_dst,
    float* __restrict__ a_src, float* __restrict__ a_dst,
    int Nn, int H, int Dd)
{
    int wave = (blockIdx.x * blockDim.x + threadIdx.x) >> 6;
    int lane = threadIdx.x & 63;
    if (wave >= Nn) return;
    const float* hr = h + (size_t)wave * H * Dd;
    for (int hh = 0; hh < H; ++hh) {
        float s = 0.f, d = 0.f;
        for (int j = lane; j < Dd; j += 64) {
            float v = hr[hh * Dd + j];
            s += v * att_src[hh * Dd + j];
            d += v * att_dst[hh * Dd + j];
        }
        #pragma unroll
        for (int off = 32; off > 0; off >>= 1) {
            s += __shfl_down(s, off);
            d += __shfl_down(d, off);
        }
        if (lane == 0) { a_src[wave * H + hh] = s; a_dst[wave * H + hh] = d; }
    }
}

__device__ __forceinline__ void edge_src_dst(const int* ei, int e, int& src, int& dst) {
    if (e < NEDGES) { src = ei[e]; dst = ei[NEDGES + e]; }
    else { src = e - NEDGES; dst = src; }
}

// ================= CSR build =================
__global__ __launch_bounds__(256) void csr_count(const int* __restrict__ ei, int* __restrict__ cnt) {
    int e = blockIdx.x * blockDim.x + threadIdx.x;
    if (e >= ETOT) return;
    int src, dst; edge_src_dst(ei, e, src, dst); (void)src;
    atomicAdd(&cnt[dst], 1);
}

// -------- 3-phase hierarchical exclusive scan of cnt[0..N) --------
#define SCAN_CH 1024
#define SCAN_NB ((NNODES + SCAN_CH - 1) / SCAN_CH)   // 49

__global__ __launch_bounds__(256) void scan1(const int* __restrict__ cnt, int* __restrict__ part) {
    int t = threadIdx.x;
    int base = blockIdx.x * SCAN_CH + t * 4;
    int4 v = {0, 0, 0, 0};
    if (base + 3 < NNODES) v = *(const int4*)(cnt + base);
    else {
        if (base + 0 < NNODES) v.x = cnt[base + 0];
        if (base + 1 < NNODES) v.y = cnt[base + 1];
        if (base + 2 < NNODES) v.z = cnt[base + 2];
        if (base + 3 < NNODES) v.w = cnt[base + 3];
    }
    int s = v.x + v.y + v.z + v.w;
    __shared__ int sm[256];
    sm[t] = s;
    __syncthreads();
    for (int off = 128; off > 0; off >>= 1) {
        if (t < off) sm[t] += sm[t + off];
        __syncthreads();
    }
    if (t == 0) part[blockIdx.x] = sm[0];
}

__global__ void scan2(int* __restrict__ part, int* __restrict__ rowstart) {
    int lane = threadIdx.x;                  // one wave of 64, SCAN_NB <= 64
    int v = (lane < SCAN_NB) ? part[lane] : 0;
    #pragma unroll
    for (int off = 1; off < 64; off <<= 1) {
        int t = __shfl_up(v, off);
        if (lane >= off) v += t;
    }
    int ex = __shfl_up(v, 1);
    if (lane == 0) ex = 0;
    if (lane < SCAN_NB) part[lane] = ex;
    if (lane == 0) rowstart[NNODES] = ETOT;
}

__global__ __launch_bounds__(256) void scan3(const int* __restrict__ cnt, const int* __restrict__ part,
                                             int* __restrict__ rowstart, int* __restrict__ cursor) {
    int t = threadIdx.x;
    int base = blockIdx.x * SCAN_CH + t * 4;
    int4 v = {0, 0, 0, 0};
    if (base + 3 < NNODES) v = *(const int4*)(cnt + base);
    else {
        if (base + 0 < NNODES) v.x = cnt[base + 0];
        if (base + 1 < NNODES) v.y = cnt[base + 1];
        if (base + 2 < NNODES) v.z = cnt[base + 2];
        if (base + 3 < NNODES) v.w = cnt[base + 3];
    }
    int s = v.x + v.y + v.z + v.w;
    __shared__ int sm[2][256];
    sm[0][t] = s;
    __syncthreads();
    int cur = 0;
    #pragma unroll
    for (int off = 1; off < 256; off <<= 1) {
        int nxt = cur ^ 1;
        int val = sm[cur][t];
        if (t >= off) val += sm[cur][t - off];
        sm[nxt][t] = val;
        __syncthreads();
        cur = nxt;
    }
    int p = sm[cur][t] - s + part[blockIdx.x];   // exclusive prefix for this thread's chunk
    if (base + 0 < NNODES) { rowstart[base + 0] = p; cursor[base + 0] = p; } p += v.x;
    if (base + 1 < NNODES) { rowstart[base + 1] = p; cursor[base + 1] = p; } p += v.y;
    if (base + 2 < NNODES) { rowstart[base + 2] = p; cursor[base + 2] = p; } p += v.z;
    if (base + 3 < NNODES) { rowstart[base + 3] = p; cursor[base + 3] = p; }
}

__global__ __launch_bounds__(256) void csr_fill(const int* __restrict__ ei,
                                                int* __restrict__ cursor,
                                                int* __restrict__ esrc) {
    int e = blockIdx.x * blockDim.x + threadIdx.x;
    if (e >= ETOT) return;
    int src, dst; edge_src_dst(ei, e, src, dst);
    int pos = atomicAdd(&cursor[dst], 1);
    esrc[pos] = src;
}

// ================= fused GAT aggregation (one wave per node) =================
__global__ __launch_bounds__(256) void gat_gather_h2(
    const int* __restrict__ rowstart, const int* __restrict__ esrc,
    const float* __restrict__ h, const float* __restrict__ a_src,
    const float* __restrict__ a_dst, const float* __restrict__ bias,
    unsigned short* __restrict__ xcat)
{
    int n = (blockIdx.x * blockDim.x + threadIdx.x) >> 6;
    int lane = threadIdx.x & 63;
    if (n >= NNODES) return;
    int beg = rowstart[n], end = rowstart[n + 1];
    float ad0 = a_dst[n * 2], ad1 = a_dst[n * 2 + 1];

    float m0 = -1e30f, m1 = -1e30f;
    for (int i = beg + lane; i < end; i += 64) {
        int s = esrc[i];
        float l0 = a_src[s * 2] + ad0;     l0 = l0 >= 0.f ? l0 : 0.2f * l0;
        float l1 = a_src[s * 2 + 1] + ad1; l1 = l1 >= 0.f ? l1 : 0.2f * l1;
        m0 = fmaxf(m0, l0); m1 = fmaxf(m1, l1);
    }
    #pragma unroll
    for (int off = 1; off < 64; off <<= 1) {
        m0 = fmaxf(m0, __shfl_xor(m0, off));
        m1 = fmaxf(m1, __shfl_xor(m1, off));
    }
    float s0 = 0.f, s1 = 0.f;
    for (int i = beg + lane; i < end; i += 64) {
        int s = esrc[i];
        float l0 = a_src[s * 2] + ad0;     l0 = l0 >= 0.f ? l0 : 0.2f * l0;
        float l1 = a_src[s * 2 + 1] + ad1; l1 = l1 >= 0.f ? l1 : 0.2f * l1;
        s0 += __expf(l0 - m0); s1 += __expf(l1 - m1);
    }
    #pragma unroll
    for (int off = 1; off < 64; off <<= 1) {
        s0 += __shfl_xor(s0, off);
        s1 += __shfl_xor(s1, off);
    }
    int head = lane >> 5;
    float mh   = head ? m1 : m0;
    float invh = head ? 1.f / (s1 + 1e-16f) : 1.f / (s0 + 1e-16f);
    float adh  = head ? ad1 : ad0;

    float4 acc = {0.f, 0.f, 0.f, 0.f};
    for (int i = beg; i < end; ++i) {
        int s = esrc[i];
        float l = a_src[s * 2 + head] + adh; l = l >= 0.f ? l : 0.2f * l;
        float w = __expf(l - mh) * invh;
        const float4 hv = *(const float4*)(h + (size_t)s * 256 + lane * 4);
        acc.x += w * hv.x; acc.y += w * hv.y; acc.z += w * hv.z; acc.w += w * hv.w;
    }
    const float4 b = *(const float4*)(bias + lane * 4);
    ushort4v o;
    o.x = f2bf(acc.x + b.x); o.y = f2bf(acc.y + b.y);
    o.z = f2bf(acc.z + b.z); o.w = f2bf(acc.w + b.w);
    *(ushort4v*)(xcat + (size_t)n * 384 + lane * 4) = o;
}

__global__ __launch_bounds__(256) void gat_gather_h1(
    const int* __restrict__ rowstart, const int* __restrict__ esrc,
    const float* __restrict__ h, const float* __restrict__ a_src,
    const float* __restrict__ a_dst, const float* __restrict__ bias,
    unsigned short* __restrict__ xcat)
{
    int n = (blockIdx.x * blockDim.x + threadIdx.x) >> 6;
    int lane = threadIdx.x & 63;
    if (n >= NNODES) return;
    int beg = rowstart[n], end = rowstart[n + 1];
    float ad0 = a_dst[n];

    float m0 = -1e30f;
    for (int i = beg + lane; i < end; i += 64) {
        int s = esrc[i];
        float l0 = a_src[s] + ad0; l0 = l0 >= 0.f ? l0 : 0.2f * l0;
        m0 = fmaxf(m0, l0);
    }
    #pragma unroll
    for (int off = 1; off < 64; off <<= 1) m0 = fmaxf(m0, __shfl_xor(m0, off));
    float s0 = 0.f;
    for (int i = beg + lane; i < end; i += 64) {
        int s = esrc[i];
        float l0 = a_src[s] + ad0; l0 = l0 >= 0.f ? l0 : 0.2f * l0;
        s0 += __expf(l0 - m0);
    }
    #pragma unroll
    for (int off = 1; off < 64; off <<= 1) s0 += __shfl_xor(s0, off);
    float inv0 = 1.f / (s0 + 1e-16f);

    float2 acc = {0.f, 0.f};
    for (int i = beg; i < end; ++i) {
        int s = esrc[i];
        float l = a_src[s] + ad0; l = l >= 0.f ? l : 0.2f * l;
        float w = __expf(l - m0) * inv0;
        const float2 hv = *(const float2*)(h + (size_t)s * 128 + lane * 2);
        acc.x += w * hv.x; acc.y += w * hv.y;
    }
    const float2 b = *(const float2*)(bias + lane * 2);
    ushort2v o;
    o.x = f2bf(acc.x + b.x); o.y = f2bf(acc.y + b.y);
    *(ushort2v*)(xcat + (size_t)n * 384 + 256 + lane * 2) = o;
}

// ================= BN helpers =================
__global__ void bn_finalize(const float* __restrict__ colsum, const float* __restrict__ colsq,
                            const float* __restrict__ gamma, const float* __restrict__ beta,
                            float* __restrict__ scale, float* __restrict__ shift,
                            int Ncols, float invM)
{
    int j = blockIdx.x * blockDim.x + threadIdx.x;
    if (j >= Ncols) return;
    float mu  = colsum[j] * invM;
    float var = colsq[j] * invM - mu * mu;
    if (var < 0.f) var = 0.f;
    float sc = gamma[j] * rsqrtf(var + 1e-5f);
    scale[j] = sc;
    shift[j] = beta[j] - mu * sc;
}

__global__ void bn_apply(float* __restrict__ y, const float* __restrict__ scale,
                         const float* __restrict__ shift, int total, int Ncols)
{
    int i = blockIdx.x * blockDim.x + threadIdx.x;
    if (i >= total) return;
    int j = i % Ncols;
    y[i] = y[i] * scale[j] + shift[j];
}

__global__ void bn_apply_bf16(const float* __restrict__ y, const float* __restrict__ scale,
                              const float* __restrict__ shift, unsigned short* __restrict__ out,
                              int total, int Ncols)
{
    int i = blockIdx.x * blockDim.x + threadIdx.x;
    if (i >= total) return;
    int j = i % Ncols;
    out[i] = f2bf(y[i] * scale[j] + shift[j]);
}

extern "C" void kernel_launch(void* const* d_in, const int* in_sizes, int n_in,
                              void* d_out, int out_size, void* d_ws, size_t ws_size,
                              hipStream_t stream) {
    const float* x        = (const float*)d_in[0];
    const int*   ei       = (const int*)d_in[1];
    const float* W1       = (const float*)d_in[2];
    const float* att_src1 = (const float*)d_in[3];
    const float* att_dst1 = (const float*)d_in[4];
    const float* bias1    = (const float*)d_in[5];
    const float* W2       = (const float*)d_in[6];
    const float* att_src2 = (const float*)d_in[7];
    const float* att_dst2 = (const float*)d_in[8];
    const float* bias2    = (const float*)d_in[9];
    const float* Wl       = (const float*)d_in[10];
    const float* bl       = (const float*)d_in[11];
    const float* gl       = (const float*)d_in[12];
    const float* betal    = (const float*)d_in[13];
    const float* Wa       = (const float*)d_in[14];
    const float* ba       = (const float*)d_in[15];
    const float* ga       = (const float*)d_in[16];
    const float* betaa    = (const float*)d_in[17];
    const float* Wb       = (const float*)d_in[18];
    const float* bb       = (const float*)d_in[19];
    const float* gb       = (const float*)d_in[20];
    const float* betab    = (const float*)d_in[21];
    float* out = (float*)d_out;
    char* ws = (char*)d_ws;

    const int N = NNODES;

    // ---------- workspace layout (bytes) ----------
    const size_t offA    = 0;            // 51.2 MB: h1 -> h2 -> y1 -> y2 (fp32)
    const size_t offXcat = 51200000;     // 38.4 MB: xcat bf16 [50000][384]
    const size_t offXb   = 89600000;     // 12.8 MB: xb bf16 [50000][128]
    const size_t offY1b  = 102400000;    //  9.6 MB: y1b bf16 [50000][96]
    const size_t offW1t  = 112000000;
    const size_t offW2t  = 112065536;
    const size_t offWlt  = 112131072;
    const size_t offWat  = 112229376;
    const size_t offRow  = 113000000;    // cnt -> rowstart [N+1] ints
    const size_t offCur  = 113200128;    // cursor [N] ints
    const size_t offEsrc = 113400832;    // esrc [ETOT] ints
    const size_t offPart = 115600896;    // scan partials [64] ints
    const size_t offAs1  = 115601408;    // a_src1 [N*2] f32
    const size_t offAd1  = 116001408;
    const size_t offAs2  = 116401408;
    const size_t offAd2  = 116601408;
    const size_t offSt   = 116801408;    // stats: 12 x 512 B

    float* h1   = (float*)(ws + offA);
    float* h2   = (float*)(ws + offA);
    float* y1   = (float*)(ws + offA);
    float* y2   = (float*)(ws + offA);
    unsigned short* xcat = (unsigned short*)(ws + offXcat);
    unsigned short* xb   = (unsigned short*)(ws + offXb);
    unsigned short* y1b  = (unsigned short*)(ws + offY1b);
    unsigned short* W1t  = (unsigned short*)(ws + offW1t);
    unsigned short* W2t  = (unsigned short*)(ws + offW2t);
    unsigned short* Wlt  = (unsigned short*)(ws + offWlt);
    unsigned short* Wat  = (unsigned short*)(ws + offWat);
    int* rowst  = (int*)(ws + offRow);
    int* cursor = (int*)(ws + offCur);
    int* esrc   = (int*)(ws + offEsrc);
    int* part   = (int*)(ws + offPart);
    float* as1  = (float*)(ws + offAs1);
    float* ad1  = (float*)(ws + offAd1);
    float* as2  = (float*)(ws + offAs2);
    float* ad2  = (float*)(ws + offAd2);

    float* csum_l = (float*)(ws + offSt + 0);
    float* csq_l  = (float*)(ws + offSt + 512);
    float* scl_l  = (float*)(ws + offSt + 1024);
    float* shf_l  = (float*)(ws + offSt + 1536);
    float* csum_a = (float*)(ws + offSt + 2048);
    float* csq_a  = (float*)(ws + offSt + 2560);
    float* scl_a  = (float*)(ws + offSt + 3072);
    float* shf_a  = (float*)(ws + offSt + 3584);
    float* csum_b = (float*)(ws + offSt + 4096);
    float* csq_b  = (float*)(ws + offSt + 4608);
    float* scl_b  = (float*)(ws + offSt + 5120);
    float* shf_b  = (float*)(ws + offSt + 5632);

    hipMemsetAsync(ws + offRow, 0, (NNODES + 1) * sizeof(int), stream);
    hipMemsetAsync(ws + offSt, 0, 6144, stream);

    dim3 blk(256);
    int edgeBlocks  = (ETOT + 255) / 256;
    int waveBlocksN = (N + 3) / 4;

    // ---- casts ----
    cast_x_k<<<(N * 128 / 4 + 255) / 256, blk, 0, stream>>>(x, xb, N * 128 / 4);
    cast_wt<<<dim3(1, 256), blk, 0, stream>>>(W1, W1t, 128, 256);
    cast_wt<<<dim3(1, 128), blk, 0, stream>>>(W2, W2t, 256, 128);
    cast_wt<<<dim3(2, 128), blk, 0, stream>>>(Wl, Wlt, 384, 96);
    cast_wt<<<dim3(1, 128), blk, 0, stream>>>(Wa, Wat, 96, 96);

    // ---- CSR build: count -> 3-phase scan -> fill ----
    csr_count<<<edgeBlocks, blk, 0, stream>>>(ei, rowst);
    scan1<<<SCAN_NB, blk, 0, stream>>>(rowst, part);
    scan2<<<1, 64, 0, stream>>>(part, rowst);
    scan3<<<SCAN_NB, blk, 0, stream>>>(rowst, part, rowst, cursor);
    csr_fill<<<edgeBlocks, blk, 0, stream>>>(ei, cursor, esrc);

    // ---- conv1 ----
    gemm_mfma<<<dim3(4, (N + GBM - 1) / GBM), blk, 0, stream>>>(
        xb, 128, W1t, h1, nullptr, nullptr, nullptr, N, 256, 128, 0);
    att_dots<<<waveBlocksN, blk, 0, stream>>>(h1, att_src1, att_dst1, as1, ad1, N, 2, 128);
    gat_gather_h2<<<waveBlocksN, blk, 0, stream>>>(rowst, esrc, h1, as1, ad1, bias1, xcat);

    // ---- conv2 ----
    gemm_mfma<<<dim3(2, (N + GBM - 1) / GBM), blk, 0, stream>>>(
        xcat, 384, W2t, h2, nullptr, nullptr, nullptr, N, 128, 256, 0);
    att_dots<<<waveBlocksN, blk, 0, stream>>>(h2, att_src2, att_dst2, as2, ad2, N, 1, 128);
    gat_gather_h1<<<waveBlocksN, blk, 0, stream>>>(rowst, esrc, h2, as2, ad2, bias2, xcat);

    // ---- lin1 ----
    gemm_mfma<<<dim3(2, (N + GBM - 1) / GBM), blk, 0, stream>>>(
        xcat, 384, Wlt, y1, bl, csum_l, csq_l, N, 96, 384, 1);
    bn_finalize<<<1, 128, 0, stream>>>(csum_l, csq_l, gl, betal, scl_l, shf_l, 96, 1.f / N);
    bn_apply_bf16<<<(N * 96 + 255) / 256, blk, 0, stream>>>(y1, scl_l, shf_l, y1b, N * 96, 96);

    // ---- mlp1 layer 1 ----
    gemm_mfma<<<dim3(2, (N + GBM - 1) / GBM), blk, 0, stream>>>(
        y1b, 96, Wat, y2, ba, csum_a, csq_a, N, 96, 96, 1);
    bn_finalize<<<1, 128, 0, stream>>>(csum_a, csq_a, ga, betaa, scl_a, shf_a, 96, 1.f / N);
    bn_apply<<<(N * 96 + 255) / 256, blk, 0, stream>>>(y2, scl_a, shf_a, N * 96, 96);

    // ---- mlp1 layer 2 (fp32, N=2, writes d_out) ----
    gemm_fused<<<dim3(1, (N + BM - 1) / BM), blk, 0, stream>>>(
        y2, 96, nullptr, 0, 96, Wb, out, bb, csum_b, csq_b, N, 2, 96, 1);
    bn_finalize<<<1, 64, 0, stream>>>(csum_b, csq_b, gb, betab, scl_b, shf_b, 2, 1.f / N);
    bn_apply<<<(N * 2 + 255) / 256, blk, 0, stream>>>(out, scl_b, shf_b, N * 2, 2);
}

// Round 5
// 505.407 us; speedup vs baseline: 3.1268x; 1.0541x over previous
//
#include <hip/hip_runtime.h>
#include <hip/hip_bf16.h>
#include <cstdint>
#include <cstddef>

#define NNODES 50000
#define NEDGES 500000
#define ETOT   (NEDGES + NNODES)

typedef __attribute__((ext_vector_type(8))) short short8;
typedef __attribute__((ext_vector_type(4))) float floatx4;
typedef __attribute__((ext_vector_type(4))) unsigned short ushort4v;
typedef __attribute__((ext_vector_type(2))) unsigned short ushort2v;

__device__ __forceinline__ unsigned short f2bf(float f) {
    union { __hip_bfloat16 h; unsigned short u; } cv;
    cv.h = __float2bfloat16(f);
    return cv.u;
}
__device__ __forceinline__ float bf2f(unsigned short u) {
    union { unsigned int i; float f; } cv;
    cv.i = ((unsigned int)u) << 16;
    return cv.f;
}

// ================= bf16 MFMA GEMM: C/Cb = op(A @ Bt^T + bias) =================
// Optional fused epilogues: bf16 output (Cb), per-row attention dots
// (as_out/ad_out += row . att_s/att_d, head = col-block >> 7), column stats.
#define GBM 128
#define GBN 64
#define GBK 32

__global__ __launch_bounds__(256, 4) void gemm_mfma(
    const unsigned short* __restrict__ A, int lda,
    const unsigned short* __restrict__ Bt,
    float* __restrict__ C,
    unsigned short* __restrict__ Cb,
    const float* __restrict__ bias,
    float* __restrict__ colsum, float* __restrict__ colsq,
    const float* __restrict__ att_s, const float* __restrict__ att_d,
    float* __restrict__ as_out, float* __restrict__ ad_out, int Hheads,
    int M, int N, int K, int do_relu)
{
    __shared__ __attribute__((aligned(16))) unsigned short Alds[GBM * GBK];
    __shared__ __attribute__((aligned(16))) unsigned short Blds[GBN * GBK];
    __shared__ float scol[GBN], sqcol[GBN];

    int tid = threadIdx.x;
    int wave = tid >> 6, lane = tid & 63;
    int row0 = blockIdx.y * GBM;
    int col0 = blockIdx.x * GBN;
    int m = lane & 15, q = lane >> 4;

    floatx4 acc[2][4] = {};

    for (int k0 = 0; k0 < K; k0 += GBK) {
        #pragma unroll
        for (int i = 0; i < 2; ++i) {
            int c = tid + i * 256;
            int r = c >> 2, off = (c & 3) * 8;
            int gr = row0 + r;
            short8 v = {};
            if (gr < M) v = *(const short8*)(A + (size_t)gr * lda + k0 + off);
            *(short8*)(Alds + r * GBK + off) = v;
        }
        {
            int r = tid >> 2, off = (tid & 3) * 8;
            short8 v = *(const short8*)(Bt + (size_t)(col0 + r) * K + k0 + off);
            *(short8*)(Blds + r * GBK + off) = v;
        }
        __syncthreads();

        short8 a0 = *(const short8*)(Alds + (wave * 32 + m) * GBK + q * 8);
        short8 a1 = *(const short8*)(Alds + (wave * 32 + 16 + m) * GBK + q * 8);
        #pragma unroll
        for (int ct = 0; ct < 4; ++ct) {
            short8 b = *(const short8*)(Blds + (ct * 16 + m) * GBK + q * 8);
            acc[0][ct] = __builtin_amdgcn_mfma_f32_16x16x32_bf16(a0, b, acc[0][ct], 0, 0, 0);
            acc[1][ct] = __builtin_amdgcn_mfma_f32_16x16x32_bf16(a1, b, acc[1][ct], 0, 0, 0);
        }
        __syncthreads();
    }

    float ps[4] = {}, pq[4] = {};
    #pragma unroll
    for (int rt = 0; rt < 2; ++rt) {
        #pragma unroll
        for (int r = 0; r < 4; ++r) {
            int gr = row0 + wave * 32 + rt * 16 + q * 4 + r;
            float ds = 0.f, dd = 0.f;
            #pragma unroll
            for (int ct = 0; ct < 4; ++ct) {
                int gc = col0 + ct * 16 + m;
                float v = acc[rt][ct][r];
                if (gc < N) {
                    if (att_s != nullptr) { ds += v * att_s[gc]; dd += v * att_d[gc]; }
                    float vb = v;
                    if (bias != nullptr) vb += bias[gc];
                    if (do_relu) vb = fmaxf(vb, 0.f);
                    if (gr < M) {
                        if (C  != nullptr) C[(size_t)gr * N + gc] = vb;
                        if (Cb != nullptr) Cb[(size_t)gr * N + gc] = f2bf(vb);
                        ps[ct] += vb; pq[ct] += vb * vb;
                    }
                }
            }
            if (att_s != nullptr) {
                #pragma unroll
                for (int off = 1; off < 16; off <<= 1) {
                    ds += __shfl_xor(ds, off);
                    dd += __shfl_xor(dd, off);
                }
                if (m == 0 && gr < M) {
                    int head = col0 >> 7;
                    atomicAdd(&as_out[gr * Hheads + head], ds);
                    atomicAdd(&ad_out[gr * Hheads + head], dd);
                }
            }
        }
    }
    if (colsum != nullptr) {
        if (tid < GBN) { scol[tid] = 0.f; sqcol[tid] = 0.f; }
        __syncthreads();
        #pragma unroll
        for (int ct = 0; ct < 4; ++ct) {
            atomicAdd(&scol[ct * 16 + m], ps[ct]);
            atomicAdd(&sqcol[ct * 16 + m], pq[ct]);
        }
        __syncthreads();
        if (tid < GBN) {
            int gc = col0 + tid;
            if (gc < N) {
                atomicAdd(&colsum[gc], scol[tid]);
                atomicAdd(&colsq[gc], sqcol[tid]);
            }
        }
    }
}

// ================= fp32 fallback GEMM (mlp1b only, N=2) =================
#define BM 64
#define BN 64
#define BK 16

__global__ __launch_bounds__(256, 2) void gemm_fused(
    const float* __restrict__ A, int lda,
    const float* __restrict__ B,
    float* __restrict__ C,
    const float* __restrict__ bias,
    float* __restrict__ colsum, float* __restrict__ colsq,
    int M, int N, int K, int do_relu)
{
    __shared__ float As[BK][BM + 1];
    __shared__ float Bs[BK][BN + 1];
    __shared__ float red[16][BN];

    int tid = threadIdx.x;
    int tx = tid & 15, ty = tid >> 4;
    int row0 = blockIdx.y * BM;
    int col0 = blockIdx.x * BN;

    float acc[4][4] = {};

    for (int k0 = 0; k0 < K; k0 += BK) {
        #pragma unroll
        for (int i = 0; i < 4; ++i) {
            int t = tid + i * 256;
            int r  = t >> 4;
            int kk = t & 15;
            int gr = row0 + r, gk = k0 + kk;
            float v = 0.f;
            if (gr < M && gk < K) v = A[(size_t)gr * lda + gk];
            As[kk][r] = v;
        }
        #pragma unroll
        for (int i = 0; i < 4; ++i) {
            int t = tid + i * 256;
            int nn = t & 63;
            int kk = t >> 6;
            int gk = k0 + kk, gn = col0 + nn;
            Bs[kk][nn] = (gk < K && gn < N) ? B[(size_t)gk * N + gn] : 0.f;
        }
        __syncthreads();
        #pragma unroll
        for (int kk = 0; kk < BK; ++kk) {
            float a[4], b[4];
            #pragma unroll
            for (int r = 0; r < 4; ++r) a[r] = As[kk][ty * 4 + r];
            #pragma unroll
            for (int c = 0; c < 4; ++c) b[c] = Bs[kk][tx * 4 + c];
            #pragma unroll
            for (int r = 0; r < 4; ++r)
                #pragma unroll
                for (int c = 0; c < 4; ++c)
                    acc[r][c] += a[r] * b[c];
        }
        __syncthreads();
    }

    float vals[4][4];
    #pragma unroll
    for (int r = 0; r < 4; ++r) {
        int gr = row0 + ty * 4 + r;
        #pragma unroll
        for (int c = 0; c < 4; ++c) {
            int gc = col0 + tx * 4 + c;
            float v = acc[r][c];
            if (bias != nullptr && gc < N) v += bias[gc];
            if (do_relu) v = fmaxf(v, 0.f);
            bool ok = (gr < M) && (gc < N);
            vals[r][c] = ok ? v : 0.f;
            if (ok) C[(size_t)gr * N + gc] = v;
        }
    }

    if (colsum != nullptr) {
        float ps[4] = {}, pq[4] = {};
        #pragma unroll
        for (int r = 0; r < 4; ++r)
            #pragma unroll
            for (int c = 0; c < 4; ++c) {
                float v = vals[r][c];
                ps[c] += v; pq[c] += v * v;
            }
        #pragma unroll
        for (int c = 0; c < 4; ++c) red[ty][tx * 4 + c] = ps[c];
        __syncthreads();
        if (tid < 64) {
            float s = 0.f;
            #pragma unroll
            for (int t = 0; t < 16; ++t) s += red[t][tid];
            int gc = col0 + tid;
            if (gc < N) atomicAdd(&colsum[gc], s);
        }
        __syncthreads();
        #pragma unroll
        for (int c = 0; c < 4; ++c) red[ty][tx * 4 + c] = pq[c];
        __syncthreads();
        if (tid < 64) {
            float s = 0.f;
            #pragma unroll
            for (int t = 0; t < 16; ++t) s += red[t][tid];
            int gc = col0 + tid;
            if (gc < N) atomicAdd(&colsq[gc], s);
        }
    }
}

// ================= casts =================
__global__ void cast_x_k(const float* __restrict__ x, unsigned short* __restrict__ xb, int total4) {
    int i = blockIdx.x * blockDim.x + threadIdx.x;
    if (i >= total4) return;
    const float4 v = ((const float4*)x)[i];
    ushort4v o;
    o.x = f2bf(v.x); o.y = f2bf(v.y); o.z = f2bf(v.z); o.w = f2bf(v.w);
    ((ushort4v*)xb)[i] = o;
}

__global__ void cast_wt(const float* __restrict__ W, unsigned short* __restrict__ Wt, int K, int N) {
    int k = blockIdx.x * blockDim.x + threadIdx.x;
    int n = blockIdx.y;
    if (k >= K) return;
    Wt[(size_t)n * K + k] = (n < N) ? f2bf(W[(size_t)k * N + n]) : (unsigned short)0;
}

__device__ __forceinline__ void edge_src_dst(const int* ei, int e, int& src, int& dst) {
    if (e < NEDGES) { src = ei[e]; dst = ei[NEDGES + e]; }
    else { src = e - NEDGES; dst = src; }
}

// ================= CSR build =================
__global__ __launch_bounds__(256) void csr_count(const int* __restrict__ ei, int* __restrict__ cnt) {
    int e = blockIdx.x * blockDim.x + threadIdx.x;
    if (e >= ETOT) return;
    int src, dst; edge_src_dst(ei, e, src, dst); (void)src;
    atomicAdd(&cnt[dst], 1);
}

#define SCAN_CH 1024
#define SCAN_NB ((NNODES + SCAN_CH - 1) / SCAN_CH)   // 49

__global__ __launch_bounds__(256) void scan1(const int* __restrict__ cnt, int* __restrict__ part) {
    int t = threadIdx.x;
    int base = blockIdx.x * SCAN_CH + t * 4;
    int4 v = {0, 0, 0, 0};
    if (base + 3 < NNODES) v = *(const int4*)(cnt + base);
    else {
        if (base + 0 < NNODES) v.x = cnt[base + 0];
        if (base + 1 < NNODES) v.y = cnt[base + 1];
        if (base + 2 < NNODES) v.z = cnt[base + 2];
        if (base + 3 < NNODES) v.w = cnt[base + 3];
    }
    int s = v.x + v.y + v.z + v.w;
    __shared__ int sm[256];
    sm[t] = s;
    __syncthreads();
    for (int off = 128; off > 0; off >>= 1) {
        if (t < off) sm[t] += sm[t + off];
        __syncthreads();
    }
    if (t == 0) part[blockIdx.x] = sm[0];
}

__global__ void scan2(int* __restrict__ part, int* __restrict__ rowstart) {
    int lane = threadIdx.x;
    int v = (lane < SCAN_NB) ? part[lane] : 0;
    #pragma unroll
    for (int off = 1; off < 64; off <<= 1) {
        int t = __shfl_up(v, off);
        if (lane >= off) v += t;
    }
    int ex = __shfl_up(v, 1);
    if (lane == 0) ex = 0;
    if (lane < SCAN_NB) part[lane] = ex;
    if (lane == 0) rowstart[NNODES] = ETOT;
}

__global__ __launch_bounds__(256) void scan3(const int* __restrict__ cnt, const int* __restrict__ part,
                                             int* __restrict__ rowstart, int* __restrict__ cursor) {
    int t = threadIdx.x;
    int base = blockIdx.x * SCAN_CH + t * 4;
    int4 v = {0, 0, 0, 0};
    if (base + 3 < NNODES) v = *(const int4*)(cnt + base);
    else {
        if (base + 0 < NNODES) v.x = cnt[base + 0];
        if (base + 1 < NNODES) v.y = cnt[base + 1];
        if (base + 2 < NNODES) v.z = cnt[base + 2];
        if (base + 3 < NNODES) v.w = cnt[base + 3];
    }
    int s = v.x + v.y + v.z + v.w;
    __shared__ int sm[2][256];
    sm[0][t] = s;
    __syncthreads();
    int cur = 0;
    #pragma unroll
    for (int off = 1; off < 256; off <<= 1) {
        int nxt = cur ^ 1;
        int val = sm[cur][t];
        if (t >= off) val += sm[cur][t - off];
        sm[nxt][t] = val;
        __syncthreads();
        cur = nxt;
    }
    int p = sm[cur][t] - s + part[blockIdx.x];
    if (base + 0 < NNODES) { rowstart[base + 0] = p; cursor[base + 0] = p; } p += v.x;
    if (base + 1 < NNODES) { rowstart[base + 1] = p; cursor[base + 1] = p; } p += v.y;
    if (base + 2 < NNODES) { rowstart[base + 2] = p; cursor[base + 2] = p; } p += v.z;
    if (base + 3 < NNODES) { rowstart[base + 3] = p; cursor[base + 3] = p; }
}

__global__ __launch_bounds__(256) void csr_fill(const int* __restrict__ ei,
                                                int* __restrict__ cursor,
                                                int* __restrict__ esrc) {
    int e = blockIdx.x * blockDim.x + threadIdx.x;
    if (e >= ETOT) return;
    int src, dst; edge_src_dst(ei, e, src, dst);
    int pos = atomicAdd(&cursor[dst], 1);
    esrc[pos] = src;
}

// ================= fused GAT aggregation (one wave per node, bf16 h) =================
__global__ __launch_bounds__(256) void gat_gather_h2(
    const int* __restrict__ rowstart, const int* __restrict__ esrc,
    const unsigned short* __restrict__ hb, const float* __restrict__ a_src,
    const float* __restrict__ a_dst, const float* __restrict__ bias,
    unsigned short* __restrict__ xcat)
{
    int n = (blockIdx.x * blockDim.x + threadIdx.x) >> 6;
    int lane = threadIdx.x & 63;
    if (n >= NNODES) return;
    int beg = rowstart[n], end = rowstart[n + 1];
    float ad0 = a_dst[n * 2], ad1 = a_dst[n * 2 + 1];

    float m0 = -1e30f, m1 = -1e30f;
    for (int i = beg + lane; i < end; i += 64) {
        int s = esrc[i];
        float l0 = a_src[s * 2] + ad0;     l0 = l0 >= 0.f ? l0 : 0.2f * l0;
        float l1 = a_src[s * 2 + 1] + ad1; l1 = l1 >= 0.f ? l1 : 0.2f * l1;
        m0 = fmaxf(m0, l0); m1 = fmaxf(m1, l1);
    }
    #pragma unroll
    for (int off = 1; off < 64; off <<= 1) {
        m0 = fmaxf(m0, __shfl_xor(m0, off));
        m1 = fmaxf(m1, __shfl_xor(m1, off));
    }
    float s0 = 0.f, s1 = 0.f;
    for (int i = beg + lane; i < end; i += 64) {
        int s = esrc[i];
        float l0 = a_src[s * 2] + ad0;     l0 = l0 >= 0.f ? l0 : 0.2f * l0;
        float l1 = a_src[s * 2 + 1] + ad1; l1 = l1 >= 0.f ? l1 : 0.2f * l1;
        s0 += __expf(l0 - m0); s1 += __expf(l1 - m1);
    }
    #pragma unroll
    for (int off = 1; off < 64; off <<= 1) {
        s0 += __shfl_xor(s0, off);
        s1 += __shfl_xor(s1, off);
    }
    int head = lane >> 5;
    float mh   = head ? m1 : m0;
    float invh = head ? 1.f / (s1 + 1e-16f) : 1.f / (s0 + 1e-16f);
    float adh  = head ? ad1 : ad0;

    float4 acc = {0.f, 0.f, 0.f, 0.f};
    for (int i = beg; i < end; ++i) {
        int s = esrc[i];
        float l = a_src[s * 2 + head] + adh; l = l >= 0.f ? l : 0.2f * l;
        float w = __expf(l - mh) * invh;
        const ushort4v hv = *(const ushort4v*)(hb + (size_t)s * 256 + lane * 4);
        acc.x += w * bf2f(hv.x); acc.y += w * bf2f(hv.y);
        acc.z += w * bf2f(hv.z); acc.w += w * bf2f(hv.w);
    }
    const float4 b = *(const float4*)(bias + lane * 4);
    ushort4v o;
    o.x = f2bf(acc.x + b.x); o.y = f2bf(acc.y + b.y);
    o.z = f2bf(acc.z + b.z); o.w = f2bf(acc.w + b.w);
    *(ushort4v*)(xcat + (size_t)n * 384 + lane * 4) = o;
}

__global__ __launch_bounds__(256) void gat_gather_h1(
    const int* __restrict__ rowstart, const int* __restrict__ esrc,
    const unsigned short* __restrict__ hb, const float* __restrict__ a_src,
    const float* __restrict__ a_dst, const float* __restrict__ bias,
    unsigned short* __restrict__ xcat)
{
    int n = (blockIdx.x * blockDim.x + threadIdx.x) >> 6;
    int lane = threadIdx.x & 63;
    if (n >= NNODES) return;
    int beg = rowstart[n], end = rowstart[n + 1];
    float ad0 = a_dst[n];

    float m0 = -1e30f;
    for (int i = beg + lane; i < end; i += 64) {
        int s = esrc[i];
        float l0 = a_src[s] + ad0; l0 = l0 >= 0.f ? l0 : 0.2f * l0;
        m0 = fmaxf(m0, l0);
    }
    #pragma unroll
    for (int off = 1; off < 64; off <<= 1) m0 = fmaxf(m0, __shfl_xor(m0, off));
    float s0 = 0.f;
    for (int i = beg + lane; i < end; i += 64) {
        int s = esrc[i];
        float l0 = a_src[s] + ad0; l0 = l0 >= 0.f ? l0 : 0.2f * l0;
        s0 += __expf(l0 - m0);
    }
    #pragma unroll
    for (int off = 1; off < 64; off <<= 1) s0 += __shfl_xor(s0, off);
    float inv0 = 1.f / (s0 + 1e-16f);

    float2 acc = {0.f, 0.f};
    for (int i = beg; i < end; ++i) {
        int s = esrc[i];
        float l = a_src[s] + ad0; l = l >= 0.f ? l : 0.2f * l;
        float w = __expf(l - m0) * inv0;
        const ushort2v hv = *(const ushort2v*)(hb + (size_t)s * 128 + lane * 2);
        acc.x += w * bf2f(hv.x); acc.y += w * bf2f(hv.y);
    }
    const float2 b = *(const float2*)(bias + lane * 2);
    ushort2v o;
    o.x = f2bf(acc.x + b.x); o.y = f2bf(acc.y + b.y);
    *(ushort2v*)(xcat + (size_t)n * 384 + 256 + lane * 2) = o;
}

// ================= BN helpers =================
__global__ void bn_finalize(const float* __restrict__ colsum, const float* __restrict__ colsq,
                            const float* __restrict__ gamma, const float* __restrict__ beta,
                            float* __restrict__ scale, float* __restrict__ shift,
                            int Ncols, float invM)
{
    int j = blockIdx.x * blockDim.x + threadIdx.x;
    if (j >= Ncols) return;
    float mu  = colsum[j] * invM;
    float var = colsq[j] * invM - mu * mu;
    if (var < 0.f) var = 0.f;
    float sc = gamma[j] * rsqrtf(var + 1e-5f);
    scale[j] = sc;
    shift[j] = beta[j] - mu * sc;
}

__global__ void bn_apply(float* __restrict__ y, const float* __restrict__ scale,
                         const float* __restrict__ shift, int total, int Ncols)
{
    int i = blockIdx.x * blockDim.x + threadIdx.x;
    if (i >= total) return;
    int j = i % Ncols;
    y[i] = y[i] * scale[j] + shift[j];
}

__global__ void bn_apply_bf16(const float* __restrict__ y, const float* __restrict__ scale,
                              const float* __restrict__ shift, unsigned short* __restrict__ out,
                              int total, int Ncols)
{
    int i = blockIdx.x * blockDim.x + threadIdx.x;
    if (i >= total) return;
    int j = i % Ncols;
    out[i] = f2bf(y[i] * scale[j] + shift[j]);
}

extern "C" void kernel_launch(void* const* d_in, const int* in_sizes, int n_in,
                              void* d_out, int out_size, void* d_ws, size_t ws_size,
                              hipStream_t stream) {
    const float* x        = (const float*)d_in[0];
    const int*   ei       = (const int*)d_in[1];
    const float* W1       = (const float*)d_in[2];
    const float* att_src1 = (const float*)d_in[3];
    const float* att_dst1 = (const float*)d_in[4];
    const float* bias1    = (const float*)d_in[5];
    const float* W2       = (const float*)d_in[6];
    const float* att_src2 = (const float*)d_in[7];
    const float* att_dst2 = (const float*)d_in[8];
    const float* bias2    = (const float*)d_in[9];
    const float* Wl       = (const float*)d_in[10];
    const float* bl       = (const float*)d_in[11];
    const float* gl       = (const float*)d_in[12];
    const float* betal    = (const float*)d_in[13];
    const float* Wa       = (const float*)d_in[14];
    const float* ba       = (const float*)d_in[15];
    const float* ga       = (const float*)d_in[16];
    const float* betaa    = (const float*)d_in[17];
    const float* Wb       = (const float*)d_in[18];
    const float* bb       = (const float*)d_in[19];
    const float* gb       = (const float*)d_in[20];
    const float* betab    = (const float*)d_in[21];
    float* out = (float*)d_out;
    char* ws = (char*)d_ws;

    const int N = NNODES;

    // ---------- workspace layout (bytes), ~110 MB ----------
    const size_t offY    = 0;            // 19.2 MB: y1 -> y2 (fp32 [50000][96])
    const size_t offXcat = 19200000;     // 38.4 MB: xcat bf16 [50000][384]
    const size_t offXb   = 57600000;     // 12.8 MB: xb bf16 -> hb2 bf16 [50000][128]
    const size_t offY1b  = 70400000;     //  9.6 MB: y1b bf16 [50000][96]
    const size_t offHb1  = 80000000;     // 25.6 MB: hb1 bf16 [50000][256]
    const size_t offW1t  = 105600000;
    const size_t offW2t  = 105665536;
    const size_t offWlt  = 105731072;
    const size_t offWat  = 105829376;
    const size_t offRow  = 106000000;    // cnt -> rowstart [N+1] ints
    const size_t offCur  = 106200128;    // cursor [N] ints
    const size_t offEsrc = 106400832;    // esrc [ETOT] ints
    const size_t offPart = 108700000;    // scan partials [64] ints
    const size_t offAs1  = 108800000;    // a_src1 [N*2] f32
    const size_t offAd1  = 109200000;
    const size_t offAs2  = 109600000;
    const size_t offAd2  = 109800000;
    const size_t offSt   = 110000000;    // stats: 12 x 512 B

    float* y1   = (float*)(ws + offY);
    float* y2   = (float*)(ws + offY);
    unsigned short* xcat = (unsigned short*)(ws + offXcat);
    unsigned short* xb   = (unsigned short*)(ws + offXb);
    unsigned short* hb2  = (unsigned short*)(ws + offXb);   // reuse (xb dead after conv1)
    unsigned short* y1b  = (unsigned short*)(ws + offY1b);
    unsigned short* hb1  = (unsigned short*)(ws + offHb1);
    unsigned short* W1t  = (unsigned short*)(ws + offW1t);
    unsigned short* W2t  = (unsigned short*)(ws + offW2t);
    unsigned short* Wlt  = (unsigned short*)(ws + offWlt);
    unsigned short* Wat  = (unsigned short*)(ws + offWat);
    int* rowst  = (int*)(ws + offRow);
    int* cursor = (int*)(ws + offCur);
    int* esrc   = (int*)(ws + offEsrc);
    int* part   = (int*)(ws + offPart);
    float* as1  = (float*)(ws + offAs1);
    float* ad1  = (float*)(ws + offAd1);
    float* as2  = (float*)(ws + offAs2);
    float* ad2  = (float*)(ws + offAd2);

    float* csum_l = (float*)(ws + offSt + 0);
    float* csq_l  = (float*)(ws + offSt + 512);
    float* scl_l  = (float*)(ws + offSt + 1024);
    float* shf_l  = (float*)(ws + offSt + 1536);
    float* csum_a = (float*)(ws + offSt + 2048);
    float* csq_a  = (float*)(ws + offSt + 2560);
    float* scl_a  = (float*)(ws + offSt + 3072);
    float* shf_a  = (float*)(ws + offSt + 3584);
    float* csum_b = (float*)(ws + offSt + 4096);
    float* csq_b  = (float*)(ws + offSt + 4608);
    float* scl_b  = (float*)(ws + offSt + 5120);
    float* shf_b  = (float*)(ws + offSt + 5632);

    // zero: CSR histogram + att-dot accumulators + BN stats
    hipMemsetAsync(ws + offRow, 0, (NNODES + 1) * sizeof(int), stream);
    hipMemsetAsync(ws + offAs1, 0, (offSt + 6144) - offAs1, stream);

    dim3 blk(256);
    int edgeBlocks  = (ETOT + 255) / 256;
    int waveBlocksN = (N + 3) / 4;

    // ---- casts ----
    cast_x_k<<<(N * 128 / 4 + 255) / 256, blk, 0, stream>>>(x, xb, N * 128 / 4);
    cast_wt<<<dim3(1, 256), blk, 0, stream>>>(W1, W1t, 128, 256);
    cast_wt<<<dim3(1, 128), blk, 0, stream>>>(W2, W2t, 256, 128);
    cast_wt<<<dim3(2, 128), blk, 0, stream>>>(Wl, Wlt, 384, 96);
    cast_wt<<<dim3(1, 128), blk, 0, stream>>>(Wa, Wat, 96, 96);

    // ---- CSR build ----
    csr_count<<<edgeBlocks, blk, 0, stream>>>(ei, rowst);
    scan1<<<SCAN_NB, blk, 0, stream>>>(rowst, part);
    scan2<<<1, 64, 0, stream>>>(part, rowst);
    scan3<<<SCAN_NB, blk, 0, stream>>>(rowst, part, rowst, cursor);
    csr_fill<<<edgeBlocks, blk, 0, stream>>>(ei, cursor, esrc);

    // ---- conv1: hb1 = bf16(xb @ W1), fused att dots ----
    gemm_mfma<<<dim3(4, (N + GBM - 1) / GBM), blk, 0, stream>>>(
        xb, 128, W1t, nullptr, hb1, nullptr, nullptr, nullptr,
        att_src1, att_dst1, as1, ad1, 2, N, 256, 128, 0);
    gat_gather_h2<<<waveBlocksN, blk, 0, stream>>>(rowst, esrc, hb1, as1, ad1, bias1, xcat);

    // ---- conv2: hb2 = bf16(xcat[:, :256] @ W2), fused att dots ----
    gemm_mfma<<<dim3(2, (N + GBM - 1) / GBM), blk, 0, stream>>>(
        xcat, 384, W2t, nullptr, hb2, nullptr, nullptr, nullptr,
        att_src2, att_dst2, as2, ad2, 1, N, 128, 256, 0);
    gat_gather_h1<<<waveBlocksN, blk, 0, stream>>>(rowst, esrc, hb2, as2, ad2, bias2, xcat);

    // ---- lin1: y1 = relu(xcat @ Wl + bl), stats ----
    gemm_mfma<<<dim3(2, (N + GBM - 1) / GBM), blk, 0, stream>>>(
        xcat, 384, Wlt, y1, nullptr, bl, csum_l, csq_l,
        nullptr, nullptr, nullptr, nullptr, 0, N, 96, 384, 1);
    bn_finalize<<<1, 128, 0, stream>>>(csum_l, csq_l, gl, betal, scl_l, shf_l, 96, 1.f / N);
    bn_apply_bf16<<<(N * 96 + 255) / 256, blk, 0, stream>>>(y1, scl_l, shf_l, y1b, N * 96, 96);

    // ---- mlp1 layer 1: y2 = relu(y1b @ Wa + ba), stats ----
    gemm_mfma<<<dim3(2, (N + GBM - 1) / GBM), blk, 0, stream>>>(
        y1b, 96, Wat, y2, nullptr, ba, csum_a, csq_a,
        nullptr, nullptr, nullptr, nullptr, 0, N, 96, 96, 1);
    bn_finalize<<<1, 128, 0, stream>>>(csum_a, csq_a, ga, betaa, scl_a, shf_a, 96, 1.f / N);
    bn_apply<<<(N * 96 + 255) / 256, blk, 0, stream>>>(y2, scl_a, shf_a, N * 96, 96);

    // ---- mlp1 layer 2 (fp32, N=2, writes d_out) ----
    gemm_fused<<<dim3(1, (N + BM - 1) / BM), blk, 0, stream>>>(
        y2, 96, Wb, out, bb, csum_b, csq_b, N, 2, 96, 1);
    bn_finalize<<<1, 64, 0, stream>>>(csum_b, csq_b, gb, betab, scl_b, shf_b, 2, 1.f / N);
    bn_apply<<<(N * 2 + 255) / 256, blk, 0, stream>>>(out, scl_b, shf_b, N * 2, 2);
}

// Round 6
// 441.001 us; speedup vs baseline: 3.5835x; 1.1460x over previous
//
#include <hip/hip_runtime.h>
#include <hip/hip_bf16.h>
#include <cstdint>
#include <cstddef>

#define NNODES 50000
#define NEDGES 500000
#define ETOT   (NEDGES + NNODES)

typedef __attribute__((ext_vector_type(8))) short short8;
typedef __attribute__((ext_vector_type(8))) unsigned short ushort8v;
typedef __attribute__((ext_vector_type(4))) float floatx4;
typedef __attribute__((ext_vector_type(4))) unsigned short ushort4v;

__device__ __forceinline__ unsigned short f2bf(float f) {
    union { __hip_bfloat16 h; unsigned short u; } cv;
    cv.h = __float2bfloat16(f);
    return cv.u;
}
__device__ __forceinline__ float bf2f(unsigned short u) {
    union { unsigned int i; float f; } cv;
    cv.i = ((unsigned int)u) << 16;
    return cv.f;
}

// ================= bf16 MFMA GEMM: C/Cb = op(A @ Bt^T + bias) =================
#define GBM 128
#define GBN 64
#define GBK 32

__global__ __launch_bounds__(256, 4) void gemm_mfma(
    const unsigned short* __restrict__ A, int lda,
    const unsigned short* __restrict__ Bt,
    float* __restrict__ C,
    unsigned short* __restrict__ Cb,
    const float* __restrict__ bias,
    float* __restrict__ colsum, float* __restrict__ colsq,
    const float* __restrict__ att_s, const float* __restrict__ att_d,
    float* __restrict__ as_out, float* __restrict__ ad_out, int Hheads,
    int M, int N, int K, int do_relu)
{
    __shared__ __attribute__((aligned(16))) unsigned short Alds[GBM * GBK];
    __shared__ __attribute__((aligned(16))) unsigned short Blds[GBN * GBK];
    __shared__ float scol[GBN], sqcol[GBN];

    int tid = threadIdx.x;
    int wave = tid >> 6, lane = tid & 63;
    int row0 = blockIdx.y * GBM;
    int col0 = blockIdx.x * GBN;
    int m = lane & 15, q = lane >> 4;

    floatx4 acc[2][4] = {};

    for (int k0 = 0; k0 < K; k0 += GBK) {
        #pragma unroll
        for (int i = 0; i < 2; ++i) {
            int c = tid + i * 256;
            int r = c >> 2, off = (c & 3) * 8;
            int gr = row0 + r;
            short8 v = {};
            if (gr < M) v = *(const short8*)(A + (size_t)gr * lda + k0 + off);
            *(short8*)(Alds + r * GBK + off) = v;
        }
        {
            int r = tid >> 2, off = (tid & 3) * 8;
            short8 v = *(const short8*)(Bt + (size_t)(col0 + r) * K + k0 + off);
            *(short8*)(Blds + r * GBK + off) = v;
        }
        __syncthreads();

        short8 a0 = *(const short8*)(Alds + (wave * 32 + m) * GBK + q * 8);
        short8 a1 = *(const short8*)(Alds + (wave * 32 + 16 + m) * GBK + q * 8);
        #pragma unroll
        for (int ct = 0; ct < 4; ++ct) {
            short8 b = *(const short8*)(Blds + (ct * 16 + m) * GBK + q * 8);
            acc[0][ct] = __builtin_amdgcn_mfma_f32_16x16x32_bf16(a0, b, acc[0][ct], 0, 0, 0);
            acc[1][ct] = __builtin_amdgcn_mfma_f32_16x16x32_bf16(a1, b, acc[1][ct], 0, 0, 0);
        }
        __syncthreads();
    }

    float ps[4] = {}, pq[4] = {};
    #pragma unroll
    for (int rt = 0; rt < 2; ++rt) {
        #pragma unroll
        for (int r = 0; r < 4; ++r) {
            int gr = row0 + wave * 32 + rt * 16 + q * 4 + r;
            float ds = 0.f, dd = 0.f;
            #pragma unroll
            for (int ct = 0; ct < 4; ++ct) {
                int gc = col0 + ct * 16 + m;
                float v = acc[rt][ct][r];
                if (gc < N) {
                    if (att_s != nullptr) { ds += v * att_s[gc]; dd += v * att_d[gc]; }
                    float vb = v;
                    if (bias != nullptr) vb += bias[gc];
                    if (do_relu) vb = fmaxf(vb, 0.f);
                    if (gr < M) {
                        if (C  != nullptr) C[(size_t)gr * N + gc] = vb;
                        if (Cb != nullptr) Cb[(size_t)gr * N + gc] = f2bf(vb);
                        ps[ct] += vb; pq[ct] += vb * vb;
                    }
                }
            }
            if (att_s != nullptr) {
                #pragma unroll
                for (int off = 1; off < 16; off <<= 1) {
                    ds += __shfl_xor(ds, off);
                    dd += __shfl_xor(dd, off);
                }
                if (m == 0 && gr < M) {
                    int head = col0 >> 7;
                    atomicAdd(&as_out[gr * Hheads + head], ds);
                    atomicAdd(&ad_out[gr * Hheads + head], dd);
                }
            }
        }
    }
    if (colsum != nullptr) {
        if (tid < GBN) { scol[tid] = 0.f; sqcol[tid] = 0.f; }
        __syncthreads();
        #pragma unroll
        for (int ct = 0; ct < 4; ++ct) {
            atomicAdd(&scol[ct * 16 + m], ps[ct]);
            atomicAdd(&sqcol[ct * 16 + m], pq[ct]);
        }
        __syncthreads();
        if (tid < GBN) {
            int gc = col0 + tid;
            if (gc < N) {
                atomicAdd(&colsum[gc], scol[tid]);
                atomicAdd(&colsq[gc], sqcol[tid]);
            }
        }
    }
}

// ================= fp32 fallback GEMM (mlp1b only, N=2) =================
#define BM 64
#define BN 64
#define BK 16

__global__ __launch_bounds__(256, 2) void gemm_fused(
    const float* __restrict__ A, int lda,
    const float* __restrict__ B,
    float* __restrict__ C,
    const float* __restrict__ bias,
    float* __restrict__ colsum, float* __restrict__ colsq,
    int M, int N, int K, int do_relu)
{
    __shared__ float As[BK][BM + 1];
    __shared__ float Bs[BK][BN + 1];
    __shared__ float red[16][BN];

    int tid = threadIdx.x;
    int tx = tid & 15, ty = tid >> 4;
    int row0 = blockIdx.y * BM;
    int col0 = blockIdx.x * BN;

    float acc[4][4] = {};

    for (int k0 = 0; k0 < K; k0 += BK) {
        #pragma unroll
        for (int i = 0; i < 4; ++i) {
            int t = tid + i * 256;
            int r  = t >> 4;
            int kk = t & 15;
            int gr = row0 + r, gk = k0 + kk;
            float v = 0.f;
            if (gr < M && gk < K) v = A[(size_t)gr * lda + gk];
            As[kk][r] = v;
        }
        #pragma unroll
        for (int i = 0; i < 4; ++i) {
            int t = tid + i * 256;
            int nn = t & 63;
            int kk = t >> 6;
            int gk = k0 + kk, gn = col0 + nn;
            Bs[kk][nn] = (gk < K && gn < N) ? B[(size_t)gk * N + gn] : 0.f;
        }
        __syncthreads();
        #pragma unroll
        for (int kk = 0; kk < BK; ++kk) {
            float a[4], b[4];
            #pragma unroll
            for (int r = 0; r < 4; ++r) a[r] = As[kk][ty * 4 + r];
            #pragma unroll
            for (int c = 0; c < 4; ++c) b[c] = Bs[kk][tx * 4 + c];
            #pragma unroll
            for (int r = 0; r < 4; ++r)
                #pragma unroll
                for (int c = 0; c < 4; ++c)
                    acc[r][c] += a[r] * b[c];
        }
        __syncthreads();
    }

    float vals[4][4];
    #pragma unroll
    for (int r = 0; r < 4; ++r) {
        int gr = row0 + ty * 4 + r;
        #pragma unroll
        for (int c = 0; c < 4; ++c) {
            int gc = col0 + tx * 4 + c;
            float v = acc[r][c];
            if (bias != nullptr && gc < N) v += bias[gc];
            if (do_relu) v = fmaxf(v, 0.f);
            bool ok = (gr < M) && (gc < N);
            vals[r][c] = ok ? v : 0.f;
            if (ok) C[(size_t)gr * N + gc] = v;
        }
    }

    if (colsum != nullptr) {
        float ps[4] = {}, pq[4] = {};
        #pragma unroll
        for (int r = 0; r < 4; ++r)
            #pragma unroll
            for (int c = 0; c < 4; ++c) {
                float v = vals[r][c];
                ps[c] += v; pq[c] += v * v;
            }
        #pragma unroll
        for (int c = 0; c < 4; ++c) red[ty][tx * 4 + c] = ps[c];
        __syncthreads();
        if (tid < 64) {
            float s = 0.f;
            #pragma unroll
            for (int t = 0; t < 16; ++t) s += red[t][tid];
            int gc = col0 + tid;
            if (gc < N) atomicAdd(&colsum[gc], s);
        }
        __syncthreads();
        #pragma unroll
        for (int c = 0; c < 4; ++c) red[ty][tx * 4 + c] = pq[c];
        __syncthreads();
        if (tid < 64) {
            float s = 0.f;
            #pragma unroll
            for (int t = 0; t < 16; ++t) s += red[t][tid];
            int gc = col0 + tid;
            if (gc < N) atomicAdd(&colsq[gc], s);
        }
    }
}

// ================= casts =================
__global__ void cast_x_k(const float* __restrict__ x, unsigned short* __restrict__ xb, int total4) {
    int i = blockIdx.x * blockDim.x + threadIdx.x;
    if (i >= total4) return;
    const float4 v = ((const float4*)x)[i];
    ushort4v o;
    o.x = f2bf(v.x); o.y = f2bf(v.y); o.z = f2bf(v.z); o.w = f2bf(v.w);
    ((ushort4v*)xb)[i] = o;
}

__global__ void cast_wt(const float* __restrict__ W, unsigned short* __restrict__ Wt, int K, int N) {
    int k = blockIdx.x * blockDim.x + threadIdx.x;
    int n = blockIdx.y;
    if (k >= K) return;
    Wt[(size_t)n * K + k] = (n < N) ? f2bf(W[(size_t)k * N + n]) : (unsigned short)0;
}

// ================= BN fold kernels =================
// Wat2[n][k] = bf16(scl[k] * Wa[k][n]) for n<96 else 0 (n in [0,128)); ba_f[n] = ba[n] + sum_k shf[k]*Wa[k][n]
__global__ void fold_wa(const float* __restrict__ Wa, const float* __restrict__ ba,
                        const float* __restrict__ scl, const float* __restrict__ shf,
                        unsigned short* __restrict__ Wat2, float* __restrict__ ba_f) {
    int tid = threadIdx.x;
    for (int idx = tid; idx < 128 * 96; idx += 256) {
        int n = idx / 96, k = idx % 96;
        float v = 0.f;
        if (n < 96) v = scl[k] * Wa[k * 96 + n];
        Wat2[n * 96 + k] = f2bf(v);
    }
    if (tid < 96) {
        float s = ba[tid];
        for (int k = 0; k < 96; ++k) s += shf[k] * Wa[k * 96 + tid];
        ba_f[tid] = s;
    }
}

// Wb_f[k][n] = scl[k]*Wb[k][n]; bb_f[n] = bb[n] + sum_k shf[k]*Wb[k][n]
__global__ void fold_wb(const float* __restrict__ Wb, const float* __restrict__ bb,
                        const float* __restrict__ scl, const float* __restrict__ shf,
                        float* __restrict__ Wb_f, float* __restrict__ bb_f) {
    int tid = threadIdx.x;
    if (tid < 192) {
        int k = tid >> 1;
        Wb_f[tid] = scl[k] * Wb[tid];
    }
    if (tid < 2) {
        float s = bb[tid];
        for (int k = 0; k < 96; ++k) s += shf[k] * Wb[k * 2 + tid];
        bb_f[tid] = s;
    }
}

__device__ __forceinline__ void edge_src_dst(const int* ei, int e, int& src, int& dst) {
    if (e < NEDGES) { src = ei[e]; dst = ei[NEDGES + e]; }
    else { src = e - NEDGES; dst = src; }
}

// ================= CSR build =================
__global__ __launch_bounds__(256) void csr_count(const int* __restrict__ ei, int* __restrict__ cnt) {
    int e = blockIdx.x * blockDim.x + threadIdx.x;
    if (e >= ETOT) return;
    int src, dst; edge_src_dst(ei, e, src, dst); (void)src;
    atomicAdd(&cnt[dst], 1);
}

#define SCAN_CH 1024
#define SCAN_NB ((NNODES + SCAN_CH - 1) / SCAN_CH)   // 49

__global__ __launch_bounds__(256) void scan1(const int* __restrict__ cnt, int* __restrict__ part) {
    int t = threadIdx.x;
    int base = blockIdx.x * SCAN_CH + t * 4;
    int4 v = {0, 0, 0, 0};
    if (base + 3 < NNODES) v = *(const int4*)(cnt + base);
    else {
        if (base + 0 < NNODES) v.x = cnt[base + 0];
        if (base + 1 < NNODES) v.y = cnt[base + 1];
        if (base + 2 < NNODES) v.z = cnt[base + 2];
        if (base + 3 < NNODES) v.w = cnt[base + 3];
    }
    int s = v.x + v.y + v.z + v.w;
    __shared__ int sm[256];
    sm[t] = s;
    __syncthreads();
    for (int off = 128; off > 0; off >>= 1) {
        if (t < off) sm[t] += sm[t + off];
        __syncthreads();
    }
    if (t == 0) part[blockIdx.x] = sm[0];
}

__global__ void scan2(int* __restrict__ part, int* __restrict__ rowstart) {
    int lane = threadIdx.x;
    int v = (lane < SCAN_NB) ? part[lane] : 0;
    #pragma unroll
    for (int off = 1; off < 64; off <<= 1) {
        int t = __shfl_up(v, off);
        if (lane >= off) v += t;
    }
    int ex = __shfl_up(v, 1);
    if (lane == 0) ex = 0;
    if (lane < SCAN_NB) part[lane] = ex;
    if (lane == 0) rowstart[NNODES] = ETOT;
}

__global__ __launch_bounds__(256) void scan3(const int* __restrict__ cnt, const int* __restrict__ part,
                                             int* __restrict__ rowstart, int* __restrict__ cursor) {
    int t = threadIdx.x;
    int base = blockIdx.x * SCAN_CH + t * 4;
    int4 v = {0, 0, 0, 0};
    if (base + 3 < NNODES) v = *(const int4*)(cnt + base);
    else {
        if (base + 0 < NNODES) v.x = cnt[base + 0];
        if (base + 1 < NNODES) v.y = cnt[base + 1];
        if (base + 2 < NNODES) v.z = cnt[base + 2];
        if (base + 3 < NNODES) v.w = cnt[base + 3];
    }
    int s = v.x + v.y + v.z + v.w;
    __shared__ int sm[2][256];
    sm[0][t] = s;
    __syncthreads();
    int cur = 0;
    #pragma unroll
    for (int off = 1; off < 256; off <<= 1) {
        int nxt = cur ^ 1;
        int val = sm[cur][t];
        if (t >= off) val += sm[cur][t - off];
        sm[nxt][t] = val;
        __syncthreads();
        cur = nxt;
    }
    int p = sm[cur][t] - s + part[blockIdx.x];
    if (base + 0 < NNODES) { rowstart[base + 0] = p; cursor[base + 0] = p; } p += v.x;
    if (base + 1 < NNODES) { rowstart[base + 1] = p; cursor[base + 1] = p; } p += v.y;
    if (base + 2 < NNODES) { rowstart[base + 2] = p; cursor[base + 2] = p; } p += v.z;
    if (base + 3 < NNODES) { rowstart[base + 3] = p; cursor[base + 3] = p; }
}

__global__ __launch_bounds__(256) void csr_fill(const int* __restrict__ ei,
                                                int* __restrict__ cursor,
                                                int* __restrict__ esrc) {
    int e = blockIdx.x * blockDim.x + threadIdx.x;
    if (e >= ETOT) return;
    int src, dst; edge_src_dst(ei, e, src, dst);
    int pos = atomicAdd(&cursor[dst], 1);
    esrc[pos] = src;
}

// ================= fused GAT aggregation =================
// conv1 (H=2, 256 feats): 2 edge-groups of 32 lanes, 16 B/lane gathers.
__global__ __launch_bounds__(256) void gat_gather_h2(
    const int* __restrict__ rowstart, const int* __restrict__ esrc,
    const unsigned short* __restrict__ hb, const float* __restrict__ a_src,
    const float* __restrict__ a_dst, const float* __restrict__ bias,
    unsigned short* __restrict__ xcat)
{
    int n = (blockIdx.x * blockDim.x + threadIdx.x) >> 6;
    int lane = threadIdx.x & 63;
    if (n >= NNODES) return;
    int beg = rowstart[n], end = rowstart[n + 1];
    float ad0 = a_dst[n * 2], ad1 = a_dst[n * 2 + 1];

    float m0 = -1e30f, m1 = -1e30f;
    for (int i = beg + lane; i < end; i += 64) {
        int s = esrc[i];
        float l0 = a_src[s * 2] + ad0;     l0 = l0 >= 0.f ? l0 : 0.2f * l0;
        float l1 = a_src[s * 2 + 1] + ad1; l1 = l1 >= 0.f ? l1 : 0.2f * l1;
        m0 = fmaxf(m0, l0); m1 = fmaxf(m1, l1);
    }
    #pragma unroll
    for (int off = 1; off < 64; off <<= 1) {
        m0 = fmaxf(m0, __shfl_xor(m0, off));
        m1 = fmaxf(m1, __shfl_xor(m1, off));
    }
    float s0 = 0.f, s1 = 0.f;
    for (int i = beg + lane; i < end; i += 64) {
        int s = esrc[i];
        float l0 = a_src[s * 2] + ad0;     l0 = l0 >= 0.f ? l0 : 0.2f * l0;
        float l1 = a_src[s * 2 + 1] + ad1; l1 = l1 >= 0.f ? l1 : 0.2f * l1;
        s0 += __expf(l0 - m0); s1 += __expf(l1 - m1);
    }
    #pragma unroll
    for (int off = 1; off < 64; off <<= 1) {
        s0 += __shfl_xor(s0, off);
        s1 += __shfl_xor(s1, off);
    }

    int g  = lane >> 5;        // edge group (0/1)
    int sl = lane & 31;        // 16 B slot within row
    int head = sl >> 4;        // feats sl*8: 0-127 head0, 128-255 head1
    float mh   = head ? m1 : m0;
    float invh = head ? 1.f / (s1 + 1e-16f) : 1.f / (s0 + 1e-16f);
    float adh  = head ? ad1 : ad0;

    float acc[8] = {};
    for (int i = beg + g; i < end; i += 2) {
        int s = esrc[i];
        float l = a_src[s * 2 + head] + adh; l = l >= 0.f ? l : 0.2f * l;
        float w = __expf(l - mh) * invh;
        const ushort8v hv = *(const ushort8v*)(hb + (size_t)s * 256 + sl * 8);
        #pragma unroll
        for (int j = 0; j < 8; ++j) acc[j] += w * bf2f(hv[j]);
    }
    #pragma unroll
    for (int j = 0; j < 8; ++j) acc[j] += __shfl_xor(acc[j], 32);
    if (g == 0) {
        ushort8v o;
        #pragma unroll
        for (int j = 0; j < 8; ++j) o[j] = f2bf(acc[j] + bias[sl * 8 + j]);
        *(ushort8v*)(xcat + (size_t)n * 384 + sl * 8) = o;
    }
}

// conv2 (H=1, 128 feats): 4 edge-groups of 16 lanes, 16 B/lane gathers.
__global__ __launch_bounds__(256) void gat_gather_h1(
    const int* __restrict__ rowstart, const int* __restrict__ esrc,
    const unsigned short* __restrict__ hb, const float* __restrict__ a_src,
    const float* __restrict__ a_dst, const float* __restrict__ bias,
    unsigned short* __restrict__ xcat)
{
    int n = (blockIdx.x * blockDim.x + threadIdx.x) >> 6;
    int lane = threadIdx.x & 63;
    if (n >= NNODES) return;
    int beg = rowstart[n], end = rowstart[n + 1];
    float ad0 = a_dst[n];

    float m0 = -1e30f;
    for (int i = beg + lane; i < end; i += 64) {
        int s = esrc[i];
        float l0 = a_src[s] + ad0; l0 = l0 >= 0.f ? l0 : 0.2f * l0;
        m0 = fmaxf(m0, l0);
    }
    #pragma unroll
    for (int off = 1; off < 64; off <<= 1) m0 = fmaxf(m0, __shfl_xor(m0, off));
    float s0 = 0.f;
    for (int i = beg + lane; i < end; i += 64) {
        int s = esrc[i];
        float l0 = a_src[s] + ad0; l0 = l0 >= 0.f ? l0 : 0.2f * l0;
        s0 += __expf(l0 - m0);
    }
    #pragma unroll
    for (int off = 1; off < 64; off <<= 1) s0 += __shfl_xor(s0, off);
    float inv0 = 1.f / (s0 + 1e-16f);

    int g  = lane >> 4;        // edge group (0..3)
    int sl = lane & 15;        // 16 B slot within row

    float acc[8] = {};
    for (int i = beg + g; i < end; i += 4) {
        int s = esrc[i];
        float l = a_src[s] + ad0; l = l >= 0.f ? l : 0.2f * l;
        float w = __expf(l - m0) * inv0;
        const ushort8v hv = *(const ushort8v*)(hb + (size_t)s * 128 + sl * 8);
        #pragma unroll
        for (int j = 0; j < 8; ++j) acc[j] += w * bf2f(hv[j]);
    }
    #pragma unroll
    for (int j = 0; j < 8; ++j) acc[j] += __shfl_xor(acc[j], 16);
    #pragma unroll
    for (int j = 0; j < 8; ++j) acc[j] += __shfl_xor(acc[j], 32);
    if (g == 0) {
        ushort8v o;
        #pragma unroll
        for (int j = 0; j < 8; ++j) o[j] = f2bf(acc[j] + bias[sl * 8 + j]);
        *(ushort8v*)(xcat + (size_t)n * 384 + 256 + sl * 8) = o;
    }
}

// ================= BN helpers =================
__global__ void bn_finalize(const float* __restrict__ colsum, const float* __restrict__ colsq,
                            const float* __restrict__ gamma, const float* __restrict__ beta,
                            float* __restrict__ scale, float* __restrict__ shift,
                            int Ncols, float invM)
{
    int j = blockIdx.x * blockDim.x + threadIdx.x;
    if (j >= Ncols) return;
    float mu  = colsum[j] * invM;
    float var = colsq[j] * invM - mu * mu;
    if (var < 0.f) var = 0.f;
    float sc = gamma[j] * rsqrtf(var + 1e-5f);
    scale[j] = sc;
    shift[j] = beta[j] - mu * sc;
}

__global__ void bn_apply(float* __restrict__ y, const float* __restrict__ scale,
                         const float* __restrict__ shift, int total, int Ncols)
{
    int i = blockIdx.x * blockDim.x + threadIdx.x;
    if (i >= total) return;
    int j = i % Ncols;
    y[i] = y[i] * scale[j] + shift[j];
}

extern "C" void kernel_launch(void* const* d_in, const int* in_sizes, int n_in,
                              void* d_out, int out_size, void* d_ws, size_t ws_size,
                              hipStream_t stream) {
    const float* x        = (const float*)d_in[0];
    const int*   ei       = (const int*)d_in[1];
    const float* W1       = (const float*)d_in[2];
    const float* att_src1 = (const float*)d_in[3];
    const float* att_dst1 = (const float*)d_in[4];
    const float* bias1    = (const float*)d_in[5];
    const float* W2       = (const float*)d_in[6];
    const float* att_src2 = (const float*)d_in[7];
    const float* att_dst2 = (const float*)d_in[8];
    const float* bias2    = (const float*)d_in[9];
    const float* Wl       = (const float*)d_in[10];
    const float* bl       = (const float*)d_in[11];
    const float* gl       = (const float*)d_in[12];
    const float* betal    = (const float*)d_in[13];
    const float* Wa       = (const float*)d_in[14];
    const float* ba       = (const float*)d_in[15];
    const float* ga       = (const float*)d_in[16];
    const float* betaa    = (const float*)d_in[17];
    const float* Wb       = (const float*)d_in[18];
    const float* bb       = (const float*)d_in[19];
    const float* gb       = (const float*)d_in[20];
    const float* betab    = (const float*)d_in[21];
    float* out = (float*)d_out;
    char* ws = (char*)d_ws;

    const int N = NNODES;

    // ---------- workspace layout (bytes) ----------
    const size_t offY    = 0;            // 19.2 MB: y2 (fp32 [50000][96])
    const size_t offXcat = 19200000;     // 38.4 MB: xcat bf16 [50000][384]
    const size_t offXb   = 57600000;     // 12.8 MB: xb bf16 -> hb2 bf16 [50000][128]
    const size_t offY1b  = 70400000;     //  9.6 MB: y1b bf16 [50000][96]
    const size_t offHb1  = 80000000;     // 25.6 MB: hb1 bf16 [50000][256]
    const size_t offW1t  = 105600000;
    const size_t offW2t  = 105665536;
    const size_t offWlt  = 105731072;
    const size_t offWat  = 105829376;
    const size_t offWat2 = 105900000;    // folded Wa [128][96] bf16
    const size_t offBaf  = 105930000;    // folded ba [96] f32
    const size_t offWbf  = 105931000;    // folded Wb [96][2] f32
    const size_t offBbf  = 105932000;    // folded bb [2] f32
    const size_t offRow  = 106000000;    // cnt -> rowstart [N+1] ints
    const size_t offCur  = 106200128;    // cursor [N] ints
    const size_t offEsrc = 106400832;    // esrc [ETOT] ints
    const size_t offPart = 108700000;    // scan partials [64] ints
    const size_t offAs1  = 108800000;    // a_src1 [N*2] f32
    const size_t offAd1  = 109200000;
    const size_t offAs2  = 109600000;
    const size_t offAd2  = 109800000;
    const size_t offSt   = 110000000;    // stats: 12 x 512 B

    float* y2   = (float*)(ws + offY);
    unsigned short* xcat = (unsigned short*)(ws + offXcat);
    unsigned short* xb   = (unsigned short*)(ws + offXb);
    unsigned short* hb2  = (unsigned short*)(ws + offXb);   // reuse (xb dead after conv1)
    unsigned short* y1b  = (unsigned short*)(ws + offY1b);
    unsigned short* hb1  = (unsigned short*)(ws + offHb1);
    unsigned short* W1t  = (unsigned short*)(ws + offW1t);
    unsigned short* W2t  = (unsigned short*)(ws + offW2t);
    unsigned short* Wlt  = (unsigned short*)(ws + offWlt);
    unsigned short* Wat  = (unsigned short*)(ws + offWat);
    unsigned short* Wat2 = (unsigned short*)(ws + offWat2);
    float* ba_f = (float*)(ws + offBaf);
    float* Wb_f = (float*)(ws + offWbf);
    float* bb_f = (float*)(ws + offBbf);
    int* rowst  = (int*)(ws + offRow);
    int* cursor = (int*)(ws + offCur);
    int* esrc   = (int*)(ws + offEsrc);
    int* part   = (int*)(ws + offPart);
    float* as1  = (float*)(ws + offAs1);
    float* ad1  = (float*)(ws + offAd1);
    float* as2  = (float*)(ws + offAs2);
    float* ad2  = (float*)(ws + offAd2);

    float* csum_l = (float*)(ws + offSt + 0);
    float* csq_l  = (float*)(ws + offSt + 512);
    float* scl_l  = (float*)(ws + offSt + 1024);
    float* shf_l  = (float*)(ws + offSt + 1536);
    float* csum_a = (float*)(ws + offSt + 2048);
    float* csq_a  = (float*)(ws + offSt + 2560);
    float* scl_a  = (float*)(ws + offSt + 3072);
    float* shf_a  = (float*)(ws + offSt + 3584);
    float* csum_b = (float*)(ws + offSt + 4096);
    float* csq_b  = (float*)(ws + offSt + 4608);
    float* scl_b  = (float*)(ws + offSt + 5120);
    float* shf_b  = (float*)(ws + offSt + 5632);

    // zero: CSR histogram + att-dot accumulators + BN stats
    hipMemsetAsync(ws + offRow, 0, (NNODES + 1) * sizeof(int), stream);
    hipMemsetAsync(ws + offAs1, 0, (offSt + 6144) - offAs1, stream);

    dim3 blk(256);
    int edgeBlocks  = (ETOT + 255) / 256;
    int waveBlocksN = (N + 3) / 4;

    // ---- casts ----
    cast_x_k<<<(N * 128 / 4 + 255) / 256, blk, 0, stream>>>(x, xb, N * 128 / 4);
    cast_wt<<<dim3(1, 256), blk, 0, stream>>>(W1, W1t, 128, 256);
    cast_wt<<<dim3(1, 128), blk, 0, stream>>>(W2, W2t, 256, 128);
    cast_wt<<<dim3(2, 128), blk, 0, stream>>>(Wl, Wlt, 384, 96);
    cast_wt<<<dim3(1, 128), blk, 0, stream>>>(Wa, Wat, 96, 96);

    // ---- CSR build ----
    csr_count<<<edgeBlocks, blk, 0, stream>>>(ei, rowst);
    scan1<<<SCAN_NB, blk, 0, stream>>>(rowst, part);
    scan2<<<1, 64, 0, stream>>>(part, rowst);
    scan3<<<SCAN_NB, blk, 0, stream>>>(rowst, part, rowst, cursor);
    csr_fill<<<edgeBlocks, blk, 0, stream>>>(ei, cursor, esrc);

    // ---- conv1: hb1 = bf16(xb @ W1), fused att dots ----
    gemm_mfma<<<dim3(4, (N + GBM - 1) / GBM), blk, 0, stream>>>(
        xb, 128, W1t, nullptr, hb1, nullptr, nullptr, nullptr,
        att_src1, att_dst1, as1, ad1, 2, N, 256, 128, 0);
    gat_gather_h2<<<waveBlocksN, blk, 0, stream>>>(rowst, esrc, hb1, as1, ad1, bias1, xcat);

    // ---- conv2: hb2 = bf16(xcat[:, :256] @ W2), fused att dots ----
    gemm_mfma<<<dim3(2, (N + GBM - 1) / GBM), blk, 0, stream>>>(
        xcat, 384, W2t, nullptr, hb2, nullptr, nullptr, nullptr,
        att_src2, att_dst2, as2, ad2, 1, N, 128, 256, 0);
    gat_gather_h1<<<waveBlocksN, blk, 0, stream>>>(rowst, esrc, hb2, as2, ad2, bias2, xcat);

    // ---- lin1: y1b = bf16(relu(xcat @ Wl + bl)), stats; BN folded into Wa/ba ----
    gemm_mfma<<<dim3(2, (N + GBM - 1) / GBM), blk, 0, stream>>>(
        xcat, 384, Wlt, nullptr, y1b, bl, csum_l, csq_l,
        nullptr, nullptr, nullptr, nullptr, 0, N, 96, 384, 1);
    bn_finalize<<<1, 128, 0, stream>>>(csum_l, csq_l, gl, betal, scl_l, shf_l, 96, 1.f / N);
    fold_wa<<<1, 256, 0, stream>>>(Wa, ba, scl_l, shf_l, Wat2, ba_f);

    // ---- mlp1 layer 1: y2 = relu(y1b @ Wa' + ba'), stats; BN folded into Wb/bb ----
    gemm_mfma<<<dim3(2, (N + GBM - 1) / GBM), blk, 0, stream>>>(
        y1b, 96, Wat2, y2, nullptr, ba_f, csum_a, csq_a,
        nullptr, nullptr, nullptr, nullptr, 0, N, 96, 96, 1);
    bn_finalize<<<1, 128, 0, stream>>>(csum_a, csq_a, ga, betaa, scl_a, shf_a, 96, 1.f / N);
    fold_wb<<<1, 256, 0, stream>>>(Wb, bb, scl_a, shf_a, Wb_f, bb_f);

    // ---- mlp1 layer 2 (fp32, N=2, writes d_out) ----
    gemm_fused<<<dim3(1, (N + BM - 1) / BM), blk, 0, stream>>>(
        y2, 96, Wb_f, out, bb_f, csum_b, csq_b, N, 2, 96, 1);
    bn_finalize<<<1, 64, 0, stream>>>(csum_b, csq_b, gb, betab, scl_b, shf_b, 2, 1.f / N);
    bn_apply<<<(N * 2 + 255) / 256, blk, 0, stream>>>(out, scl_b, shf_b, N * 2, 2);
}

// Round 7
// 407.755 us; speedup vs baseline: 3.8756x; 1.0815x over previous
//
#include <hip/hip_runtime.h>
#include <hip/hip_bf16.h>
#include <cstdint>
#include <cstddef>

#define NNODES 50000
#define NEDGES 500000
#define ETOT   (NEDGES + NNODES)
#define MAXDEG 96

typedef __attribute__((ext_vector_type(8))) short short8;
typedef __attribute__((ext_vector_type(8))) unsigned short ushort8v;
typedef __attribute__((ext_vector_type(4))) float floatx4;
typedef __attribute__((ext_vector_type(4))) unsigned short ushort4v;

__device__ __forceinline__ unsigned short f2bf(float f) {
    union { __hip_bfloat16 h; unsigned short u; } cv;
    cv.h = __float2bfloat16(f);
    return cv.u;
}
__device__ __forceinline__ float bf2f(unsigned short u) {
    union { unsigned int i; float f; } cv;
    cv.i = ((unsigned int)u) << 16;
    return cv.f;
}

// ================= bf16 MFMA GEMM: C/Cb = op(A @ Bt^T + bias) =================
#define GBM 128
#define GBN 64
#define GBK 32

__global__ __launch_bounds__(256, 4) void gemm_mfma(
    const unsigned short* __restrict__ A, int lda,
    const unsigned short* __restrict__ Bt,
    float* __restrict__ C,
    unsigned short* __restrict__ Cb,
    const float* __restrict__ bias,
    float* __restrict__ colsum, float* __restrict__ colsq,
    const float* __restrict__ att_s, const float* __restrict__ att_d,
    float* __restrict__ as_out, float* __restrict__ ad_out, int Hheads,
    int M, int N, int K, int do_relu)
{
    __shared__ __attribute__((aligned(16))) unsigned short Alds[GBM * GBK];
    __shared__ __attribute__((aligned(16))) unsigned short Blds[GBN * GBK];
    __shared__ float scol[GBN], sqcol[GBN];

    int tid = threadIdx.x;
    int wave = tid >> 6, lane = tid & 63;
    int row0 = blockIdx.y * GBM;
    int col0 = blockIdx.x * GBN;
    int m = lane & 15, q = lane >> 4;

    floatx4 acc[2][4] = {};

    for (int k0 = 0; k0 < K; k0 += GBK) {
        #pragma unroll
        for (int i = 0; i < 2; ++i) {
            int c = tid + i * 256;
            int r = c >> 2, off = (c & 3) * 8;
            int gr = row0 + r;
            short8 v = {};
            if (gr < M) v = *(const short8*)(A + (size_t)gr * lda + k0 + off);
            *(short8*)(Alds + r * GBK + off) = v;
        }
        {
            int r = tid >> 2, off = (tid & 3) * 8;
            short8 v = *(const short8*)(Bt + (size_t)(col0 + r) * K + k0 + off);
            *(short8*)(Blds + r * GBK + off) = v;
        }
        __syncthreads();

        short8 a0 = *(const short8*)(Alds + (wave * 32 + m) * GBK + q * 8);
        short8 a1 = *(const short8*)(Alds + (wave * 32 + 16 + m) * GBK + q * 8);
        #pragma unroll
        for (int ct = 0; ct < 4; ++ct) {
            short8 b = *(const short8*)(Blds + (ct * 16 + m) * GBK + q * 8);
            acc[0][ct] = __builtin_amdgcn_mfma_f32_16x16x32_bf16(a0, b, acc[0][ct], 0, 0, 0);
            acc[1][ct] = __builtin_amdgcn_mfma_f32_16x16x32_bf16(a1, b, acc[1][ct], 0, 0, 0);
        }
        __syncthreads();
    }

    float ps[4] = {}, pq[4] = {};
    #pragma unroll
    for (int rt = 0; rt < 2; ++rt) {
        #pragma unroll
        for (int r = 0; r < 4; ++r) {
            int gr = row0 + wave * 32 + rt * 16 + q * 4 + r;
            float ds = 0.f, dd = 0.f;
            #pragma unroll
            for (int ct = 0; ct < 4; ++ct) {
                int gc = col0 + ct * 16 + m;
                float v = acc[rt][ct][r];
                if (gc < N) {
                    if (att_s != nullptr) { ds += v * att_s[gc]; dd += v * att_d[gc]; }
                    float vb = v;
                    if (bias != nullptr) vb += bias[gc];
                    if (do_relu) vb = fmaxf(vb, 0.f);
                    if (gr < M) {
                        if (C  != nullptr) C[(size_t)gr * N + gc] = vb;
                        if (Cb != nullptr) Cb[(size_t)gr * N + gc] = f2bf(vb);
                        ps[ct] += vb; pq[ct] += vb * vb;
                    }
                }
            }
            if (att_s != nullptr) {
                #pragma unroll
                for (int off = 1; off < 16; off <<= 1) {
                    ds += __shfl_xor(ds, off);
                    dd += __shfl_xor(dd, off);
                }
                if (m == 0 && gr < M) {
                    int head = col0 >> 7;
                    atomicAdd(&as_out[gr * Hheads + head], ds);
                    atomicAdd(&ad_out[gr * Hheads + head], dd);
                }
            }
        }
    }
    if (colsum != nullptr) {
        if (tid < GBN) { scol[tid] = 0.f; sqcol[tid] = 0.f; }
        __syncthreads();
        #pragma unroll
        for (int ct = 0; ct < 4; ++ct) {
            atomicAdd(&scol[ct * 16 + m], ps[ct]);
            atomicAdd(&sqcol[ct * 16 + m], pq[ct]);
        }
        __syncthreads();
        if (tid < GBN) {
            int gc = col0 + tid;
            if (gc < N) {
                atomicAdd(&colsum[gc], scol[tid]);
                atomicAdd(&colsq[gc], sqcol[tid]);
            }
        }
    }
}

// ================= casts =================
__global__ void cast_x_k(const float* __restrict__ x, unsigned short* __restrict__ xb, int total4) {
    int i = blockIdx.x * blockDim.x + threadIdx.x;
    if (i >= total4) return;
    const float4 v = ((const float4*)x)[i];
    ushort4v o;
    o.x = f2bf(v.x); o.y = f2bf(v.y); o.z = f2bf(v.z); o.w = f2bf(v.w);
    ((ushort4v*)xb)[i] = o;
}

// all three weight transposes+casts in one launch
__global__ void cast_weights(const float* __restrict__ W1, const float* __restrict__ W2,
                             const float* __restrict__ Wl,
                             unsigned short* __restrict__ W1t, unsigned short* __restrict__ W2t,
                             unsigned short* __restrict__ Wlt) {
    int i = blockIdx.x * 256 + threadIdx.x;
    if (i < 32768) {                                   // W1t [256][128], W1 [128][256]
        int n = i >> 7, k = i & 127;
        W1t[i] = f2bf(W1[k * 256 + n]);
    } else if (i < 65536) {                            // W2t [128][256], W2 [256][128]
        int j = i - 32768;
        int n = j >> 8, k = j & 255;
        W2t[j] = f2bf(W2[k * 128 + n]);
    } else if (i < 114688) {                           // Wlt [128][384], Wl [384][96]
        int j = i - 65536;
        int n = j / 384, k = j % 384;
        Wlt[j] = (n < 96) ? f2bf(Wl[(size_t)k * 96 + n]) : (unsigned short)0;
    }
}

// ================= fused BN-finalize + weight-fold kernels (one block each) =================
__global__ void bnfold_a(const float* __restrict__ csum, const float* __restrict__ csq,
                         const float* __restrict__ gamma, const float* __restrict__ beta,
                         const float* __restrict__ Wa, const float* __restrict__ ba,
                         unsigned short* __restrict__ Wat2, float* __restrict__ ba_f) {
    __shared__ float scl[96], shf[96];
    int tid = threadIdx.x;
    if (tid < 96) {
        float mu  = csum[tid] / (float)NNODES;
        float var = csq[tid] / (float)NNODES - mu * mu;
        if (var < 0.f) var = 0.f;
        float sc = gamma[tid] * rsqrtf(var + 1e-5f);
        scl[tid] = sc; shf[tid] = beta[tid] - mu * sc;
    }
    __syncthreads();
    for (int idx = tid; idx < 128 * 96; idx += 256) {
        int n = idx / 96, k = idx % 96;
        Wat2[idx] = (n < 96) ? f2bf(scl[k] * Wa[k * 96 + n]) : (unsigned short)0;
    }
    if (tid < 96) {
        float s = ba[tid];
        for (int k = 0; k < 96; ++k) s += shf[k] * Wa[k * 96 + tid];
        ba_f[tid] = s;
    }
}

__global__ void bnfold_b(const float* __restrict__ csum, const float* __restrict__ csq,
                         const float* __restrict__ gamma, const float* __restrict__ beta,
                         const float* __restrict__ Wb, const float* __restrict__ bb,
                         unsigned short* __restrict__ Wbt, float* __restrict__ bb_f) {
    __shared__ float scl[96], shf[96];
    int tid = threadIdx.x;
    if (tid < 96) {
        float mu  = csum[tid] / (float)NNODES;
        float var = csq[tid] / (float)NNODES - mu * mu;
        if (var < 0.f) var = 0.f;
        float sc = gamma[tid] * rsqrtf(var + 1e-5f);
        scl[tid] = sc; shf[tid] = beta[tid] - mu * sc;
    }
    __syncthreads();
    for (int idx = tid; idx < 64 * 96; idx += 256) {
        int n = idx / 96, k = idx % 96;
        Wbt[idx] = (n < 2) ? f2bf(scl[k] * Wb[k * 2 + n]) : (unsigned short)0;
    }
    if (tid < 2) {
        float s = bb[tid];
        for (int k = 0; k < 96; ++k) s += shf[k] * Wb[k * 2 + tid];
        bb_f[tid] = s;
    }
}

// final BN (C=2): finalize+apply fused
__global__ void bn_fin_apply(const float* __restrict__ csum, const float* __restrict__ csq,
                             const float* __restrict__ gamma, const float* __restrict__ beta,
                             float* __restrict__ y, int total) {
    int i = blockIdx.x * blockDim.x + threadIdx.x;
    if (i >= total) return;
    int j = i & 1;
    float mu  = csum[j] / (float)NNODES;
    float var = csq[j] / (float)NNODES - mu * mu;
    if (var < 0.f) var = 0.f;
    float sc = gamma[j] * rsqrtf(var + 1e-5f);
    float sh = beta[j] - mu * sc;
    y[i] = y[i] * sc + sh;
}

__device__ __forceinline__ void edge_src_dst(const int* ei, int e, int& src, int& dst) {
    if (e < NEDGES) { src = ei[e]; dst = ei[NEDGES + e]; }
    else { src = e - NEDGES; dst = src; }
}

// ================= CSR build =================
__global__ __launch_bounds__(256) void csr_count(const int* __restrict__ ei, int* __restrict__ cnt) {
    int e = blockIdx.x * blockDim.x + threadIdx.x;
    if (e >= ETOT) return;
    int src, dst; edge_src_dst(ei, e, src, dst); (void)src;
    atomicAdd(&cnt[dst], 1);
}

#define SCAN_CH 1024
#define SCAN_NB ((NNODES + SCAN_CH - 1) / SCAN_CH)   // 49

__global__ __launch_bounds__(256) void scan1(const int* __restrict__ cnt, int* __restrict__ part) {
    int t = threadIdx.x;
    int base = blockIdx.x * SCAN_CH + t * 4;
    int4 v = {0, 0, 0, 0};
    if (base + 3 < NNODES) v = *(const int4*)(cnt + base);
    else {
        if (base + 0 < NNODES) v.x = cnt[base + 0];
        if (base + 1 < NNODES) v.y = cnt[base + 1];
        if (base + 2 < NNODES) v.z = cnt[base + 2];
        if (base + 3 < NNODES) v.w = cnt[base + 3];
    }
    int s = v.x + v.y + v.z + v.w;
    __shared__ int sm[256];
    sm[t] = s;
    __syncthreads();
    for (int off = 128; off > 0; off >>= 1) {
        if (t < off) sm[t] += sm[t + off];
        __syncthreads();
    }
    if (t == 0) part[blockIdx.x] = sm[0];
}

__global__ void scan2(int* __restrict__ part, int* __restrict__ rowstart) {
    int lane = threadIdx.x;
    int v = (lane < SCAN_NB) ? part[lane] : 0;
    #pragma unroll
    for (int off = 1; off < 64; off <<= 1) {
        int t = __shfl_up(v, off);
        if (lane >= off) v += t;
    }
    int ex = __shfl_up(v, 1);
    if (lane == 0) ex = 0;
    if (lane < SCAN_NB) part[lane] = ex;
    if (lane == 0) rowstart[NNODES] = ETOT;
}

__global__ __launch_bounds__(256) void scan3(const int* __restrict__ cnt, const int* __restrict__ part,
                                             int* __restrict__ rowstart, int* __restrict__ cursor) {
    int t = threadIdx.x;
    int base = blockIdx.x * SCAN_CH + t * 4;
    int4 v = {0, 0, 0, 0};
    if (base + 3 < NNODES) v = *(const int4*)(cnt + base);
    else {
        if (base + 0 < NNODES) v.x = cnt[base + 0];
        if (base + 1 < NNODES) v.y = cnt[base + 1];
        if (base + 2 < NNODES) v.z = cnt[base + 2];
        if (base + 3 < NNODES) v.w = cnt[base + 3];
    }
    int s = v.x + v.y + v.z + v.w;
    __shared__ int sm[2][256];
    sm[0][t] = s;
    __syncthreads();
    int cur = 0;
    #pragma unroll
    for (int off = 1; off < 256; off <<= 1) {
        int nxt = cur ^ 1;
        int val = sm[cur][t];
        if (t >= off) val += sm[cur][t - off];
        sm[nxt][t] = val;
        __syncthreads();
        cur = nxt;
    }
    int p = sm[cur][t] - s + part[blockIdx.x];
    if (base + 0 < NNODES) { rowstart[base + 0] = p; cursor[base + 0] = p; } p += v.x;
    if (base + 1 < NNODES) { rowstart[base + 1] = p; cursor[base + 1] = p; } p += v.y;
    if (base + 2 < NNODES) { rowstart[base + 2] = p; cursor[base + 2] = p; } p += v.z;
    if (base + 3 < NNODES) { rowstart[base + 3] = p; cursor[base + 3] = p; }
}

__global__ __launch_bounds__(256) void csr_fill(const int* __restrict__ ei,
                                                int* __restrict__ cursor,
                                                int* __restrict__ esrc) {
    int e = blockIdx.x * blockDim.x + threadIdx.x;
    if (e >= ETOT) return;
    int src, dst; edge_src_dst(ei, e, src, dst);
    int pos = atomicAdd(&cursor[dst], 1);
    esrc[pos] = src;
}

// ================= fused GAT aggregation =================
// conv1 (H=2, 256 feats). LDS-cached softmax weights; 2 edge-groups of 32 lanes.
__global__ __launch_bounds__(256) void gat_gather_h2(
    const int* __restrict__ rowstart, const int* __restrict__ esrc,
    const unsigned short* __restrict__ hb, const float* __restrict__ a_src,
    const float* __restrict__ a_dst, const float* __restrict__ bias,
    unsigned short* __restrict__ xcat)
{
    __shared__ float wl[4][2][MAXDEG];
    int wave = threadIdx.x >> 6;
    int n = (blockIdx.x * blockDim.x + threadIdx.x) >> 6;
    int lane = threadIdx.x & 63;
    if (n >= NNODES) return;
    int beg = rowstart[n], end = rowstart[n + 1];
    int deg = end - beg;
    float ad0 = a_dst[n * 2], ad1 = a_dst[n * 2 + 1];

    // pass A: logits -> LDS, track max
    float m0 = -1e30f, m1 = -1e30f;
    for (int idx = lane; idx < deg; idx += 64) {
        int s = esrc[beg + idx];
        float l0 = a_src[s * 2] + ad0;     l0 = l0 >= 0.f ? l0 : 0.2f * l0;
        float l1 = a_src[s * 2 + 1] + ad1; l1 = l1 >= 0.f ? l1 : 0.2f * l1;
        m0 = fmaxf(m0, l0); m1 = fmaxf(m1, l1);
        if (idx < MAXDEG) { wl[wave][0][idx] = l0; wl[wave][1][idx] = l1; }
    }
    #pragma unroll
    for (int off = 1; off < 64; off <<= 1) {
        m0 = fmaxf(m0, __shfl_xor(m0, off));
        m1 = fmaxf(m1, __shfl_xor(m1, off));
    }
    // pass B: exp -> LDS, track sum
    float s0 = 0.f, s1 = 0.f;
    for (int idx = lane; idx < deg; idx += 64) {
        float l0, l1;
        if (idx < MAXDEG) { l0 = wl[wave][0][idx]; l1 = wl[wave][1][idx]; }
        else {
            int s = esrc[beg + idx];
            l0 = a_src[s * 2] + ad0;     l0 = l0 >= 0.f ? l0 : 0.2f * l0;
            l1 = a_src[s * 2 + 1] + ad1; l1 = l1 >= 0.f ? l1 : 0.2f * l1;
        }
        float e0 = __expf(l0 - m0), e1 = __expf(l1 - m1);
        s0 += e0; s1 += e1;
        if (idx < MAXDEG) { wl[wave][0][idx] = e0; wl[wave][1][idx] = e1; }
    }
    #pragma unroll
    for (int off = 1; off < 64; off <<= 1) {
        s0 += __shfl_xor(s0, off);
        s1 += __shfl_xor(s1, off);
    }

    int g  = lane >> 5;        // edge group (0/1)
    int sl = lane & 31;        // 16 B slot within 512 B row
    int head = sl >> 4;
    float mh   = head ? m1 : m0;
    float invh = head ? 1.f / (s1 + 1e-16f) : 1.f / (s0 + 1e-16f);
    float adh  = head ? ad1 : ad0;

    float acc[8] = {};
    for (int idx = g; idx < deg; idx += 2) {
        int s = esrc[beg + idx];
        float w;
        if (idx < MAXDEG) w = wl[wave][head][idx] * invh;
        else {
            float l = a_src[s * 2 + head] + adh; l = l >= 0.f ? l : 0.2f * l;
            w = __expf(l - mh) * invh;
        }
        const ushort8v hv = *(const ushort8v*)(hb + (size_t)s * 256 + sl * 8);
        #pragma unroll
        for (int j = 0; j < 8; ++j) acc[j] += w * bf2f(hv[j]);
    }
    #pragma unroll
    for (int j = 0; j < 8; ++j) acc[j] += __shfl_xor(acc[j], 32);
    if (g == 0) {
        ushort8v o;
        #pragma unroll
        for (int j = 0; j < 8; ++j) o[j] = f2bf(acc[j] + bias[sl * 8 + j]);
        *(ushort8v*)(xcat + (size_t)n * 384 + sl * 8) = o;
    }
}

// conv2 (H=1, 128 feats). 4 edge-groups of 16 lanes.
__global__ __launch_bounds__(256) void gat_gather_h1(
    const int* __restrict__ rowstart, const int* __restrict__ esrc,
    const unsigned short* __restrict__ hb, const float* __restrict__ a_src,
    const float* __restrict__ a_dst, const float* __restrict__ bias,
    unsigned short* __restrict__ xcat)
{
    __shared__ float wl[4][MAXDEG];
    int wave = threadIdx.x >> 6;
    int n = (blockIdx.x * blockDim.x + threadIdx.x) >> 6;
    int lane = threadIdx.x & 63;
    if (n >= NNODES) return;
    int beg = rowstart[n], end = rowstart[n + 1];
    int deg = end - beg;
    float ad0 = a_dst[n];

    float m0 = -1e30f;
    for (int idx = lane; idx < deg; idx += 64) {
        int s = esrc[beg + idx];
        float l0 = a_src[s] + ad0; l0 = l0 >= 0.f ? l0 : 0.2f * l0;
        m0 = fmaxf(m0, l0);
        if (idx < MAXDEG) wl[wave][idx] = l0;
    }
    #pragma unroll
    for (int off = 1; off < 64; off <<= 1) m0 = fmaxf(m0, __shfl_xor(m0, off));
    float s0 = 0.f;
    for (int idx = lane; idx < deg; idx += 64) {
        float l0;
        if (idx < MAXDEG) l0 = wl[wave][idx];
        else {
            int s = esrc[beg + idx];
            l0 = a_src[s] + ad0; l0 = l0 >= 0.f ? l0 : 0.2f * l0;
        }
        float e0 = __expf(l0 - m0);
        s0 += e0;
        if (idx < MAXDEG) wl[wave][idx] = e0;
    }
    #pragma unroll
    for (int off = 1; off < 64; off <<= 1) s0 += __shfl_xor(s0, off);
    float inv0 = 1.f / (s0 + 1e-16f);

    int g  = lane >> 4;        // edge group (0..3)
    int sl = lane & 15;        // 16 B slot within 256 B row

    float acc[8] = {};
    for (int idx = g; idx < deg; idx += 4) {
        int s = esrc[beg + idx];
        float w;
        if (idx < MAXDEG) w = wl[wave][idx] * inv0;
        else {
            float l = a_src[s] + ad0; l = l >= 0.f ? l : 0.2f * l;
            w = __expf(l - m0) * inv0;
        }
        const ushort8v hv = *(const ushort8v*)(hb + (size_t)s * 128 + sl * 8);
        #pragma unroll
        for (int j = 0; j < 8; ++j) acc[j] += w * bf2f(hv[j]);
    }
    #pragma unroll
    for (int j = 0; j < 8; ++j) acc[j] += __shfl_xor(acc[j], 16);
    #pragma unroll
    for (int j = 0; j < 8; ++j) acc[j] += __shfl_xor(acc[j], 32);
    if (g == 0) {
        ushort8v o;
        #pragma unroll
        for (int j = 0; j < 8; ++j) o[j] = f2bf(acc[j] + bias[sl * 8 + j]);
        *(ushort8v*)(xcat + (size_t)n * 384 + 256 + sl * 8) = o;
    }
}

extern "C" void kernel_launch(void* const* d_in, const int* in_sizes, int n_in,
                              void* d_out, int out_size, void* d_ws, size_t ws_size,
                              hipStream_t stream) {
    const float* x        = (const float*)d_in[0];
    const int*   ei       = (const int*)d_in[1];
    const float* W1       = (const float*)d_in[2];
    const float* att_src1 = (const float*)d_in[3];
    const float* att_dst1 = (const float*)d_in[4];
    const float* bias1    = (const float*)d_in[5];
    const float* W2       = (const float*)d_in[6];
    const float* att_src2 = (const float*)d_in[7];
    const float* att_dst2 = (const float*)d_in[8];
    const float* bias2    = (const float*)d_in[9];
    const float* Wl       = (const float*)d_in[10];
    const float* bl       = (const float*)d_in[11];
    const float* gl       = (const float*)d_in[12];
    const float* betal    = (const float*)d_in[13];
    const float* Wa       = (const float*)d_in[14];
    const float* ba       = (const float*)d_in[15];
    const float* ga       = (const float*)d_in[16];
    const float* betaa    = (const float*)d_in[17];
    const float* Wb       = (const float*)d_in[18];
    const float* bb       = (const float*)d_in[19];
    const float* gb       = (const float*)d_in[20];
    const float* betab    = (const float*)d_in[21];
    float* out = (float*)d_out;
    char* ws = (char*)d_ws;

    const int N = NNODES;

    // ---------- workspace layout (bytes) ----------
    const size_t offY2b  = 0;            //  9.6 MB: y2b bf16 [50000][96]
    const size_t offXcat = 19200000;     // 38.4 MB: xcat bf16 [50000][384]
    const size_t offXb   = 57600000;     // 12.8 MB: xb bf16 -> hb2 bf16 [50000][128]
    const size_t offY1b  = 70400000;     //  9.6 MB: y1b bf16 [50000][96]
    const size_t offHb1  = 80000000;     // 25.6 MB: hb1 bf16 [50000][256]
    const size_t offW1t  = 105600000;    // 64 KB
    const size_t offW2t  = 105665536;    // 64 KB
    const size_t offWlt  = 105731072;    // 96 KB
    const size_t offWat2 = 105829376;    // folded Wa bf16 [128][96]
    const size_t offWbt  = 105853952;    // folded Wb bf16 [64][96]
    const size_t offBaf  = 105866240;    // folded ba [96] f32
    const size_t offBbf  = 105866640;    // folded bb [2] f32
    const size_t offRow  = 106000000;    // cnt -> rowstart [N+1] ints
    const size_t offCur  = 106200128;    // cursor [N] ints
    const size_t offEsrc = 106400832;    // esrc [ETOT] ints
    const size_t offPart = 108700000;    // scan partials [64] ints
    const size_t offAs1  = 108800000;    // a_src1 [N*2] f32
    const size_t offAd1  = 109200000;
    const size_t offAs2  = 109600000;
    const size_t offAd2  = 109800000;
    const size_t offSt   = 110000000;    // stats

    unsigned short* y2b  = (unsigned short*)(ws + offY2b);
    unsigned short* xcat = (unsigned short*)(ws + offXcat);
    unsigned short* xb   = (unsigned short*)(ws + offXb);
    unsigned short* hb2  = (unsigned short*)(ws + offXb);   // reuse (xb dead after conv1)
    unsigned short* y1b  = (unsigned short*)(ws + offY1b);
    unsigned short* hb1  = (unsigned short*)(ws + offHb1);
    unsigned short* W1t  = (unsigned short*)(ws + offW1t);
    unsigned short* W2t  = (unsigned short*)(ws + offW2t);
    unsigned short* Wlt  = (unsigned short*)(ws + offWlt);
    unsigned short* Wat2 = (unsigned short*)(ws + offWat2);
    unsigned short* Wbt  = (unsigned short*)(ws + offWbt);
    float* ba_f = (float*)(ws + offBaf);
    float* bb_f = (float*)(ws + offBbf);
    int* rowst  = (int*)(ws + offRow);
    int* cursor = (int*)(ws + offCur);
    int* esrc   = (int*)(ws + offEsrc);
    int* part   = (int*)(ws + offPart);
    float* as1  = (float*)(ws + offAs1);
    float* ad1  = (float*)(ws + offAd1);
    float* as2  = (float*)(ws + offAs2);
    float* ad2  = (float*)(ws + offAd2);

    float* csum_l = (float*)(ws + offSt + 0);
    float* csq_l  = (float*)(ws + offSt + 512);
    float* csum_a = (float*)(ws + offSt + 2048);
    float* csq_a  = (float*)(ws + offSt + 2560);
    float* csum_b = (float*)(ws + offSt + 4096);
    float* csq_b  = (float*)(ws + offSt + 4608);

    // zero: CSR histogram + att-dot accumulators + BN stats
    hipMemsetAsync(ws + offRow, 0, (NNODES + 1) * sizeof(int), stream);
    hipMemsetAsync(ws + offAs1, 0, (offSt + 6144) - offAs1, stream);

    dim3 blk(256);
    int edgeBlocks  = (ETOT + 255) / 256;
    int waveBlocksN = (N + 3) / 4;

    // ---- casts ----
    cast_x_k<<<(N * 128 / 4 + 255) / 256, blk, 0, stream>>>(x, xb, N * 128 / 4);
    cast_weights<<<(114688 + 255) / 256, blk, 0, stream>>>(W1, W2, Wl, W1t, W2t, Wlt);

    // ---- CSR build ----
    csr_count<<<edgeBlocks, blk, 0, stream>>>(ei, rowst);
    scan1<<<SCAN_NB, blk, 0, stream>>>(rowst, part);
    scan2<<<1, 64, 0, stream>>>(part, rowst);
    scan3<<<SCAN_NB, blk, 0, stream>>>(rowst, part, rowst, cursor);
    csr_fill<<<edgeBlocks, blk, 0, stream>>>(ei, cursor, esrc);

    // ---- conv1: hb1 = bf16(xb @ W1), fused att dots ----
    gemm_mfma<<<dim3(4, (N + GBM - 1) / GBM), blk, 0, stream>>>(
        xb, 128, W1t, nullptr, hb1, nullptr, nullptr, nullptr,
        att_src1, att_dst1, as1, ad1, 2, N, 256, 128, 0);
    gat_gather_h2<<<waveBlocksN, blk, 0, stream>>>(rowst, esrc, hb1, as1, ad1, bias1, xcat);

    // ---- conv2: hb2 = bf16(xcat[:, :256] @ W2), fused att dots ----
    gemm_mfma<<<dim3(2, (N + GBM - 1) / GBM), blk, 0, stream>>>(
        xcat, 384, W2t, nullptr, hb2, nullptr, nullptr, nullptr,
        att_src2, att_dst2, as2, ad2, 1, N, 128, 256, 0);
    gat_gather_h1<<<waveBlocksN, blk, 0, stream>>>(rowst, esrc, hb2, as2, ad2, bias2, xcat);

    // ---- lin1: y1b = bf16(relu(xcat @ Wl + bl)), stats; fold BN into Wa ----
    gemm_mfma<<<dim3(2, (N + GBM - 1) / GBM), blk, 0, stream>>>(
        xcat, 384, Wlt, nullptr, y1b, bl, csum_l, csq_l,
        nullptr, nullptr, nullptr, nullptr, 0, N, 96, 384, 1);
    bnfold_a<<<1, 256, 0, stream>>>(csum_l, csq_l, gl, betal, Wa, ba, Wat2, ba_f);

    // ---- mlp1 layer 1: y2b = bf16(relu(y1b @ Wa' + ba')), stats; fold BN into Wb ----
    gemm_mfma<<<dim3(2, (N + GBM - 1) / GBM), blk, 0, stream>>>(
        y1b, 96, Wat2, nullptr, y2b, ba_f, csum_a, csq_a,
        nullptr, nullptr, nullptr, nullptr, 0, N, 96, 96, 1);
    bnfold_b<<<1, 256, 0, stream>>>(csum_a, csq_a, ga, betaa, Wb, bb, Wbt, bb_f);

    // ---- mlp1 layer 2: out = relu(y2b @ Wb' + bb'), stats (MFMA, N=2) ----
    gemm_mfma<<<dim3(1, (N + GBM - 1) / GBM), blk, 0, stream>>>(
        y2b, 96, Wbt, out, nullptr, bb_f, csum_b, csq_b,
        nullptr, nullptr, nullptr, nullptr, 0, N, 2, 96, 1);

    // ---- final BN (fused finalize+apply) ----
    bn_fin_apply<<<(N * 2 + 255) / 256, blk, 0, stream>>>(csum_b, csq_b, gb, betab, out, N * 2);
}

// Round 8
// 394.585 us; speedup vs baseline: 4.0050x; 1.0334x over previous
//
#include <hip/hip_runtime.h>
#include <hip/hip_bf16.h>
#include <cstdint>
#include <cstddef>

#define NNODES 50000
#define NEDGES 500000
#define ETOT   (NEDGES + NNODES)
#define MAXDEG 96

typedef __attribute__((ext_vector_type(8))) short short8;
typedef __attribute__((ext_vector_type(8))) unsigned short ushort8v;
typedef __attribute__((ext_vector_type(4))) float floatx4;
typedef __attribute__((ext_vector_type(4))) unsigned short ushort4v;

__device__ __forceinline__ unsigned short f2bf(float f) {
    union { __hip_bfloat16 h; unsigned short u; } cv;
    cv.h = __float2bfloat16(f);
    return cv.u;
}
__device__ __forceinline__ float bf2f(unsigned short u) {
    union { unsigned int i; float f; } cv;
    cv.i = ((unsigned int)u) << 16;
    return cv.f;
}

// ================= bf16 MFMA GEMM: C/Cb = op(A @ Bt^T + bias) =================
#define GBM 128
#define GBN 64
#define GBK 32

__global__ __launch_bounds__(256, 4) void gemm_mfma(
    const unsigned short* __restrict__ A, int lda,
    const unsigned short* __restrict__ Bt,
    float* __restrict__ C,
    unsigned short* __restrict__ Cb,
    const float* __restrict__ bias,
    float* __restrict__ colsum, float* __restrict__ colsq,
    const float* __restrict__ att_s, const float* __restrict__ att_d,
    float* __restrict__ as_out, float* __restrict__ ad_out, int Hheads,
    int M, int N, int K, int do_relu)
{
    __shared__ __attribute__((aligned(16))) unsigned short Alds[GBM * GBK];
    __shared__ __attribute__((aligned(16))) unsigned short Blds[GBN * GBK];
    __shared__ float scol[GBN], sqcol[GBN];

    int tid = threadIdx.x;
    int wave = tid >> 6, lane = tid & 63;
    int row0 = blockIdx.y * GBM;
    int col0 = blockIdx.x * GBN;
    int m = lane & 15, q = lane >> 4;

    floatx4 acc[2][4] = {};

    for (int k0 = 0; k0 < K; k0 += GBK) {
        #pragma unroll
        for (int i = 0; i < 2; ++i) {
            int c = tid + i * 256;
            int r = c >> 2, off = (c & 3) * 8;
            int gr = row0 + r;
            short8 v = {};
            if (gr < M) v = *(const short8*)(A + (size_t)gr * lda + k0 + off);
            *(short8*)(Alds + r * GBK + off) = v;
        }
        {
            int r = tid >> 2, off = (tid & 3) * 8;
            short8 v = *(const short8*)(Bt + (size_t)(col0 + r) * K + k0 + off);
            *(short8*)(Blds + r * GBK + off) = v;
        }
        __syncthreads();

        short8 a0 = *(const short8*)(Alds + (wave * 32 + m) * GBK + q * 8);
        short8 a1 = *(const short8*)(Alds + (wave * 32 + 16 + m) * GBK + q * 8);
        #pragma unroll
        for (int ct = 0; ct < 4; ++ct) {
            short8 b = *(const short8*)(Blds + (ct * 16 + m) * GBK + q * 8);
            acc[0][ct] = __builtin_amdgcn_mfma_f32_16x16x32_bf16(a0, b, acc[0][ct], 0, 0, 0);
            acc[1][ct] = __builtin_amdgcn_mfma_f32_16x16x32_bf16(a1, b, acc[1][ct], 0, 0, 0);
        }
        __syncthreads();
    }

    float ps[4] = {}, pq[4] = {};
    #pragma unroll
    for (int rt = 0; rt < 2; ++rt) {
        #pragma unroll
        for (int r = 0; r < 4; ++r) {
            int gr = row0 + wave * 32 + rt * 16 + q * 4 + r;
            float ds = 0.f, dd = 0.f;
            #pragma unroll
            for (int ct = 0; ct < 4; ++ct) {
                int gc = col0 + ct * 16 + m;
                float v = acc[rt][ct][r];
                if (gc < N) {
                    if (att_s != nullptr) { ds += v * att_s[gc]; dd += v * att_d[gc]; }
                    float vb = v;
                    if (bias != nullptr) vb += bias[gc];
                    if (do_relu) vb = fmaxf(vb, 0.f);
                    if (gr < M) {
                        if (C  != nullptr) C[(size_t)gr * N + gc] = vb;
                        if (Cb != nullptr) Cb[(size_t)gr * N + gc] = f2bf(vb);
                        ps[ct] += vb; pq[ct] += vb * vb;
                    }
                }
            }
            if (att_s != nullptr) {
                #pragma unroll
                for (int off = 1; off < 16; off <<= 1) {
                    ds += __shfl_xor(ds, off);
                    dd += __shfl_xor(dd, off);
                }
                if (m == 0 && gr < M) {
                    int head = col0 >> 7;
                    atomicAdd(&as_out[gr * Hheads + head], ds);
                    atomicAdd(&ad_out[gr * Hheads + head], dd);
                }
            }
        }
    }
    if (colsum != nullptr) {
        if (tid < GBN) { scol[tid] = 0.f; sqcol[tid] = 0.f; }
        __syncthreads();
        #pragma unroll
        for (int ct = 0; ct < 4; ++ct) {
            atomicAdd(&scol[ct * 16 + m], ps[ct]);
            atomicAdd(&sqcol[ct * 16 + m], pq[ct]);
        }
        __syncthreads();
        if (tid < GBN) {
            int gc = col0 + tid;
            if (gc < N) {
                atomicAdd(&colsum[gc], scol[tid]);
                atomicAdd(&colsq[gc], sqcol[tid]);
            }
        }
    }
}

// ================= casts =================
__global__ void cast_x_k(const float* __restrict__ x, unsigned short* __restrict__ xb, int total4) {
    int i = blockIdx.x * blockDim.x + threadIdx.x;
    if (i >= total4) return;
    const float4 v = ((const float4*)x)[i];
    ushort4v o;
    o.x = f2bf(v.x); o.y = f2bf(v.y); o.z = f2bf(v.z); o.w = f2bf(v.w);
    ((ushort4v*)xb)[i] = o;
}

__global__ void cast_weights(const float* __restrict__ W1, const float* __restrict__ W2,
                             const float* __restrict__ Wl,
                             unsigned short* __restrict__ W1t, unsigned short* __restrict__ W2t,
                             unsigned short* __restrict__ Wlt) {
    int i = blockIdx.x * 256 + threadIdx.x;
    if (i < 32768) {                                   // W1t [256][128], W1 [128][256]
        int n = i >> 7, k = i & 127;
        W1t[i] = f2bf(W1[k * 256 + n]);
    } else if (i < 65536) {                            // W2t [128][256], W2 [256][128]
        int j = i - 32768;
        int n = j >> 8, k = j & 255;
        W2t[j] = f2bf(W2[k * 128 + n]);
    } else if (i < 114688) {                           // Wlt [128][384], Wl [384][96]
        int j = i - 65536;
        int n = j / 384, k = j % 384;
        Wlt[j] = (n < 96) ? f2bf(Wl[(size_t)k * 96 + n]) : (unsigned short)0;
    }
}

// ================= fused BN-finalize + weight-fold kernels =================
__global__ void bnfold_a(const float* __restrict__ csum, const float* __restrict__ csq,
                         const float* __restrict__ gamma, const float* __restrict__ beta,
                         const float* __restrict__ Wa, const float* __restrict__ ba,
                         unsigned short* __restrict__ Wat2, float* __restrict__ ba_f) {
    __shared__ float scl[96], shf[96];
    int tid = threadIdx.x;
    if (tid < 96) {
        float mu  = csum[tid] / (float)NNODES;
        float var = csq[tid] / (float)NNODES - mu * mu;
        if (var < 0.f) var = 0.f;
        float sc = gamma[tid] * rsqrtf(var + 1e-5f);
        scl[tid] = sc; shf[tid] = beta[tid] - mu * sc;
    }
    __syncthreads();
    for (int idx = tid; idx < 128 * 96; idx += 256) {
        int n = idx / 96, k = idx % 96;
        Wat2[idx] = (n < 96) ? f2bf(scl[k] * Wa[k * 96 + n]) : (unsigned short)0;
    }
    if (tid < 96) {
        float s = ba[tid];
        for (int k = 0; k < 96; ++k) s += shf[k] * Wa[k * 96 + tid];
        ba_f[tid] = s;
    }
}

__global__ void bnfold_b(const float* __restrict__ csum, const float* __restrict__ csq,
                         const float* __restrict__ gamma, const float* __restrict__ beta,
                         const float* __restrict__ Wb, const float* __restrict__ bb,
                         unsigned short* __restrict__ Wbt, float* __restrict__ bb_f) {
    __shared__ float scl[96], shf[96];
    int tid = threadIdx.x;
    if (tid < 96) {
        float mu  = csum[tid] / (float)NNODES;
        float var = csq[tid] / (float)NNODES - mu * mu;
        if (var < 0.f) var = 0.f;
        float sc = gamma[tid] * rsqrtf(var + 1e-5f);
        scl[tid] = sc; shf[tid] = beta[tid] - mu * sc;
    }
    __syncthreads();
    for (int idx = tid; idx < 64 * 96; idx += 256) {
        int n = idx / 96, k = idx % 96;
        Wbt[idx] = (n < 2) ? f2bf(scl[k] * Wb[k * 2 + n]) : (unsigned short)0;
    }
    if (tid < 2) {
        float s = bb[tid];
        for (int k = 0; k < 96; ++k) s += shf[k] * Wb[k * 2 + tid];
        bb_f[tid] = s;
    }
}

__global__ void bn_fin_apply(const float* __restrict__ csum, const float* __restrict__ csq,
                             const float* __restrict__ gamma, const float* __restrict__ beta,
                             float* __restrict__ y, int total) {
    int i = blockIdx.x * blockDim.x + threadIdx.x;
    if (i >= total) return;
    int j = i & 1;
    float mu  = csum[j] / (float)NNODES;
    float var = csq[j] / (float)NNODES - mu * mu;
    if (var < 0.f) var = 0.f;
    float sc = gamma[j] * rsqrtf(var + 1e-5f);
    float sh = beta[j] - mu * sc;
    y[i] = y[i] * sc + sh;
}

__device__ __forceinline__ void edge_src_dst(const int* ei, int e, int& src, int& dst) {
    if (e < NEDGES) { src = ei[e]; dst = ei[NEDGES + e]; }
    else { src = e - NEDGES; dst = src; }
}

// ================= CSR build =================
__global__ __launch_bounds__(256) void csr_count(const int* __restrict__ ei, int* __restrict__ cnt) {
    int e = blockIdx.x * blockDim.x + threadIdx.x;
    if (e >= ETOT) return;
    int src, dst; edge_src_dst(ei, e, src, dst); (void)src;
    atomicAdd(&cnt[dst], 1);
}

#define SCAN_CH 1024
#define SCAN_NB ((NNODES + SCAN_CH - 1) / SCAN_CH)   // 49

__global__ __launch_bounds__(256) void scan1(const int* __restrict__ cnt, int* __restrict__ part) {
    int t = threadIdx.x;
    int base = blockIdx.x * SCAN_CH + t * 4;
    int4 v = {0, 0, 0, 0};
    if (base + 3 < NNODES) v = *(const int4*)(cnt + base);
    else {
        if (base + 0 < NNODES) v.x = cnt[base + 0];
        if (base + 1 < NNODES) v.y = cnt[base + 1];
        if (base + 2 < NNODES) v.z = cnt[base + 2];
        if (base + 3 < NNODES) v.w = cnt[base + 3];
    }
    int s = v.x + v.y + v.z + v.w;
    __shared__ int sm[256];
    sm[t] = s;
    __syncthreads();
    for (int off = 128; off > 0; off >>= 1) {
        if (t < off) sm[t] += sm[t + off];
        __syncthreads();
    }
    if (t == 0) part[blockIdx.x] = sm[0];
}

__global__ void scan2(int* __restrict__ part, int* __restrict__ rowstart) {
    int lane = threadIdx.x;
    int v = (lane < SCAN_NB) ? part[lane] : 0;
    #pragma unroll
    for (int off = 1; off < 64; off <<= 1) {
        int t = __shfl_up(v, off);
        if (lane >= off) v += t;
    }
    int ex = __shfl_up(v, 1);
    if (lane == 0) ex = 0;
    if (lane < SCAN_NB) part[lane] = ex;
    if (lane == 0) rowstart[NNODES] = ETOT;
}

__global__ __launch_bounds__(256) void scan3(const int* __restrict__ cnt, const int* __restrict__ part,
                                             int* __restrict__ rowstart, int* __restrict__ cursor) {
    int t = threadIdx.x;
    int base = blockIdx.x * SCAN_CH + t * 4;
    int4 v = {0, 0, 0, 0};
    if (base + 3 < NNODES) v = *(const int4*)(cnt + base);
    else {
        if (base + 0 < NNODES) v.x = cnt[base + 0];
        if (base + 1 < NNODES) v.y = cnt[base + 1];
        if (base + 2 < NNODES) v.z = cnt[base + 2];
        if (base + 3 < NNODES) v.w = cnt[base + 3];
    }
    int s = v.x + v.y + v.z + v.w;
    __shared__ int sm[2][256];
    sm[0][t] = s;
    __syncthreads();
    int cur = 0;
    #pragma unroll
    for (int off = 1; off < 256; off <<= 1) {
        int nxt = cur ^ 1;
        int val = sm[cur][t];
        if (t >= off) val += sm[cur][t - off];
        sm[nxt][t] = val;
        __syncthreads();
        cur = nxt;
    }
    int p = sm[cur][t] - s + part[blockIdx.x];
    if (base + 0 < NNODES) { rowstart[base + 0] = p; cursor[base + 0] = p; } p += v.x;
    if (base + 1 < NNODES) { rowstart[base + 1] = p; cursor[base + 1] = p; } p += v.y;
    if (base + 2 < NNODES) { rowstart[base + 2] = p; cursor[base + 2] = p; } p += v.z;
    if (base + 3 < NNODES) { rowstart[base + 3] = p; cursor[base + 3] = p; }
}

__global__ __launch_bounds__(256) void csr_fill(const int* __restrict__ ei,
                                                int* __restrict__ cursor,
                                                int* __restrict__ esrc) {
    int e = blockIdx.x * blockDim.x + threadIdx.x;
    if (e >= ETOT) return;
    int src, dst; edge_src_dst(ei, e, src, dst);
    int pos = atomicAdd(&cursor[dst], 1);
    esrc[pos] = src;
}

// ================= fused GAT aggregation =================
// conv1 (H=2, 256 feats). LDS softmax weights + edge ids; 2 groups x unroll 2.
__global__ __launch_bounds__(256) void gat_gather_h2(
    const int* __restrict__ rowstart, const int* __restrict__ esrc,
    const unsigned short* __restrict__ hb, const float* __restrict__ a_src,
    const float* __restrict__ a_dst, const float* __restrict__ bias,
    unsigned short* __restrict__ xcat)
{
    __shared__ float wl[4][2][MAXDEG];
    __shared__ int   esl[4][MAXDEG];
    int wave = threadIdx.x >> 6;
    int n = (blockIdx.x * blockDim.x + threadIdx.x) >> 6;
    int lane = threadIdx.x & 63;
    if (n >= NNODES) return;
    int beg = rowstart[n], end = rowstart[n + 1];
    int deg = end - beg;
    float ad0 = a_dst[n * 2], ad1 = a_dst[n * 2 + 1];

    // pass A: logits -> LDS, track max
    float m0 = -1e30f, m1 = -1e30f;
    for (int idx = lane; idx < deg; idx += 64) {
        int s = esrc[beg + idx];
        float l0 = a_src[s * 2] + ad0;     l0 = l0 >= 0.f ? l0 : 0.2f * l0;
        float l1 = a_src[s * 2 + 1] + ad1; l1 = l1 >= 0.f ? l1 : 0.2f * l1;
        m0 = fmaxf(m0, l0); m1 = fmaxf(m1, l1);
        if (idx < MAXDEG) { wl[wave][0][idx] = l0; wl[wave][1][idx] = l1; esl[wave][idx] = s; }
    }
    #pragma unroll
    for (int off = 1; off < 64; off <<= 1) {
        m0 = fmaxf(m0, __shfl_xor(m0, off));
        m1 = fmaxf(m1, __shfl_xor(m1, off));
    }
    // pass B: exp -> LDS, track sum
    float s0 = 0.f, s1 = 0.f;
    for (int idx = lane; idx < deg; idx += 64) {
        float l0, l1;
        if (idx < MAXDEG) { l0 = wl[wave][0][idx]; l1 = wl[wave][1][idx]; }
        else {
            int s = esrc[beg + idx];
            l0 = a_src[s * 2] + ad0;     l0 = l0 >= 0.f ? l0 : 0.2f * l0;
            l1 = a_src[s * 2 + 1] + ad1; l1 = l1 >= 0.f ? l1 : 0.2f * l1;
        }
        float e0 = __expf(l0 - m0), e1 = __expf(l1 - m1);
        s0 += e0; s1 += e1;
        if (idx < MAXDEG) { wl[wave][0][idx] = e0; wl[wave][1][idx] = e1; }
    }
    #pragma unroll
    for (int off = 1; off < 64; off <<= 1) {
        s0 += __shfl_xor(s0, off);
        s1 += __shfl_xor(s1, off);
    }

    int g  = lane >> 5;        // edge group (0/1)
    int sl = lane & 31;        // 16 B slot within 512 B row
    int head = sl >> 4;
    float mh   = head ? m1 : m0;
    float invh = head ? 1.f / (s1 + 1e-16f) : 1.f / (s0 + 1e-16f);
    float adh  = head ? ad1 : ad0;

    float acc[8] = {}, acc2[8] = {};
    for (int idx = g; idx < deg; idx += 4) {
        int sA; float wA;
        if (idx < MAXDEG) { sA = esl[wave][idx]; wA = wl[wave][head][idx] * invh; }
        else {
            sA = esrc[beg + idx];
            float l = a_src[sA * 2 + head] + adh; l = l >= 0.f ? l : 0.2f * l;
            wA = __expf(l - mh) * invh;
        }
        const ushort8v hvA = *(const ushort8v*)(hb + (size_t)sA * 256 + sl * 8);
        int i2 = idx + 2;
        if (i2 < deg) {
            int sB; float wB;
            if (i2 < MAXDEG) { sB = esl[wave][i2]; wB = wl[wave][head][i2] * invh; }
            else {
                sB = esrc[beg + i2];
                float l = a_src[sB * 2 + head] + adh; l = l >= 0.f ? l : 0.2f * l;
                wB = __expf(l - mh) * invh;
            }
            const ushort8v hvB = *(const ushort8v*)(hb + (size_t)sB * 256 + sl * 8);
            #pragma unroll
            for (int j = 0; j < 8; ++j) acc2[j] += wB * bf2f(hvB[j]);
        }
        #pragma unroll
        for (int j = 0; j < 8; ++j) acc[j] += wA * bf2f(hvA[j]);
    }
    #pragma unroll
    for (int j = 0; j < 8; ++j) acc[j] += acc2[j];
    #pragma unroll
    for (int j = 0; j < 8; ++j) acc[j] += __shfl_xor(acc[j], 32);
    if (g == 0) {
        ushort8v o;
        #pragma unroll
        for (int j = 0; j < 8; ++j) o[j] = f2bf(acc[j] + bias[sl * 8 + j]);
        *(ushort8v*)(xcat + (size_t)n * 384 + sl * 8) = o;
    }
}

// conv2 (H=1, 128 feats). 4 groups of 16 lanes x unroll 2.
__global__ __launch_bounds__(256) void gat_gather_h1(
    const int* __restrict__ rowstart, const int* __restrict__ esrc,
    const unsigned short* __restrict__ hb, const float* __restrict__ a_src,
    const float* __restrict__ a_dst, const float* __restrict__ bias,
    unsigned short* __restrict__ xcat)
{
    __shared__ float wl[4][MAXDEG];
    __shared__ int   esl[4][MAXDEG];
    int wave = threadIdx.x >> 6;
    int n = (blockIdx.x * blockDim.x + threadIdx.x) >> 6;
    int lane = threadIdx.x & 63;
    if (n >= NNODES) return;
    int beg = rowstart[n], end = rowstart[n + 1];
    int deg = end - beg;
    float ad0 = a_dst[n];

    float m0 = -1e30f;
    for (int idx = lane; idx < deg; idx += 64) {
        int s = esrc[beg + idx];
        float l0 = a_src[s] + ad0; l0 = l0 >= 0.f ? l0 : 0.2f * l0;
        m0 = fmaxf(m0, l0);
        if (idx < MAXDEG) { wl[wave][idx] = l0; esl[wave][idx] = s; }
    }
    #pragma unroll
    for (int off = 1; off < 64; off <<= 1) m0 = fmaxf(m0, __shfl_xor(m0, off));
    float s0 = 0.f;
    for (int idx = lane; idx < deg; idx += 64) {
        float l0;
        if (idx < MAXDEG) l0 = wl[wave][idx];
        else {
            int s = esrc[beg + idx];
            l0 = a_src[s] + ad0; l0 = l0 >= 0.f ? l0 : 0.2f * l0;
        }
        float e0 = __expf(l0 - m0);
        s0 += e0;
        if (idx < MAXDEG) wl[wave][idx] = e0;
    }
    #pragma unroll
    for (int off = 1; off < 64; off <<= 1) s0 += __shfl_xor(s0, off);
    float inv0 = 1.f / (s0 + 1e-16f);

    int g  = lane >> 4;        // edge group (0..3)
    int sl = lane & 15;        // 16 B slot within 256 B row

    float acc[8] = {}, acc2[8] = {};
    for (int idx = g; idx < deg; idx += 8) {
        int sA; float wA;
        if (idx < MAXDEG) { sA = esl[wave][idx]; wA = wl[wave][idx] * inv0; }
        else {
            sA = esrc[beg + idx];
            float l = a_src[sA] + ad0; l = l >= 0.f ? l : 0.2f * l;
            wA = __expf(l - m0) * inv0;
        }
        const ushort8v hvA = *(const ushort8v*)(hb + (size_t)sA * 128 + sl * 8);
        int i2 = idx + 4;
        if (i2 < deg) {
            int sB; float wB;
            if (i2 < MAXDEG) { sB = esl[wave][i2]; wB = wl[wave][i2] * inv0; }
            else {
                sB = esrc[beg + i2];
                float l = a_src[sB] + ad0; l = l >= 0.f ? l : 0.2f * l;
                wB = __expf(l - m0) * inv0;
            }
            const ushort8v hvB = *(const ushort8v*)(hb + (size_t)sB * 128 + sl * 8);
            #pragma unroll
            for (int j = 0; j < 8; ++j) acc2[j] += wB * bf2f(hvB[j]);
        }
        #pragma unroll
        for (int j = 0; j < 8; ++j) acc[j] += wA * bf2f(hvA[j]);
    }
    #pragma unroll
    for (int j = 0; j < 8; ++j) acc[j] += acc2[j];
    #pragma unroll
    for (int j = 0; j < 8; ++j) acc[j] += __shfl_xor(acc[j], 16);
    #pragma unroll
    for (int j = 0; j < 8; ++j) acc[j] += __shfl_xor(acc[j], 32);
    if (g == 0) {
        ushort8v o;
        #pragma unroll
        for (int j = 0; j < 8; ++j) o[j] = f2bf(acc[j] + bias[sl * 8 + j]);
        *(ushort8v*)(xcat + (size_t)n * 384 + 256 + sl * 8) = o;
    }
}

extern "C" void kernel_launch(void* const* d_in, const int* in_sizes, int n_in,
                              void* d_out, int out_size, void* d_ws, size_t ws_size,
                              hipStream_t stream) {
    const float* x        = (const float*)d_in[0];
    const int*   ei       = (const int*)d_in[1];
    const float* W1       = (const float*)d_in[2];
    const float* att_src1 = (const float*)d_in[3];
    const float* att_dst1 = (const float*)d_in[4];
    const float* bias1    = (const float*)d_in[5];
    const float* W2       = (const float*)d_in[6];
    const float* att_src2 = (const float*)d_in[7];
    const float* att_dst2 = (const float*)d_in[8];
    const float* bias2    = (const float*)d_in[9];
    const float* Wl       = (const float*)d_in[10];
    const float* bl       = (const float*)d_in[11];
    const float* gl       = (const float*)d_in[12];
    const float* betal    = (const float*)d_in[13];
    const float* Wa       = (const float*)d_in[14];
    const float* ba       = (const float*)d_in[15];
    const float* ga       = (const float*)d_in[16];
    const float* betaa    = (const float*)d_in[17];
    const float* Wb       = (const float*)d_in[18];
    const float* bb       = (const float*)d_in[19];
    const float* gb       = (const float*)d_in[20];
    const float* betab    = (const float*)d_in[21];
    float* out = (float*)d_out;
    char* ws = (char*)d_ws;

    const int N = NNODES;

    // ---------- workspace layout (bytes) ----------
    const size_t offY2b  = 0;            //  9.6 MB: y2b bf16 [50000][96]
    const size_t offXcat = 19200000;     // 38.4 MB: xcat bf16 [50000][384]
    const size_t offXb   = 57600000;     // 12.8 MB: xb bf16 -> hb2 bf16 [50000][128]
    const size_t offY1b  = 70400000;     //  9.6 MB: y1b bf16 [50000][96]
    const size_t offHb1  = 80000000;     // 25.6 MB: hb1 bf16 [50000][256]
    const size_t offW1t  = 105600000;    // 64 KB
    const size_t offW2t  = 105665536;    // 64 KB
    const size_t offWlt  = 105731072;    // 96 KB
    const size_t offWat2 = 105829376;    // folded Wa bf16 [128][96]
    const size_t offWbt  = 105853952;    // folded Wb bf16 [64][96]
    const size_t offBaf  = 105866240;    // folded ba [96] f32
    const size_t offBbf  = 105866640;    // folded bb [2] f32
    const size_t offRow  = 106000000;    // cnt -> rowstart [N+1] ints
    const size_t offCur  = 106200128;    // cursor [N] ints
    const size_t offEsrc = 106400832;    // esrc [ETOT] ints
    const size_t offPart = 108700000;    // scan partials [64] ints
    const size_t offAs1  = 108800000;    // a_src1 [N*2] f32
    const size_t offAd1  = 109200000;
    const size_t offAs2  = 109600000;
    const size_t offAd2  = 109800000;
    const size_t offSt   = 110000000;    // stats

    unsigned short* y2b  = (unsigned short*)(ws + offY2b);
    unsigned short* xcat = (unsigned short*)(ws + offXcat);
    unsigned short* xb   = (unsigned short*)(ws + offXb);
    unsigned short* hb2  = (unsigned short*)(ws + offXb);
    unsigned short* y1b  = (unsigned short*)(ws + offY1b);
    unsigned short* hb1  = (unsigned short*)(ws + offHb1);
    unsigned short* W1t  = (unsigned short*)(ws + offW1t);
    unsigned short* W2t  = (unsigned short*)(ws + offW2t);
    unsigned short* Wlt  = (unsigned short*)(ws + offWlt);
    unsigned short* Wat2 = (unsigned short*)(ws + offWat2);
    unsigned short* Wbt  = (unsigned short*)(ws + offWbt);
    float* ba_f = (float*)(ws + offBaf);
    float* bb_f = (float*)(ws + offBbf);
    int* rowst  = (int*)(ws + offRow);
    int* cursor = (int*)(ws + offCur);
    int* esrc   = (int*)(ws + offEsrc);
    int* part   = (int*)(ws + offPart);
    float* as1  = (float*)(ws + offAs1);
    float* ad1  = (float*)(ws + offAd1);
    float* as2  = (float*)(ws + offAs2);
    float* ad2  = (float*)(ws + offAd2);

    float* csum_l = (float*)(ws + offSt + 0);
    float* csq_l  = (float*)(ws + offSt + 512);
    float* csum_a = (float*)(ws + offSt + 2048);
    float* csq_a  = (float*)(ws + offSt + 2560);
    float* csum_b = (float*)(ws + offSt + 4096);
    float* csq_b  = (float*)(ws + offSt + 4608);

    hipMemsetAsync(ws + offRow, 0, (NNODES + 1) * sizeof(int), stream);
    hipMemsetAsync(ws + offAs1, 0, (offSt + 6144) - offAs1, stream);

    dim3 blk(256);
    int edgeBlocks  = (ETOT + 255) / 256;
    int waveBlocksN = (N + 3) / 4;

    // ---- casts ----
    cast_x_k<<<(N * 128 / 4 + 255) / 256, blk, 0, stream>>>(x, xb, N * 128 / 4);
    cast_weights<<<(114688 + 255) / 256, blk, 0, stream>>>(W1, W2, Wl, W1t, W2t, Wlt);

    // ---- CSR build ----
    csr_count<<<edgeBlocks, blk, 0, stream>>>(ei, rowst);
    scan1<<<SCAN_NB, blk, 0, stream>>>(rowst, part);
    scan2<<<1, 64, 0, stream>>>(part, rowst);
    scan3<<<SCAN_NB, blk, 0, stream>>>(rowst, part, rowst, cursor);
    csr_fill<<<edgeBlocks, blk, 0, stream>>>(ei, cursor, esrc);

    // ---- conv1: hb1 = bf16(xb @ W1), fused att dots ----
    gemm_mfma<<<dim3(4, (N + GBM - 1) / GBM), blk, 0, stream>>>(
        xb, 128, W1t, nullptr, hb1, nullptr, nullptr, nullptr,
        att_src1, att_dst1, as1, ad1, 2, N, 256, 128, 0);
    gat_gather_h2<<<waveBlocksN, blk, 0, stream>>>(rowst, esrc, hb1, as1, ad1, bias1, xcat);

    // ---- conv2: hb2 = bf16(xcat[:, :256] @ W2), fused att dots ----
    gemm_mfma<<<dim3(2, (N + GBM - 1) / GBM), blk, 0, stream>>>(
        xcat, 384, W2t, nullptr, hb2, nullptr, nullptr, nullptr,
        att_src2, att_dst2, as2, ad2, 1, N, 128, 256, 0);
    gat_gather_h1<<<waveBlocksN, blk, 0, stream>>>(rowst, esrc, hb2, as2, ad2, bias2, xcat);

    // ---- lin1: y1b = bf16(relu(xcat @ Wl + bl)), stats; fold BN into Wa ----
    gemm_mfma<<<dim3(2, (N + GBM - 1) / GBM), blk, 0, stream>>>(
        xcat, 384, Wlt, nullptr, y1b, bl, csum_l, csq_l,
        nullptr, nullptr, nullptr, nullptr, 0, N, 96, 384, 1);
    bnfold_a<<<1, 256, 0, stream>>>(csum_l, csq_l, gl, betal, Wa, ba, Wat2, ba_f);

    // ---- mlp1 layer 1: y2b = bf16(relu(y1b @ Wa' + ba')), stats; fold BN into Wb ----
    gemm_mfma<<<dim3(2, (N + GBM - 1) / GBM), blk, 0, stream>>>(
        y1b, 96, Wat2, nullptr, y2b, ba_f, csum_a, csq_a,
        nullptr, nullptr, nullptr, nullptr, 0, N, 96, 96, 1);
    bnfold_b<<<1, 256, 0, stream>>>(csum_a, csq_a, ga, betaa, Wb, bb, Wbt, bb_f);

    // ---- mlp1 layer 2: out = relu(y2b @ Wb' + bb'), stats (MFMA, N=2) ----
    gemm_mfma<<<dim3(1, (N + GBM - 1) / GBM), blk, 0, stream>>>(
        y2b, 96, Wbt, out, nullptr, bb_f, csum_b, csq_b,
        nullptr, nullptr, nullptr, nullptr, 0, N, 2, 96, 1);

    // ---- final BN (fused finalize+apply) ----
    bn_fin_apply<<<(N * 2 + 255) / 256, blk, 0, stream>>>(csum_b, csq_b, gb, betab, out, N * 2);
}